// Round 1
// baseline (4614.186 us; speedup 1.0000x reference)
//
#include <hip/hip_runtime.h>

#define T_STEPS 2048
#define NUSERS 4000
#define NLOCAS 4000
#define DD 128
#define KK 64
#define PRED_OUT 4192
#define PRED_IN 8256
#define OUT_EMB 1024000   // 8000*128
#define TT 16

// ws layout (float offsets)
#define WS_EU     0          // 2048*128
#define WS_EL     262144
#define WS_EP     524288
#define WS_KU     786432
#define WS_KL     1048576
#define WS_PREDP  1310720    // 2176 block partials
#define WS_DRIFT  1312904    // 1 float
#define NPRED_BLOCKS (128*17)

__global__ __launch_bounds__(256) void init_kernel(const float* __restrict__ emb_in,
                                                   float* __restrict__ out) {
    int i = blockIdx.x * blockDim.x + threadIdx.x;
    int stride = gridDim.x * blockDim.x;
    for (; i < OUT_EMB; i += stride) out[i] = emb_in[i];
}

// KU[t][r] = b_ih_u[r] + b_hh_u[r] + w_ih_u[r][192]*du[t] + sum_j w_ih_u[r][128+j]*kg[know_t][j]
__global__ __launch_bounds__(128) void precomp_k(const int* __restrict__ ev,
    const float* __restrict__ du, const float* __restrict__ dl,
    const float* __restrict__ kg,
    const float* __restrict__ wihu, const float* __restrict__ bihu, const float* __restrict__ bhhu,
    const float* __restrict__ wihl, const float* __restrict__ bihl, const float* __restrict__ bhhl,
    float* __restrict__ KU, float* __restrict__ KL) {
    int t = blockIdx.x;
    int r = threadIdx.x;
    __shared__ float skg[KK];
    int kn = ev[t*5 + 4];
    if (r < KK) skg[r] = kg[kn*KK + r];
    __syncthreads();
    float dut = du[t], dlt = dl[t];
    const float* wu = wihu + r*193;
    const float* wl = wihl + r*193;
    float ku = bihu[r] + bhhu[r] + wu[192]*dut;
    float kl = bihl[r] + bhhl[r] + wl[192]*dlt;
    #pragma unroll
    for (int j = 0; j < KK; ++j) {
        float s = skg[j];
        ku += wu[128+j]*s;
        kl += wl[128+j]*s;
    }
    KU[t*DD + r] = ku;
    KL[t*DD + r] = kl;
}

// Sequential chain: one block, 1024 threads. M (256x256) in registers, 64 f32/thread.
// thread: row = tid&255 (0..127 -> new_u row, 128..255 -> new_l row), q = tid>>8 (x-column quarter)
__global__ __launch_bounds__(1024) void chain_kernel(const int* __restrict__ ev,
    const float* __restrict__ wihu, const float* __restrict__ whhu,
    const float* __restrict__ whhl, const float* __restrict__ wihl,
    const float* __restrict__ KU, const float* __restrict__ KL,
    float* __restrict__ emb,
    float* __restrict__ EU, float* __restrict__ EL, float* __restrict__ EP,
    float* __restrict__ driftOut) {
    const int tid  = threadIdx.x;
    const int row  = tid & 255;
    const int q    = tid >> 8;
    const int lane = tid & 63;
    const int wid  = tid >> 6;

    // load my 64 weights: M[row][q*64 .. q*64+63]
    float w[64];
    {
        const float* src;
        const int off = (q & 1) * 64;
        if (q < 2) src = (row < 128) ? (wihu + row*193 + off) : (whhl + (row-128)*128 + off);
        else       src = (row < 128) ? (whhu + row*128 + off) : (wihl + (row-128)*193 + off);
        #pragma unroll
        for (int j = 0; j < 64; ++j) w[j] = src[j];
    }

    __shared__ float xs[256];        // [e_l(128); e_u(128)]
    __shared__ float partial[1024];
    __shared__ float wsum[4];
    __shared__ float wsum2[4];
    float driftacc = 0.f;

    for (int t = 0; t < T_STEPS; ++t) {
        const int u  = ev[t*5 + 0];
        const int lg = ev[t*5 + 1] + NUSERS;
        const int pg = ev[t*5 + 2] + NUSERS;

        if (tid < 128) {
            float v = emb[lg*DD + tid];
            xs[tid] = v;
            EL[t*DD + tid] = v;
        } else if (tid < 256) {
            int d = tid - 128;
            float v = emb[u*DD + d];
            xs[tid] = v;
            EU[t*DD + d] = v;
        } else if (tid < 384) {
            int d = tid - 256;
            EP[t*DD + d] = emb[pg*DD + d];
        }
        __syncthreads();

        // partial matvec: cols q*64 .. q*64+63
        float acc = 0.f;
        {
            const float* xp = xs + q*64;
            #pragma unroll
            for (int j = 0; j < 64; ++j) acc += w[j] * xp[j];
        }
        partial[tid] = acc;
        __syncthreads();

        float val = 0.f, old = 0.f;
        if (tid < 256) {
            float kv = (tid < 128) ? KU[t*DD + tid] : KL[t*DD + (tid - 128)];
            float pre = partial[tid] + partial[tid+256] + partial[tid+512] + partial[tid+768] + kv;
            float th = tanhf(pre);
            old = (tid < 128) ? xs[128 + tid] : xs[tid - 128];
            val = th;
            float ss = th * th;
            #pragma unroll
            for (int o = 32; o > 0; o >>= 1) ss += __shfl_down(ss, o);
            if (lane == 0) wsum[wid] = ss;
        }
        __syncthreads();

        if (tid < 256) {
            float n  = (tid < 128) ? sqrtf(wsum[0] + wsum[1]) : sqrtf(wsum[2] + wsum[3]);
            float sc = 1.f / fmaxf(n, 1e-12f);
            float v2 = val * sc;
            float dd = v2 - old;
            float ss2 = dd * dd;
            #pragma unroll
            for (int o = 32; o > 0; o >>= 1) ss2 += __shfl_down(ss2, o);
            if (lane == 0) wsum2[wid] = ss2;
            if (tid < 128) emb[u*DD + tid] = v2;
            else           emb[lg*DD + (tid - 128)] = v2;
        }
        __syncthreads();

        if (tid == 0)
            driftacc += (wsum2[0] + wsum2[1] + wsum2[2] + wsum2[3]) * (1.f / 128.f);
        // next write to wsum2/xs is separated by >=1 barrier -> safe
    }
    if (tid == 0) driftOut[0] = driftacc;
}

// pred loss: grid (128 t-tiles of 16, 17 row-chunks of 256). 256 threads.
__global__ __launch_bounds__(256) void pred_loss(const int* __restrict__ ev,
    const float* __restrict__ du, const float* __restrict__ kg,
    const float* __restrict__ pw, const float* __restrict__ projb,
    const float* __restrict__ predw, const float* __restrict__ predb,
    const float* __restrict__ EU, const float* __restrict__ EL, const float* __restrict__ EP,
    float* __restrict__ partials) {
    __shared__ float p [TT][DD];
    __shared__ float qv[TT][DD];
    __shared__ float kgp[TT][KK];
    __shared__ float kgn[TT][KK];
    __shared__ int   sprev[TT], su[TT];
    __shared__ float red[4];

    const int tid = threadIdx.x;
    const int t0  = blockIdx.x * TT;

    for (int tt = 0; tt < TT; ++tt) {
        int t = t0 + tt;
        if (tid == 0) { sprev[tt] = ev[t*5 + 2]; su[tt] = ev[t*5 + 0]; }
        if (tid < 128) {
            float fac = 1.f + pw[tid]*du[t] + projb[tid];
            p [tt][tid] = EU[(size_t)t*DD + tid] * fac;
            qv[tt][tid] = EP[(size_t)t*DD + tid];
        } else if (tid < 192) {
            int kp = ev[t*5 + 3];
            kgp[tt][tid-128] = kg[kp*KK + (tid-128)];
        } else {
            int kn = ev[t*5 + 4];
            kgn[tt][tid-192] = kg[kn*KK + (tid-192)];
        }
    }
    __syncthreads();

    const int r = blockIdx.y * 256 + tid;
    float ls = 0.f;
    if (r < PRED_OUT) {
        const float* wr = predw + (size_t)r * PRED_IN;
        float acc[TT];
        float bias = predb[r];
        #pragma unroll
        for (int tt = 0; tt < TT; ++tt)
            acc[tt] = bias + wr[320 + sprev[tt]] + wr[4320 + su[tt]];
        #pragma unroll 4
        for (int j = 0; j < KK; ++j) {
            float wv = wr[256 + j];
            #pragma unroll
            for (int tt = 0; tt < TT; ++tt) acc[tt] += wv * kgp[tt][j];
        }
        #pragma unroll 4
        for (int j = 0; j < DD; ++j) {
            float a1 = wr[j];
            #pragma unroll
            for (int tt = 0; tt < TT; ++tt) acc[tt] += a1 * p[tt][j];
        }
        #pragma unroll 4
        for (int j = 0; j < DD; ++j) {
            float a2 = wr[DD + j];
            #pragma unroll
            for (int tt = 0; tt < TT; ++tt) acc[tt] += a2 * qv[tt][j];
        }
        #pragma unroll
        for (int tt = 0; tt < TT; ++tt) {
            float tv;
            if (r < DD)                 tv = EL[(size_t)(t0+tt)*DD + r];
            else if (r < DD + NLOCAS)   tv = (r - DD == sprev[tt]) ? 1.f : 0.f;
            else                        tv = kgn[tt][r - (DD + NLOCAS)];
            float d = acc[tt] - tv;
            ls += d * d;
        }
    }
    #pragma unroll
    for (int o = 32; o > 0; o >>= 1) ls += __shfl_down(ls, o);
    const int lane = tid & 63, wid = tid >> 6;
    if (lane == 0) red[wid] = ls;
    __syncthreads();
    if (tid == 0) {
        float s = (red[0] + red[1] + red[2] + red[3]) * (1.0f / PRED_OUT);
        partials[blockIdx.y * gridDim.x + blockIdx.x] = s;
    }
}

__global__ __launch_bounds__(256) void final_reduce(const float* __restrict__ predp,
                                                    const float* __restrict__ drift,
                                                    float* __restrict__ out) {
    int tid = threadIdx.x;
    float s = 0.f;
    for (int i = tid; i < NPRED_BLOCKS; i += 256) s += predp[i];
    #pragma unroll
    for (int o = 32; o > 0; o >>= 1) s += __shfl_down(s, o);
    __shared__ float red[4];
    if ((tid & 63) == 0) red[tid >> 6] = s;
    __syncthreads();
    if (tid == 0) out[OUT_EMB] = red[0] + red[1] + red[2] + red[3] + drift[0];
}

extern "C" void kernel_launch(void* const* d_in, const int* in_sizes, int n_in,
                              void* d_out, int out_size, void* d_ws, size_t ws_size,
                              hipStream_t stream) {
    const float* emb_in = (const float*)d_in[0];
    const int*   ev     = (const int*)  d_in[1];
    const float* du     = (const float*)d_in[2];
    const float* dl     = (const float*)d_in[3];
    const float* kg     = (const float*)d_in[4];
    const float* wihu   = (const float*)d_in[5];
    const float* whhu   = (const float*)d_in[6];
    const float* bihu   = (const float*)d_in[7];
    const float* bhhu   = (const float*)d_in[8];
    const float* wihl   = (const float*)d_in[9];
    const float* whhl   = (const float*)d_in[10];
    const float* bihl   = (const float*)d_in[11];
    const float* bhhl   = (const float*)d_in[12];
    const float* projw  = (const float*)d_in[13];
    const float* projb  = (const float*)d_in[14];
    const float* predw  = (const float*)d_in[15];
    const float* predb  = (const float*)d_in[16];

    float* out = (float*)d_out;
    float* ws  = (float*)d_ws;
    float* EU = ws + WS_EU;
    float* EL = ws + WS_EL;
    float* EP = ws + WS_EP;
    float* KU = ws + WS_KU;
    float* KL = ws + WS_KL;
    float* PREDP = ws + WS_PREDP;
    float* DRIFT = ws + WS_DRIFT;

    init_kernel<<<2048, 256, 0, stream>>>(emb_in, out);
    precomp_k<<<T_STEPS, 128, 0, stream>>>(ev, du, dl, kg, wihu, bihu, bhhu,
                                           wihl, bihl, bhhl, KU, KL);
    chain_kernel<<<1, 1024, 0, stream>>>(ev, wihu, whhu, whhl, wihl, KU, KL,
                                         out, EU, EL, EP, DRIFT);
    pred_loss<<<dim3(T_STEPS/TT, 17), 256, 0, stream>>>(ev, du, kg, projw, projb,
                                                        predw, predb, EU, EL, EP, PREDP);
    final_reduce<<<1, 256, 0, stream>>>(PREDP, DRIFT, out);
}

// Round 3
// 1133.817 us; speedup vs baseline: 4.0696x; 4.0696x over previous
//
#include <hip/hip_runtime.h>

#define T_STEPS 2048
#define NUSERS 4000
#define NLOCAS 4000
#define DD 128
#define KK 64
#define PRED_OUT 4192
#define PRED_IN 8256
#define OUT_EMB 1024000   // 8000*128
#define TT 32
#define NSWEEPS 48

// ws layout (float offsets)
#define WS_NEWU   0          // 2048*128
#define WS_NEWL   262144
#define WS_KU     524288
#define WS_KL     786432
#define WS_PREDP  1048576    // 1088 block partials
#define WS_DRIFT  1050752    // 2048
#define WS_INT    1052800    // int region below
// int offsets within WS_INT
#define IO_PU     0
#define IO_PL     2048
#define IO_PP     4096
#define IO_LASTU  6144
#define IO_LASTL  8192
#define IO_ORDER  10240
#define IO_OFF    12288      // NSWEEPS+1 entries
#define IO_BAD    12352
#define NPRED_BLOCKS (64*17)

__global__ __launch_bounds__(256) void init_kernel(const float* __restrict__ emb_in,
                                                   float* __restrict__ out) {
    int i = blockIdx.x * blockDim.x + threadIdx.x;
    int stride = gridDim.x * blockDim.x;
    for (; i < OUT_EMB; i += stride) out[i] = emb_in[i];
}

// PU/PL/PP: last prior step matching u/l/prev. LASTU/LASTL: final writer flags.
__global__ __launch_bounds__(256) void preds_kernel(const int* __restrict__ ev,
                                                    int* __restrict__ ibase) {
    __shared__ int su[T_STEPS];
    __shared__ int sl[T_STEPS];
    const int tid = threadIdx.x;
    const int t = blockIdx.x * 256 + tid;
    for (int i = tid; i < T_STEPS; i += 256) { su[i] = ev[i*5]; sl[i] = ev[i*5+1]; }
    __syncthreads();
    const int u = su[t], l = sl[t], p = ev[t*5+2];
    int pu = -1, pl = -1, pp = -1;
    for (int q = t-1; q >= 0; --q) {
        if (pu < 0 && su[q] == u) pu = q;
        if (pl < 0 && sl[q] == l) pl = q;
        if (pp < 0 && sl[q] == p) pp = q;
        if (pu >= 0 && pl >= 0 && pp >= 0) break;
    }
    ibase[IO_PU + t] = pu;
    ibase[IO_PL + t] = pl;
    ibase[IO_PP + t] = pp;
    int lu = 1, ll = 1;
    for (int q = t+1; q < T_STEPS; ++q) if (su[q] == u) { lu = 0; break; }
    for (int q = t+1; q < T_STEPS; ++q) if (sl[q] == l) { ll = 0; break; }
    ibase[IO_LASTU + t] = lu;
    ibase[IO_LASTL + t] = ll;
}

// DAG levels via monotone fixpoint; then counting sort into ORDER with OFF[].
__global__ __launch_bounds__(1024) void levels_kernel(int* __restrict__ ibase) {
    __shared__ int lev[T_STEPS];
    __shared__ int spu[T_STEPS];
    __shared__ int spl[T_STEPS];
    __shared__ int cnt[NSWEEPS + 1];
    __shared__ int off[NSWEEPS + 1];
    __shared__ int changed;
    const int tid = threadIdx.x;

    for (int i = tid; i < T_STEPS; i += 1024) {
        spu[i] = ibase[IO_PU + i];
        spl[i] = ibase[IO_PL + i];
        lev[i] = 0;
    }
    __syncthreads();

    for (int it = 0; it < T_STEPS; ++it) {       // bounded; converges in depth sweeps
        if (tid == 0) changed = 0;
        __syncthreads();
        for (int i = tid; i < T_STEPS; i += 1024) {
            int nl = 0;
            int a = spu[i], b = spl[i];
            if (a >= 0) nl = lev[a] + 1;
            if (b >= 0) { int v = lev[b] + 1; if (v > nl) nl = v; }
            if (nl > lev[i]) { lev[i] = nl; changed = 1; }
        }
        __syncthreads();
        if (!changed) break;
        __syncthreads();
    }

    if (tid <= NSWEEPS) cnt[tid] = 0;
    __syncthreads();
    int bad = 0;
    for (int i = tid; i < T_STEPS; i += 1024) {
        int lv = lev[i];
        if (lv >= NSWEEPS) { lv = NSWEEPS - 1; bad = 1; }
        atomicAdd(&cnt[lv], 1);
    }
    if (bad) ibase[IO_BAD] = 1;     // poison path (benign race, idempotent)
    if (tid == 0 && !bad) ibase[IO_BAD] = 0;
    __syncthreads();
    if (tid == 0) {
        int acc = 0;
        for (int k = 0; k < NSWEEPS; ++k) { off[k] = acc; acc += cnt[k]; }
        off[NSWEEPS] = acc;
        for (int k = 0; k <= NSWEEPS; ++k) ibase[IO_OFF + k] = off[k];
        for (int k = 0; k < NSWEEPS; ++k) cnt[k] = off[k];   // running cursors
    }
    __syncthreads();
    for (int i = tid; i < T_STEPS; i += 1024) {
        int lv = lev[i]; if (lv >= NSWEEPS) lv = NSWEEPS - 1;
        int pos = atomicAdd(&cnt[lv], 1);
        ibase[IO_ORDER + pos] = i;
    }
}

// KU[t][r] = b_ih_u[r]+b_hh_u[r]+w_ih_u[r][192]*du[t]+sum_j w_ih_u[r][128+j]*kg[know_t][j]
__global__ __launch_bounds__(128) void precomp_k(const int* __restrict__ ev,
    const float* __restrict__ du, const float* __restrict__ dl,
    const float* __restrict__ kg,
    const float* __restrict__ wihu, const float* __restrict__ bihu, const float* __restrict__ bhhu,
    const float* __restrict__ wihl, const float* __restrict__ bihl, const float* __restrict__ bhhl,
    float* __restrict__ KU, float* __restrict__ KL) {
    int t = blockIdx.x;
    int r = threadIdx.x;
    __shared__ float skg[KK];
    int kn = ev[t*5 + 4];
    if (r < KK) skg[r] = kg[kn*KK + r];
    __syncthreads();
    float dut = du[t], dlt = dl[t];
    const float* wu = wihu + r*193;
    const float* wl = wihl + r*193;
    float ku = bihu[r] + bhhu[r] + wu[192]*dut;
    float kl = bihl[r] + bhhl[r] + wl[192]*dlt;
    #pragma unroll
    for (int j = 0; j < KK; ++j) {
        float s = skg[j];
        ku += wu[128+j]*s;
        kl += wl[128+j]*s;
    }
    KU[t*DD + r] = ku;
    KL[t*DD + r] = kl;
}

// One DAG level per launch. 256 blocks x 512 threads; M in registers (128/thread).
// Cross-level ordering via kernel boundaries on the stream — no device sync.
__global__ __launch_bounds__(512) void chain_sweep(int lv, const int* __restrict__ ev,
    const float* __restrict__ emb0,
    const float* __restrict__ wihu, const float* __restrict__ whhu,
    const float* __restrict__ whhl, const float* __restrict__ wihl,
    const float* __restrict__ KU, const float* __restrict__ KL,
    float* __restrict__ NEWU, float* __restrict__ NEWL, float* __restrict__ DRIFT,
    const int* __restrict__ ibase) {
    const int start = ibase[IO_OFF + lv];
    const int end   = ibase[IO_OFF + lv + 1];
    if ((int)blockIdx.x >= end - start) return;

    const int tid  = threadIdx.x;
    const int h    = tid >> 8;      // column half
    const int r    = tid & 255;     // output row
    const int lane = tid & 63;
    const int wid  = tid >> 6;

    // M[r][h*128 .. h*128+127]
    float w[128];
    {
        const float* src;
        if (h == 0) src = (r < 128) ? (wihu + r*193) : (whhl + (r-128)*128);
        else        src = (r < 128) ? (whhu + r*128) : (wihl + (r-128)*193);
        #pragma unroll
        for (int j = 0; j < 128; ++j) w[j] = src[j];
    }

    __shared__ float xs[256];        // [e_l(128); e_u(128)]
    __shared__ float partial[512];
    __shared__ float wsum[8];

    for (int s = start + blockIdx.x; s < end; s += gridDim.x) {
        const int t  = ibase[IO_ORDER + s];
        const int u  = ev[t*5];
        const int l  = ev[t*5 + 1];
        const int pu = ibase[IO_PU + t];
        const int pl = ibase[IO_PL + t];

        float kv = 0.f;
        if (tid < 128) {
            xs[tid] = (pl >= 0) ? NEWL[pl*DD + tid] : emb0[(size_t)(l + NUSERS)*DD + tid];
            kv = KU[t*DD + tid];
        } else if (tid < 256) {
            int d = tid - 128;
            xs[tid] = (pu >= 0) ? NEWU[pu*DD + d] : emb0[(size_t)u*DD + d];
            kv = KL[t*DD + d];
        }
        __syncthreads();                               // B1

        float acc = 0.f;
        {
            const float* xp = xs + h*128;              // wave-uniform -> LDS broadcast
            #pragma unroll
            for (int j = 0; j < 128; ++j) acc += w[j] * xp[j];
        }
        partial[tid] = acc;
        __syncthreads();                               // B2

        float th = 0.f;
        if (tid < 256) {
            float pre = partial[tid] + partial[256 + tid] + kv;
            th = tanhf(pre);
            float ss = th * th;
            #pragma unroll
            for (int o = 32; o > 0; o >>= 1) ss += __shfl_xor(ss, o, 64);
            if (lane == 0) wsum[wid] = ss;
        }
        __syncthreads();                               // B3

        if (tid < 256) {
            float S  = (tid < 128) ? (wsum[0] + wsum[1]) : (wsum[2] + wsum[3]);
            float sf = 1.f / fmaxf(sqrtf(S), 1e-12f);
            float v2 = th * sf;
            float old = (tid < 128) ? xs[128 + tid] : xs[tid - 128];
            if (tid < 128) NEWU[t*DD + tid]       = v2;
            else           NEWL[t*DD + (tid-128)] = v2;
            float dd = v2 - old;
            float s2 = dd * dd;
            #pragma unroll
            for (int o = 32; o > 0; o >>= 1) s2 += __shfl_xor(s2, o, 64);
            if (lane == 0) wsum[4 + wid] = s2;
        }
        __syncthreads();                               // B4
        if (tid == 0)
            DRIFT[t] = (wsum[4] + wsum[5] + wsum[6] + wsum[7]) * (1.f / 128.f);
        // next xs write races only with completed reads; wsum[4..7] rewritten after B3'
    }
}

__global__ __launch_bounds__(128) void scatter_last(const int* __restrict__ ev,
    const float* __restrict__ NEWU, const float* __restrict__ NEWL,
    const int* __restrict__ ibase, float* __restrict__ out) {
    int t = blockIdx.x, d = threadIdx.x;
    if (ibase[IO_LASTU + t]) out[(size_t)ev[t*5]*DD + d]            = NEWU[t*DD + d];
    if (ibase[IO_LASTL + t]) out[(size_t)(ev[t*5+1]+NUSERS)*DD + d] = NEWL[t*DD + d];
}

// pred loss: grid (64 t-tiles of 32, 17 row-chunks of 256). 256 threads.
__global__ __launch_bounds__(256) void pred_loss(const int* __restrict__ ev,
    const float* __restrict__ du, const float* __restrict__ kg,
    const float* __restrict__ pw, const float* __restrict__ projb,
    const float* __restrict__ predw, const float* __restrict__ predb,
    const float* __restrict__ emb0,
    const float* __restrict__ NEWU, const float* __restrict__ NEWL,
    const int* __restrict__ ibase,
    float* __restrict__ partials) {
    __shared__ float p [TT][DD];
    __shared__ float qv[TT][DD];
    __shared__ float kgp[TT][KK];
    __shared__ float kgn[TT][KK];
    __shared__ int   sv[TT][8];   // u,l,prev,kp,kn,pu,pl,pp
    __shared__ float red[4];

    const int tid = threadIdx.x;
    const int t0  = blockIdx.x * TT;

    {
        int tt = tid >> 3, wq = tid & 7;     // 256 threads = TT*8 exactly
        int t = t0 + tt;
        int v;
        switch (wq) {
            case 0: v = ev[t*5];          break;
            case 1: v = ev[t*5+1];        break;
            case 2: v = ev[t*5+2];        break;
            case 3: v = ev[t*5+3];        break;
            case 4: v = ev[t*5+4];        break;
            case 5: v = ibase[IO_PU + t]; break;
            case 6: v = ibase[IO_PL + t]; break;
            default: v = ibase[IO_PP + t]; break;
        }
        sv[tt][wq] = v;
    }
    __syncthreads();

    for (int tt = 0; tt < TT; ++tt) {
        int t = t0 + tt;
        if (tid < 128) {
            int u  = sv[tt][0], pu = sv[tt][5];
            float eu = (pu >= 0) ? NEWU[pu*DD + tid] : emb0[(size_t)u*DD + tid];
            float fac = 1.f + pw[tid]*du[t] + projb[tid];
            p[tt][tid] = eu * fac;
            int pv = sv[tt][2], pp = sv[tt][7];
            qv[tt][tid] = (pp >= 0) ? NEWL[pp*DD + tid] : emb0[(size_t)(pv + NUSERS)*DD + tid];
        } else if (tid < 192) {
            kgp[tt][tid-128] = kg[sv[tt][3]*KK + (tid-128)];
        } else {
            kgn[tt][tid-192] = kg[sv[tt][4]*KK + (tid-192)];
        }
    }
    __syncthreads();

    const int r = blockIdx.y * 256 + tid;
    float ls = 0.f;
    if (r < PRED_OUT) {
        const float* wr = predw + (size_t)r * PRED_IN;
        float acc[TT];
        float bias = predb[r];
        #pragma unroll
        for (int tt = 0; tt < TT; ++tt)
            acc[tt] = bias + wr[320 + sv[tt][2]] + wr[4320 + sv[tt][0]];
        #pragma unroll 2
        for (int j = 0; j < KK; ++j) {
            float wv = wr[256 + j];
            #pragma unroll
            for (int tt = 0; tt < TT; ++tt) acc[tt] += wv * kgp[tt][j];
        }
        #pragma unroll 2
        for (int j = 0; j < DD; ++j) {
            float a1 = wr[j];
            #pragma unroll
            for (int tt = 0; tt < TT; ++tt) acc[tt] += a1 * p[tt][j];
        }
        #pragma unroll 2
        for (int j = 0; j < DD; ++j) {
            float a2 = wr[DD + j];
            #pragma unroll
            for (int tt = 0; tt < TT; ++tt) acc[tt] += a2 * qv[tt][j];
        }
        #pragma unroll
        for (int tt = 0; tt < TT; ++tt) {
            float tv;
            if (r < DD) {
                int pl = sv[tt][6];
                tv = (pl >= 0) ? NEWL[pl*DD + r]
                               : emb0[(size_t)(sv[tt][1] + NUSERS)*DD + r];
            } else if (r < DD + NLOCAS) {
                tv = (r - DD == sv[tt][2]) ? 1.f : 0.f;
            } else {
                tv = kgn[tt][r - (DD + NLOCAS)];
            }
            float d = acc[tt] - tv;
            ls += d * d;
        }
    }
    #pragma unroll
    for (int o = 32; o > 0; o >>= 1) ls += __shfl_down(ls, o);
    const int lane = tid & 63, wid = tid >> 6;
    if (lane == 0) red[wid] = ls;
    __syncthreads();
    if (tid == 0) {
        float s = (red[0] + red[1] + red[2] + red[3]) * (1.0f / PRED_OUT);
        partials[blockIdx.y * gridDim.x + blockIdx.x] = s;
    }
}

__global__ __launch_bounds__(256) void final_reduce(const float* __restrict__ predp,
                                                    const float* __restrict__ drift,
                                                    const int* __restrict__ ibase,
                                                    float* __restrict__ out) {
    int tid = threadIdx.x;
    float s = 0.f;
    for (int i = tid; i < NPRED_BLOCKS; i += 256) s += predp[i];
    for (int i = tid; i < T_STEPS; i += 256) s += drift[i];
    #pragma unroll
    for (int o = 32; o > 0; o >>= 1) s += __shfl_down(s, o);
    __shared__ float red[4];
    if ((tid & 63) == 0) red[tid >> 6] = s;
    __syncthreads();
    if (tid == 0) {
        float tot = red[0] + red[1] + red[2] + red[3];
        if (ibase[IO_BAD]) tot += 1e30f;   // loud failure if DAG depth >= NSWEEPS
        out[OUT_EMB] = tot;
    }
}

extern "C" void kernel_launch(void* const* d_in, const int* in_sizes, int n_in,
                              void* d_out, int out_size, void* d_ws, size_t ws_size,
                              hipStream_t stream) {
    const float* emb_in = (const float*)d_in[0];
    const int*   ev     = (const int*)  d_in[1];
    const float* du     = (const float*)d_in[2];
    const float* dl     = (const float*)d_in[3];
    const float* kg     = (const float*)d_in[4];
    const float* wihu   = (const float*)d_in[5];
    const float* whhu   = (const float*)d_in[6];
    const float* bihu   = (const float*)d_in[7];
    const float* bhhu   = (const float*)d_in[8];
    const float* wihl   = (const float*)d_in[9];
    const float* whhl   = (const float*)d_in[10];
    const float* bihl   = (const float*)d_in[11];
    const float* bhhl   = (const float*)d_in[12];
    const float* projw  = (const float*)d_in[13];
    const float* projb  = (const float*)d_in[14];
    const float* predw  = (const float*)d_in[15];
    const float* predb  = (const float*)d_in[16];

    float* out = (float*)d_out;
    float* ws  = (float*)d_ws;
    float* NEWU  = ws + WS_NEWU;
    float* NEWL  = ws + WS_NEWL;
    float* KU    = ws + WS_KU;
    float* KL    = ws + WS_KL;
    float* PREDP = ws + WS_PREDP;
    float* DRIFT = ws + WS_DRIFT;
    int*   ibase = (int*)(ws + WS_INT);

    init_kernel<<<2048, 256, 0, stream>>>(emb_in, out);
    preds_kernel<<<T_STEPS/256, 256, 0, stream>>>(ev, ibase);
    levels_kernel<<<1, 1024, 0, stream>>>(ibase);
    precomp_k<<<T_STEPS, 128, 0, stream>>>(ev, du, dl, kg, wihu, bihu, bhhu,
                                           wihl, bihl, bhhl, KU, KL);
    for (int lv = 0; lv < NSWEEPS; ++lv)
        chain_sweep<<<256, 512, 0, stream>>>(lv, ev, emb_in, wihu, whhu, whhl, wihl,
                                             KU, KL, NEWU, NEWL, DRIFT, ibase);
    scatter_last<<<T_STEPS, 128, 0, stream>>>(ev, NEWU, NEWL, ibase, out);
    pred_loss<<<dim3(T_STEPS/TT, 17), 256, 0, stream>>>(ev, du, kg, projw, projb,
                                                        predw, predb, emb_in,
                                                        NEWU, NEWL, ibase, PREDP);
    final_reduce<<<1, 256, 0, stream>>>(PREDP, DRIFT, ibase, out);
}

// Round 5
// 1024.940 us; speedup vs baseline: 4.5019x; 1.1062x over previous
//
#include <hip/hip_runtime.h>
#include <hip/hip_cooperative_groups.h>
namespace cg = cooperative_groups;

#define T_STEPS 2048
#define NUSERS 4000
#define NLOCAS 4000
#define DD 128
#define KK 64
#define PRED_OUT 4192
#define PRED_IN 8256
#define OUT_EMB 1024000   // 8000*128

// ---- ws layout (float offsets) ----
#define WS_NEWU   0          // 262144
#define WS_NEWL   262144
#define WS_KU     524288
#define WS_KL     786432
#define WS_Z      1048576    // 2048*320
#define WS_ELT    1703936    // 128*2048
#define WS_DRIFT  1966080    // 2048
#define WS_ROWP   1968128    // up to 32*4192
#define WS_INT    2107392    // 14400 ints
#define WS_S      2121792    // 4192*NT floats
// ---- int offsets within WS_INT ----
#define IO_PU     0
#define IO_PL     2048
#define IO_PP     4096
#define IO_LASTU  6144
#define IO_LASTL  8192
#define IO_ORDER  10240
#define IO_OFF    12288      // 2049 entries
#define IO_NLEV   14337

__global__ __launch_bounds__(256) void init_kernel(const float* __restrict__ emb_in,
                                                   float* __restrict__ out) {
    int i = blockIdx.x * blockDim.x + threadIdx.x;
    int stride = gridDim.x * blockDim.x;
    for (; i < OUT_EMB; i += stride) out[i] = emb_in[i];
}

// PU/PL/PP: last prior step matching u/l/prev. LASTU/LASTL: final writer flags.
__global__ __launch_bounds__(256) void preds_kernel(const int* __restrict__ ev,
                                                    int* __restrict__ ibase) {
    __shared__ int su[T_STEPS];
    __shared__ int sl[T_STEPS];
    const int tid = threadIdx.x;
    const int t = blockIdx.x * 256 + tid;
    for (int i = tid; i < T_STEPS; i += 256) { su[i] = ev[i*5]; sl[i] = ev[i*5+1]; }
    __syncthreads();
    const int u = su[t], l = sl[t], p = ev[t*5+2];
    int pu = -1, pl = -1, pp = -1;
    for (int q = t-1; q >= 0; --q) {
        if (pu < 0 && su[q] == u) pu = q;
        if (pl < 0 && sl[q] == l) pl = q;
        if (pp < 0 && sl[q] == p) pp = q;
        if (pu >= 0 && pl >= 0 && pp >= 0) break;
    }
    ibase[IO_PU + t] = pu;
    ibase[IO_PL + t] = pl;
    ibase[IO_PP + t] = pp;
    int lu = 1, ll = 1;
    for (int q = t+1; q < T_STEPS; ++q) if (su[q] == u) { lu = 0; break; }
    for (int q = t+1; q < T_STEPS; ++q) if (sl[q] == l) { ll = 0; break; }
    ibase[IO_LASTU + t] = lu;
    ibase[IO_LASTL + t] = ll;
}

// DAG levels via monotone fixpoint; counting sort into ORDER with OFF[], NLEV.
__global__ __launch_bounds__(1024) void levels_kernel(int* __restrict__ ibase) {
    __shared__ int lev[T_STEPS];
    __shared__ int spu[T_STEPS];
    __shared__ int spl[T_STEPS];
    __shared__ int cnt[T_STEPS + 1];
    __shared__ int changed;
    __shared__ int smax;
    const int tid = threadIdx.x;

    for (int i = tid; i < T_STEPS; i += 1024) {
        spu[i] = ibase[IO_PU + i];
        spl[i] = ibase[IO_PL + i];
        lev[i] = 0;
    }
    if (tid == 0) smax = 0;
    __syncthreads();

    while (true) {
        if (tid == 0) changed = 0;
        __syncthreads();
        for (int i = tid; i < T_STEPS; i += 1024) {
            int nl = 0, a = spu[i], b = spl[i];
            if (a >= 0) nl = lev[a] + 1;
            if (b >= 0) { int v = lev[b] + 1; if (v > nl) nl = v; }
            if (nl > lev[i]) { lev[i] = nl; changed = 1; }
        }
        __syncthreads();
        if (!changed) break;
        __syncthreads();
    }

    for (int i = tid; i <= T_STEPS; i += 1024) cnt[i] = 0;
    __syncthreads();
    for (int i = tid; i < T_STEPS; i += 1024) {
        atomicAdd(&cnt[lev[i]], 1);
        atomicMax(&smax, lev[i]);
    }
    __syncthreads();
    if (tid == 0) {
        int nlev = smax + 1;
        int acc = 0;
        for (int k = 0; k < nlev; ++k) {
            ibase[IO_OFF + k] = acc;
            int c = cnt[k]; cnt[k] = acc; acc += c;
        }
        ibase[IO_OFF + nlev] = acc;
        ibase[IO_NLEV] = nlev;
    }
    __syncthreads();
    for (int i = tid; i < T_STEPS; i += 1024) {
        int pos = atomicAdd(&cnt[lev[i]], 1);
        ibase[IO_ORDER + pos] = i;
    }
}

// KU[t][r] = b_ih_u[r]+b_hh_u[r]+w_ih_u[r][192]*du[t]+sum_j w_ih_u[r][128+j]*kg[know_t][j]
__global__ __launch_bounds__(128) void precomp_k(const int* __restrict__ ev,
    const float* __restrict__ du, const float* __restrict__ dl,
    const float* __restrict__ kg,
    const float* __restrict__ wihu, const float* __restrict__ bihu, const float* __restrict__ bhhu,
    const float* __restrict__ wihl, const float* __restrict__ bihl, const float* __restrict__ bhhl,
    float* __restrict__ KU, float* __restrict__ KL) {
    int t = blockIdx.x;
    int r = threadIdx.x;
    __shared__ float skg[KK];
    int kn = ev[t*5 + 4];
    if (r < KK) skg[r] = kg[kn*KK + r];
    __syncthreads();
    float dut = du[t], dlt = dl[t];
    const float* wu = wihu + r*193;
    const float* wl = wihl + r*193;
    float ku = bihu[r] + bhhu[r] + wu[192]*dut;
    float kl = bihl[r] + bhhl[r] + wl[192]*dlt;
    #pragma unroll
    for (int j = 0; j < KK; ++j) {
        float s = skg[j];
        ku += wu[128+j]*s;
        kl += wl[128+j]*s;
    }
    KU[t*DD + r] = ku;
    KL[t*DD + r] = kl;
}

// Cooperative chain: 256 blocks x 512 threads (1 block/CU). Weights in registers
// once; all DAG levels in one launch with grid.sync() between levels; epilogue
// (scatter-last, Z and ELT build) fused.
__global__ __launch_bounds__(512, 1) void chain_coop(const int* __restrict__ ev,
    const float* __restrict__ emb0,
    const float* __restrict__ wihu, const float* __restrict__ whhu,
    const float* __restrict__ whhl, const float* __restrict__ wihl,
    const float* __restrict__ KU, const float* __restrict__ KL,
    const float* __restrict__ du, const float* __restrict__ pw,
    const float* __restrict__ projb, const float* __restrict__ kg,
    float* __restrict__ NEWU, float* __restrict__ NEWL, float* __restrict__ DRIFT,
    float* __restrict__ Z, float* __restrict__ ELT,
    float* __restrict__ out, int* __restrict__ ibase) {
    cg::grid_group grid = cg::this_grid();
    const int tid  = threadIdx.x;
    const int h    = tid >> 8;      // column half
    const int r    = tid & 255;     // output row
    const int lane = tid & 63;
    const int wid  = tid >> 6;

    // M[r][h*128 .. h*128+127] in registers
    float w[128];
    {
        const float* src;
        if (h == 0) src = (r < 128) ? (wihu + r*193) : (whhl + (r-128)*128);
        else        src = (r < 128) ? (whhu + r*128) : (wihl + (r-128)*193);
        #pragma unroll
        for (int j = 0; j < 128; ++j) w[j] = src[j];
    }

    __shared__ float xs[256];
    __shared__ float partial[512];
    __shared__ float wsum[8];

    const int nlev = ibase[IO_NLEV];
    for (int lv = 0; lv < nlev; ++lv) {
        const int start = ibase[IO_OFF + lv];
        const int end   = ibase[IO_OFF + lv + 1];
        for (int s = start + blockIdx.x; s < end; s += gridDim.x) {
            const int t  = ibase[IO_ORDER + s];
            const int u  = ev[t*5];
            const int l  = ev[t*5 + 1];
            const int pu = ibase[IO_PU + t];
            const int pl = ibase[IO_PL + t];

            float kv = 0.f;
            if (tid < 128) {
                xs[tid] = (pl >= 0) ? NEWL[pl*DD + tid] : emb0[(size_t)(l + NUSERS)*DD + tid];
                kv = KU[t*DD + tid];
            } else if (tid < 256) {
                int d = tid - 128;
                xs[tid] = (pu >= 0) ? NEWU[pu*DD + d] : emb0[(size_t)u*DD + d];
                kv = KL[t*DD + d];
            }
            __syncthreads();                               // B1

            float acc = 0.f;
            {
                const float* xp = xs + h*128;              // wave-uniform -> broadcast
                #pragma unroll
                for (int j = 0; j < 128; ++j) acc += w[j] * xp[j];
            }
            partial[tid] = acc;
            __syncthreads();                               // B2

            float th = 0.f;
            if (tid < 256) {
                float pre = partial[tid] + partial[256 + tid] + kv;
                th = tanhf(pre);
                float ss = th * th;
                #pragma unroll
                for (int o = 32; o > 0; o >>= 1) ss += __shfl_xor(ss, o, 64);
                if (lane == 0) wsum[wid] = ss;
            }
            __syncthreads();                               // B3

            if (tid < 256) {
                float S  = (tid < 128) ? (wsum[0] + wsum[1]) : (wsum[2] + wsum[3]);
                float sf = 1.f / fmaxf(sqrtf(S), 1e-12f);
                float v2 = th * sf;
                float old = (tid < 128) ? xs[128 + tid] : xs[tid - 128];
                if (tid < 128) NEWU[t*DD + tid]       = v2;
                else           NEWL[t*DD + (tid-128)] = v2;
                float dd = v2 - old;
                float s2 = dd * dd;
                #pragma unroll
                for (int o = 32; o > 0; o >>= 1) s2 += __shfl_xor(s2, o, 64);
                if (lane == 0) wsum[4 + wid] = s2;
            }
            __syncthreads();                               // B4
            if (tid == 0)
                DRIFT[t] = (wsum[4] + wsum[5] + wsum[6] + wsum[7]) * (1.f / 128.f);
        }
        __threadfence();
        grid.sync();
    }

    // ---- epilogue: Z, ELT, scatter-last ----
    const int gsz = gridDim.x * blockDim.x;
    const int gid = blockIdx.x * blockDim.x + tid;

    for (int i = gid; i < T_STEPS*320; i += gsz) {
        int t = i / 320, j = i - t*320;
        float zv;
        if (j < 128) {
            int pu = ibase[IO_PU + t];
            int uu = ev[t*5];
            float eu = (pu >= 0) ? NEWU[pu*DD + j] : emb0[(size_t)uu*DD + j];
            zv = eu * (1.f + pw[j]*du[t] + projb[j]);
        } else if (j < 256) {
            int jj = j - 128;
            int pp = ibase[IO_PP + t];
            int pv = ev[t*5 + 2];
            zv = (pp >= 0) ? NEWL[pp*DD + jj] : emb0[(size_t)(pv + NUSERS)*DD + jj];
        } else {
            int kp = ev[t*5 + 3];
            zv = kg[kp*KK + (j - 256)];
        }
        Z[i] = zv;
    }
    for (int i = gid; i < DD*T_STEPS; i += gsz) {     // ELT[d][t], coalesced writes
        int d = i >> 11, t = i & 2047;
        int pl = ibase[IO_PL + t];
        int l  = ev[t*5 + 1];
        ELT[i] = (pl >= 0) ? NEWL[pl*DD + d] : emb0[(size_t)(l + NUSERS)*DD + d];
    }
    for (int i = gid; i < T_STEPS*DD; i += gsz) {     // scatter last-occurrence
        int t = i >> 7, d = i & 127;
        if (ibase[IO_LASTU + t]) out[(size_t)ev[t*5]*DD + d]            = NEWU[i];
        if (ibase[IO_LASTL + t]) out[(size_t)(ev[t*5+1]+NUSERS)*DD + d] = NEWL[i];
    }
}

// Dense GEMM: S[r][t] = sum_{j<320} predw[r][j] * Z[t][j]. Tile 64r x 64t x 32j,
// 256 threads, 4x4 micro-tile, b128 LDS reads.
__global__ __launch_bounds__(256) void pred_dense(const float* __restrict__ predw,
    const float* __restrict__ Z, float* __restrict__ S, int NT, int t0) {
    __shared__ float wT[32][68];
    __shared__ float zT[32][68];
    const int tid = threadIdx.x;
    const int tx = tid & 15, ty = tid >> 4;
    const int r0  = blockIdx.y * 64;
    const int tt0 = blockIdx.x * 64;
    float acc[4][4];
    #pragma unroll
    for (int a = 0; a < 4; ++a)
        #pragma unroll
        for (int b = 0; b < 4; ++b) acc[a][b] = 0.f;

    for (int j0 = 0; j0 < 320; j0 += 32) {
        #pragma unroll
        for (int k = 0; k < 2; ++k) {
            int idx = tid + k*256;
            int rr = idx >> 3;
            int jc = (idx & 7) * 4;
            int rg = r0 + rr; if (rg > PRED_OUT-1) rg = PRED_OUT-1;
            const float4 v = *(const float4*)(predw + (size_t)rg*PRED_IN + j0 + jc);
            wT[jc+0][rr] = v.x; wT[jc+1][rr] = v.y; wT[jc+2][rr] = v.z; wT[jc+3][rr] = v.w;
        }
        #pragma unroll
        for (int k = 0; k < 2; ++k) {
            int idx = tid + k*256;
            int tt = idx >> 3;
            int jc = (idx & 7) * 4;
            const float4 v = *(const float4*)(Z + (size_t)(t0 + tt0 + tt)*320 + j0 + jc);
            zT[jc+0][tt] = v.x; zT[jc+1][tt] = v.y; zT[jc+2][tt] = v.z; zT[jc+3][tt] = v.w;
        }
        __syncthreads();
        #pragma unroll
        for (int j = 0; j < 32; ++j) {
            const float4 wv = *(const float4*)&wT[j][ty*4];
            const float4 zv = *(const float4*)&zT[j][tx*4];
            acc[0][0] += wv.x*zv.x; acc[0][1] += wv.x*zv.y; acc[0][2] += wv.x*zv.z; acc[0][3] += wv.x*zv.w;
            acc[1][0] += wv.y*zv.x; acc[1][1] += wv.y*zv.y; acc[1][2] += wv.y*zv.z; acc[1][3] += wv.y*zv.w;
            acc[2][0] += wv.z*zv.x; acc[2][1] += wv.z*zv.y; acc[2][2] += wv.z*zv.z; acc[2][3] += wv.z*zv.w;
            acc[3][0] += wv.w*zv.x; acc[3][1] += wv.w*zv.y; acc[3][2] += wv.w*zv.z; acc[3][3] += wv.w*zv.w;
        }
        __syncthreads();
    }
    #pragma unroll
    for (int a = 0; a < 4; ++a) {
        int r = r0 + ty*4 + a;
        if (r < PRED_OUT) {
            float4 o; o.x = acc[a][0]; o.y = acc[a][1]; o.z = acc[a][2]; o.w = acc[a][3];
            *(float4*)(S + (size_t)r*NT + tt0 + tx*4) = o;
        }
    }
}

// Row-centric scatter+finalize: one 64-thread block per output row r.
// W_sl/W_su rows loaded coalesced into LDS ONCE; per-t LDS gathers.
__global__ __launch_bounds__(64) void pred_scatter(const int* __restrict__ ev,
    const float* __restrict__ predw, const float* __restrict__ predb,
    const float* __restrict__ kg, const float* __restrict__ S,
    const float* __restrict__ ELT, float* __restrict__ rowp,
    int NT, int t0, int chunk) {
    __shared__ float swsl[NLOCAS];
    __shared__ float swsu[NUSERS];
    const int tid = threadIdx.x;
    const int r = blockIdx.x;
    const float* base = predw + (size_t)r*PRED_IN;
    for (int i = tid; i < NLOCAS; i += 64) swsl[i] = base[320 + i];
    for (int i = tid; i < NUSERS; i += 64) swsu[i] = base[320 + NLOCAS + i];
    __syncthreads();
    const float bias = predb[r];
    const int mode = (r < DD) ? 0 : (r < DD + NLOCAS ? 1 : 2);
    float lsum = 0.f;
    for (int tb = 0; tb < NT; tb += 64) {
        int tloc = tb + tid;
        int t = t0 + tloc;
        int pv = ev[t*5 + 2];
        int uu = ev[t*5 + 0];
        float v = S[(size_t)r*NT + tloc] + bias + swsl[pv] + swsu[uu];
        float tv;
        if (mode == 0)      tv = ELT[r*T_STEPS + t];
        else if (mode == 1) tv = (pv == r - DD) ? 1.f : 0.f;
        else                tv = kg[ev[t*5+4]*KK + (r - DD - NLOCAS)];
        float d = v - tv;
        lsum += d*d;
    }
    #pragma unroll
    for (int o = 32; o > 0; o >>= 1) lsum += __shfl_xor(lsum, o, 64);
    if (tid == 0) rowp[chunk*PRED_OUT + r] = lsum;
}

__global__ __launch_bounds__(256) void final_reduce(const float* __restrict__ rowp,
                                                    const float* __restrict__ drift,
                                                    float* __restrict__ out, int nchunk) {
    int tid = threadIdx.x;
    float s = 0.f;
    for (int i = tid; i < nchunk*PRED_OUT; i += 256) s += rowp[i];
    s *= (1.0f / PRED_OUT);
    for (int i = tid; i < T_STEPS; i += 256) s += drift[i];
    #pragma unroll
    for (int o = 32; o > 0; o >>= 1) s += __shfl_xor(s, o, 64);
    __shared__ float red[4];
    if ((tid & 63) == 0) red[tid >> 6] = s;
    __syncthreads();
    // each red[w] holds its wave's partial sum; the sum of the four IS the total
    if (tid == 0) out[OUT_EMB] = red[0] + red[1] + red[2] + red[3];
}

extern "C" void kernel_launch(void* const* d_in, const int* in_sizes, int n_in,
                              void* d_out, int out_size, void* d_ws, size_t ws_size,
                              hipStream_t stream) {
    const float* emb_in = (const float*)d_in[0];
    const int*   ev     = (const int*)  d_in[1];
    const float* du     = (const float*)d_in[2];
    const float* dl     = (const float*)d_in[3];
    const float* kg     = (const float*)d_in[4];
    const float* wihu   = (const float*)d_in[5];
    const float* whhu   = (const float*)d_in[6];
    const float* bihu   = (const float*)d_in[7];
    const float* bhhu   = (const float*)d_in[8];
    const float* wihl   = (const float*)d_in[9];
    const float* whhl   = (const float*)d_in[10];
    const float* bihl   = (const float*)d_in[11];
    const float* bhhl   = (const float*)d_in[12];
    const float* projw  = (const float*)d_in[13];
    const float* projb  = (const float*)d_in[14];
    const float* predw  = (const float*)d_in[15];
    const float* predb  = (const float*)d_in[16];

    float* out = (float*)d_out;
    float* ws  = (float*)d_ws;
    float* NEWU  = ws + WS_NEWU;
    float* NEWL  = ws + WS_NEWL;
    float* KU    = ws + WS_KU;
    float* KL    = ws + WS_KL;
    float* Z     = ws + WS_Z;
    float* ELT   = ws + WS_ELT;
    float* DRIFT = ws + WS_DRIFT;
    float* ROWP  = ws + WS_ROWP;
    float* S     = ws + WS_S;
    int*   ibase = (int*)(ws + WS_INT);

    // choose t-chunk so S fits in ws
    long avail = (long)(ws_size / 4) - WS_S;
    int NT = 2048;
    while (NT > 64 && (long)PRED_OUT * NT > avail) NT >>= 1;
    int nchunk = T_STEPS / NT;

    init_kernel<<<2048, 256, 0, stream>>>(emb_in, out);
    preds_kernel<<<T_STEPS/256, 256, 0, stream>>>(ev, ibase);
    levels_kernel<<<1, 1024, 0, stream>>>(ibase);
    precomp_k<<<T_STEPS, 128, 0, stream>>>(ev, du, dl, kg, wihu, bihu, bhhu,
                                           wihl, bihl, bhhl, KU, KL);
    {
        const int* a_ev = ev; const float* a_emb0 = emb_in;
        const float* a_wihu = wihu; const float* a_whhu = whhu;
        const float* a_whhl = whhl; const float* a_wihl = wihl;
        const float* a_KU = KU; const float* a_KL = KL;
        const float* a_du = du; const float* a_pw = projw;
        const float* a_projb = projb; const float* a_kg = kg;
        float* a_NEWU = NEWU; float* a_NEWL = NEWL; float* a_DRIFT = DRIFT;
        float* a_Z = Z; float* a_ELT = ELT; float* a_out = out;
        int* a_ibase = ibase;
        void* args[] = {(void*)&a_ev, (void*)&a_emb0, (void*)&a_wihu, (void*)&a_whhu,
                        (void*)&a_whhl, (void*)&a_wihl, (void*)&a_KU, (void*)&a_KL,
                        (void*)&a_du, (void*)&a_pw, (void*)&a_projb, (void*)&a_kg,
                        (void*)&a_NEWU, (void*)&a_NEWL, (void*)&a_DRIFT,
                        (void*)&a_Z, (void*)&a_ELT, (void*)&a_out, (void*)&a_ibase};
        hipLaunchCooperativeKernel((void*)chain_coop, dim3(256), dim3(512),
                                   args, 0, stream);
    }
    for (int c = 0; c < nchunk; ++c) {
        int t0 = c * NT;
        pred_dense<<<dim3(NT/64, 66), 256, 0, stream>>>(predw, Z, S, NT, t0);
        pred_scatter<<<PRED_OUT, 64, 0, stream>>>(ev, predw, predb, kg, S, ELT,
                                                  ROWP, NT, t0, c);
    }
    final_reduce<<<1, 256, 0, stream>>>(ROWP, DRIFT, out, nchunk);
}

// Round 6
// 601.364 us; speedup vs baseline: 7.6729x; 1.7044x over previous
//
#include <hip/hip_runtime.h>
#include <hip/hip_cooperative_groups.h>
namespace cg = cooperative_groups;

#define T_STEPS 2048
#define NUSERS 4000
#define NLOCAS 4000
#define DD 128
#define KK 64
#define PRED_OUT 4192
#define PRED_IN 8256
#define OUT_EMB 1024000   // 8000*128

// ---- ws layout (float offsets) ----
#define WS_NEWU   0          // 262144
#define WS_NEWL   262144
#define WS_KU     524288
#define WS_KL     786432
#define WS_Z      1048576    // 2048*320
#define WS_ELT    1703936    // 128*2048
#define WS_DRIFT  1966080    // 2048
#define WS_ROWP   1968128    // up to 32*4192
#define WS_INT    2107392    // 14400 ints
#define WS_S      2121792    // 4192*NT floats
// ---- int offsets within WS_INT ----
#define IO_PU     0
#define IO_PL     2048
#define IO_PP     4096
#define IO_LASTU  6144
#define IO_LASTL  8192
#define IO_ORDER  10240
#define IO_OFF    12288      // 2049 entries
#define IO_NLEV   14337

__global__ __launch_bounds__(256) void init_kernel(const float* __restrict__ emb_in,
                                                   float* __restrict__ out) {
    int i = blockIdx.x * blockDim.x + threadIdx.x;
    int stride = gridDim.x * blockDim.x;
    for (; i < OUT_EMB; i += stride) out[i] = emb_in[i];
}

// Wave-parallel predecessor scan: one 64-lane wave per step t.
// Lane k probes q = t-1-k-64*round; ballot finds the 64-window hit; rounds
// descend in q so the first nonzero ballot's lowest lane = max predecessor.
__global__ __launch_bounds__(256) void preds_kernel(const int* __restrict__ ev,
                                                    int* __restrict__ ibase) {
    __shared__ int su[T_STEPS];
    __shared__ int sl[T_STEPS];
    const int tid  = threadIdx.x;
    const int lane = tid & 63;
    const int wid  = tid >> 6;
    for (int i = tid; i < T_STEPS; i += 256) { su[i] = ev[i*5]; sl[i] = ev[i*5+1]; }
    __syncthreads();

    const int t = blockIdx.x * 4 + wid;
    const int u = su[t], l = sl[t], p = ev[t*5 + 2];

    int pu = -1, pl = -1, pp = -1;
    {
        int round = 0;
        while (true) {
            const int q = t - 1 - lane - (round << 6);
            const int squ = (q >= 0) ? su[q] : -1;
            const int sql = (q >= 0) ? sl[q] : -1;
            if (pu < 0) {
                unsigned long long b = __ballot(squ == u);
                if (b) pu = t - 1 - (__ffsll((unsigned long long)b) - 1) - (round << 6);
            }
            if (pl < 0) {
                unsigned long long b = __ballot(sql == l);
                if (b) pl = t - 1 - (__ffsll((unsigned long long)b) - 1) - (round << 6);
            }
            if (pp < 0) {
                unsigned long long b = __ballot(sql == p);
                if (b) pp = t - 1 - (__ffsll((unsigned long long)b) - 1) - (round << 6);
            }
            ++round;
            if ((pu >= 0 && pl >= 0 && pp >= 0) || (t - 1 - (round << 6) < 0)) break;
        }
    }

    int lastu = 1, lastl = 1;
    {
        int round = 0;
        while (true) {
            const int q = t + 1 + lane + (round << 6);
            const int squ = (q < T_STEPS) ? su[q] : -1;
            const int sql = (q < T_STEPS) ? sl[q] : -1;
            if (lastu && __ballot(squ == u)) lastu = 0;
            if (lastl && __ballot(sql == l)) lastl = 0;
            ++round;
            if ((!lastu && !lastl) || (t + 1 + (round << 6) >= T_STEPS)) break;
        }
    }

    if (lane == 0) {
        ibase[IO_PU + t] = pu;
        ibase[IO_PL + t] = pl;
        ibase[IO_PP + t] = pp;
        ibase[IO_LASTU + t] = lastu;
        ibase[IO_LASTL + t] = lastl;
    }
}

// DAG levels via monotone fixpoint; counting sort into ORDER with OFF[], NLEV.
__global__ __launch_bounds__(1024) void levels_kernel(int* __restrict__ ibase) {
    __shared__ int lev[T_STEPS];
    __shared__ int spu[T_STEPS];
    __shared__ int spl[T_STEPS];
    __shared__ int cnt[T_STEPS + 1];
    __shared__ int changed;
    __shared__ int smax;
    const int tid = threadIdx.x;

    for (int i = tid; i < T_STEPS; i += 1024) {
        spu[i] = ibase[IO_PU + i];
        spl[i] = ibase[IO_PL + i];
        lev[i] = 0;
    }
    if (tid == 0) smax = 0;
    __syncthreads();

    while (true) {
        if (tid == 0) changed = 0;
        __syncthreads();
        for (int i = tid; i < T_STEPS; i += 1024) {
            int nl = 0, a = spu[i], b = spl[i];
            if (a >= 0) nl = lev[a] + 1;
            if (b >= 0) { int v = lev[b] + 1; if (v > nl) nl = v; }
            if (nl > lev[i]) { lev[i] = nl; changed = 1; }
        }
        __syncthreads();
        if (!changed) break;
        __syncthreads();
    }

    for (int i = tid; i <= T_STEPS; i += 1024) cnt[i] = 0;
    __syncthreads();
    for (int i = tid; i < T_STEPS; i += 1024) {
        atomicAdd(&cnt[lev[i]], 1);
        atomicMax(&smax, lev[i]);
    }
    __syncthreads();
    if (tid == 0) {
        int nlev = smax + 1;
        int acc = 0;
        for (int k = 0; k < nlev; ++k) {
            ibase[IO_OFF + k] = acc;
            int c = cnt[k]; cnt[k] = acc; acc += c;
        }
        ibase[IO_OFF + nlev] = acc;
        ibase[IO_NLEV] = nlev;
    }
    __syncthreads();
    for (int i = tid; i < T_STEPS; i += 1024) {
        int pos = atomicAdd(&cnt[lev[i]], 1);
        ibase[IO_ORDER + pos] = i;
    }
}

// KU[t][r] = b_ih_u[r]+b_hh_u[r]+w_ih_u[r][192]*du[t]+sum_j w_ih_u[r][128+j]*kg[know_t][j]
__global__ __launch_bounds__(128) void precomp_k(const int* __restrict__ ev,
    const float* __restrict__ du, const float* __restrict__ dl,
    const float* __restrict__ kg,
    const float* __restrict__ wihu, const float* __restrict__ bihu, const float* __restrict__ bhhu,
    const float* __restrict__ wihl, const float* __restrict__ bihl, const float* __restrict__ bhhl,
    float* __restrict__ KU, float* __restrict__ KL) {
    int t = blockIdx.x;
    int r = threadIdx.x;
    __shared__ float skg[KK];
    int kn = ev[t*5 + 4];
    if (r < KK) skg[r] = kg[kn*KK + r];
    __syncthreads();
    float dut = du[t], dlt = dl[t];
    const float* wu = wihu + r*193;
    const float* wl = wihl + r*193;
    float ku = bihu[r] + bhhu[r] + wu[192]*dut;
    float kl = bihl[r] + bhhl[r] + wl[192]*dlt;
    #pragma unroll
    for (int j = 0; j < KK; ++j) {
        float s = skg[j];
        ku += wu[128+j]*s;
        kl += wl[128+j]*s;
    }
    KU[t*DD + r] = ku;
    KL[t*DD + r] = kl;
}

// Cooperative chain: 256 blocks x 512 threads (1 block/CU). Weights in registers
// once; all DAG levels in one launch with grid.sync() between levels; epilogue
// (scatter-last, Z and ELT build) fused.
__global__ __launch_bounds__(512, 1) void chain_coop(const int* __restrict__ ev,
    const float* __restrict__ emb0,
    const float* __restrict__ wihu, const float* __restrict__ whhu,
    const float* __restrict__ whhl, const float* __restrict__ wihl,
    const float* __restrict__ KU, const float* __restrict__ KL,
    const float* __restrict__ du, const float* __restrict__ pw,
    const float* __restrict__ projb, const float* __restrict__ kg,
    float* __restrict__ NEWU, float* __restrict__ NEWL, float* __restrict__ DRIFT,
    float* __restrict__ Z, float* __restrict__ ELT,
    float* __restrict__ out, int* __restrict__ ibase) {
    cg::grid_group grid = cg::this_grid();
    const int tid  = threadIdx.x;
    const int h    = tid >> 8;      // column half
    const int r    = tid & 255;     // output row
    const int lane = tid & 63;
    const int wid  = tid >> 6;

    // M[r][h*128 .. h*128+127] in registers
    float w[128];
    {
        const float* src;
        if (h == 0) src = (r < 128) ? (wihu + r*193) : (whhl + (r-128)*128);
        else        src = (r < 128) ? (whhu + r*128) : (wihl + (r-128)*193);
        #pragma unroll
        for (int j = 0; j < 128; ++j) w[j] = src[j];
    }

    __shared__ float xs[256];
    __shared__ float partial[512];
    __shared__ float wsum[8];

    const int nlev = ibase[IO_NLEV];
    for (int lv = 0; lv < nlev; ++lv) {
        const int start = ibase[IO_OFF + lv];
        const int end   = ibase[IO_OFF + lv + 1];
        for (int s = start + blockIdx.x; s < end; s += gridDim.x) {
            const int t  = ibase[IO_ORDER + s];
            const int u  = ev[t*5];
            const int l  = ev[t*5 + 1];
            const int pu = ibase[IO_PU + t];
            const int pl = ibase[IO_PL + t];

            float kv = 0.f;
            if (tid < 128) {
                xs[tid] = (pl >= 0) ? NEWL[pl*DD + tid] : emb0[(size_t)(l + NUSERS)*DD + tid];
                kv = KU[t*DD + tid];
            } else if (tid < 256) {
                int d = tid - 128;
                xs[tid] = (pu >= 0) ? NEWU[pu*DD + d] : emb0[(size_t)u*DD + d];
                kv = KL[t*DD + d];
            }
            __syncthreads();                               // B1

            float acc = 0.f;
            {
                const float* xp = xs + h*128;              // wave-uniform -> broadcast
                #pragma unroll
                for (int j = 0; j < 128; ++j) acc += w[j] * xp[j];
            }
            partial[tid] = acc;
            __syncthreads();                               // B2

            float th = 0.f;
            if (tid < 256) {
                float pre = partial[tid] + partial[256 + tid] + kv;
                th = tanhf(pre);
                float ss = th * th;
                #pragma unroll
                for (int o = 32; o > 0; o >>= 1) ss += __shfl_xor(ss, o, 64);
                if (lane == 0) wsum[wid] = ss;
            }
            __syncthreads();                               // B3

            if (tid < 256) {
                float S  = (tid < 128) ? (wsum[0] + wsum[1]) : (wsum[2] + wsum[3]);
                float sf = 1.f / fmaxf(sqrtf(S), 1e-12f);
                float v2 = th * sf;
                float old = (tid < 128) ? xs[128 + tid] : xs[tid - 128];
                if (tid < 128) NEWU[t*DD + tid]       = v2;
                else           NEWL[t*DD + (tid-128)] = v2;
                float dd = v2 - old;
                float s2 = dd * dd;
                #pragma unroll
                for (int o = 32; o > 0; o >>= 1) s2 += __shfl_xor(s2, o, 64);
                if (lane == 0) wsum[4 + wid] = s2;
            }
            __syncthreads();                               // B4
            if (tid == 0)
                DRIFT[t] = (wsum[4] + wsum[5] + wsum[6] + wsum[7]) * (1.f / 128.f);
        }
        __threadfence();
        grid.sync();
    }

    // ---- epilogue: Z, ELT, scatter-last ----
    const int gsz = gridDim.x * blockDim.x;
    const int gid = blockIdx.x * blockDim.x + tid;

    for (int i = gid; i < T_STEPS*320; i += gsz) {
        int t = i / 320, j = i - t*320;
        float zv;
        if (j < 128) {
            int pu = ibase[IO_PU + t];
            int uu = ev[t*5];
            float eu = (pu >= 0) ? NEWU[pu*DD + j] : emb0[(size_t)uu*DD + j];
            zv = eu * (1.f + pw[j]*du[t] + projb[j]);
        } else if (j < 256) {
            int jj = j - 128;
            int pp = ibase[IO_PP + t];
            int pv = ev[t*5 + 2];
            zv = (pp >= 0) ? NEWL[pp*DD + jj] : emb0[(size_t)(pv + NUSERS)*DD + jj];
        } else {
            int kp = ev[t*5 + 3];
            zv = kg[kp*KK + (j - 256)];
        }
        Z[i] = zv;
    }
    for (int i = gid; i < DD*T_STEPS; i += gsz) {     // ELT[d][t], coalesced writes
        int d = i >> 11, t = i & 2047;
        int pl = ibase[IO_PL + t];
        int l  = ev[t*5 + 1];
        ELT[i] = (pl >= 0) ? NEWL[pl*DD + d] : emb0[(size_t)(l + NUSERS)*DD + d];
    }
    for (int i = gid; i < T_STEPS*DD; i += gsz) {     // scatter last-occurrence
        int t = i >> 7, d = i & 127;
        if (ibase[IO_LASTU + t]) out[(size_t)ev[t*5]*DD + d]            = NEWU[i];
        if (ibase[IO_LASTL + t]) out[(size_t)(ev[t*5+1]+NUSERS)*DD + d] = NEWL[i];
    }
}

// Dense GEMM: S[r][t] = sum_{j<320} predw[r][j] * Z[t][j]. Tile 64r x 64t x 32j,
// 256 threads, 4x4 micro-tile, b128 LDS reads.
__global__ __launch_bounds__(256) void pred_dense(const float* __restrict__ predw,
    const float* __restrict__ Z, float* __restrict__ S, int NT, int t0) {
    __shared__ float wT[32][68];
    __shared__ float zT[32][68];
    const int tid = threadIdx.x;
    const int tx = tid & 15, ty = tid >> 4;
    const int r0  = blockIdx.y * 64;
    const int tt0 = blockIdx.x * 64;
    float acc[4][4];
    #pragma unroll
    for (int a = 0; a < 4; ++a)
        #pragma unroll
        for (int b = 0; b < 4; ++b) acc[a][b] = 0.f;

    for (int j0 = 0; j0 < 320; j0 += 32) {
        #pragma unroll
        for (int k = 0; k < 2; ++k) {
            int idx = tid + k*256;
            int rr = idx >> 3;
            int jc = (idx & 7) * 4;
            int rg = r0 + rr; if (rg > PRED_OUT-1) rg = PRED_OUT-1;
            const float4 v = *(const float4*)(predw + (size_t)rg*PRED_IN + j0 + jc);
            wT[jc+0][rr] = v.x; wT[jc+1][rr] = v.y; wT[jc+2][rr] = v.z; wT[jc+3][rr] = v.w;
        }
        #pragma unroll
        for (int k = 0; k < 2; ++k) {
            int idx = tid + k*256;
            int tt = idx >> 3;
            int jc = (idx & 7) * 4;
            const float4 v = *(const float4*)(Z + (size_t)(t0 + tt0 + tt)*320 + j0 + jc);
            zT[jc+0][tt] = v.x; zT[jc+1][tt] = v.y; zT[jc+2][tt] = v.z; zT[jc+3][tt] = v.w;
        }
        __syncthreads();
        #pragma unroll
        for (int j = 0; j < 32; ++j) {
            const float4 wv = *(const float4*)&wT[j][ty*4];
            const float4 zv = *(const float4*)&zT[j][tx*4];
            acc[0][0] += wv.x*zv.x; acc[0][1] += wv.x*zv.y; acc[0][2] += wv.x*zv.z; acc[0][3] += wv.x*zv.w;
            acc[1][0] += wv.y*zv.x; acc[1][1] += wv.y*zv.y; acc[1][2] += wv.y*zv.z; acc[1][3] += wv.y*zv.w;
            acc[2][0] += wv.z*zv.x; acc[2][1] += wv.z*zv.y; acc[2][2] += wv.z*zv.z; acc[2][3] += wv.z*zv.w;
            acc[3][0] += wv.w*zv.x; acc[3][1] += wv.w*zv.y; acc[3][2] += wv.w*zv.z; acc[3][3] += wv.w*zv.w;
        }
        __syncthreads();
    }
    #pragma unroll
    for (int a = 0; a < 4; ++a) {
        int r = r0 + ty*4 + a;
        if (r < PRED_OUT) {
            float4 o; o.x = acc[a][0]; o.y = acc[a][1]; o.z = acc[a][2]; o.w = acc[a][3];
            *(float4*)(S + (size_t)r*NT + tt0 + tx*4) = o;
        }
    }
}

// Row-centric scatter+finalize: one 64-thread block per output row r.
// W_sl/W_su rows loaded coalesced into LDS ONCE; per-t LDS gathers.
__global__ __launch_bounds__(64) void pred_scatter(const int* __restrict__ ev,
    const float* __restrict__ predw, const float* __restrict__ predb,
    const float* __restrict__ kg, const float* __restrict__ S,
    const float* __restrict__ ELT, float* __restrict__ rowp,
    int NT, int t0, int chunk) {
    __shared__ float swsl[NLOCAS];
    __shared__ float swsu[NUSERS];
    const int tid = threadIdx.x;
    const int r = blockIdx.x;
    const float* base = predw + (size_t)r*PRED_IN;
    for (int i = tid; i < NLOCAS; i += 64) swsl[i] = base[320 + i];
    for (int i = tid; i < NUSERS; i += 64) swsu[i] = base[320 + NLOCAS + i];
    __syncthreads();
    const float bias = predb[r];
    const int mode = (r < DD) ? 0 : (r < DD + NLOCAS ? 1 : 2);
    float lsum = 0.f;
    for (int tb = 0; tb < NT; tb += 64) {
        int tloc = tb + tid;
        int t = t0 + tloc;
        int pv = ev[t*5 + 2];
        int uu = ev[t*5 + 0];
        float v = S[(size_t)r*NT + tloc] + bias + swsl[pv] + swsu[uu];
        float tv;
        if (mode == 0)      tv = ELT[r*T_STEPS + t];
        else if (mode == 1) tv = (pv == r - DD) ? 1.f : 0.f;
        else                tv = kg[ev[t*5+4]*KK + (r - DD - NLOCAS)];
        float d = v - tv;
        lsum += d*d;
    }
    #pragma unroll
    for (int o = 32; o > 0; o >>= 1) lsum += __shfl_xor(lsum, o, 64);
    if (tid == 0) rowp[chunk*PRED_OUT + r] = lsum;
}

__global__ __launch_bounds__(256) void final_reduce(const float* __restrict__ rowp,
                                                    const float* __restrict__ drift,
                                                    float* __restrict__ out, int nchunk) {
    int tid = threadIdx.x;
    float s = 0.f;
    for (int i = tid; i < nchunk*PRED_OUT; i += 256) s += rowp[i];
    s *= (1.0f / PRED_OUT);
    for (int i = tid; i < T_STEPS; i += 256) s += drift[i];
    #pragma unroll
    for (int o = 32; o > 0; o >>= 1) s += __shfl_xor(s, o, 64);
    __shared__ float red[4];
    if ((tid & 63) == 0) red[tid >> 6] = s;
    __syncthreads();
    // each red[w] holds its wave's partial sum; the sum of the four IS the total
    if (tid == 0) out[OUT_EMB] = red[0] + red[1] + red[2] + red[3];
}

extern "C" void kernel_launch(void* const* d_in, const int* in_sizes, int n_in,
                              void* d_out, int out_size, void* d_ws, size_t ws_size,
                              hipStream_t stream) {
    const float* emb_in = (const float*)d_in[0];
    const int*   ev     = (const int*)  d_in[1];
    const float* du     = (const float*)d_in[2];
    const float* dl     = (const float*)d_in[3];
    const float* kg     = (const float*)d_in[4];
    const float* wihu   = (const float*)d_in[5];
    const float* whhu   = (const float*)d_in[6];
    const float* bihu   = (const float*)d_in[7];
    const float* bhhu   = (const float*)d_in[8];
    const float* wihl   = (const float*)d_in[9];
    const float* whhl   = (const float*)d_in[10];
    const float* bihl   = (const float*)d_in[11];
    const float* bhhl   = (const float*)d_in[12];
    const float* projw  = (const float*)d_in[13];
    const float* projb  = (const float*)d_in[14];
    const float* predw  = (const float*)d_in[15];
    const float* predb  = (const float*)d_in[16];

    float* out = (float*)d_out;
    float* ws  = (float*)d_ws;
    float* NEWU  = ws + WS_NEWU;
    float* NEWL  = ws + WS_NEWL;
    float* KU    = ws + WS_KU;
    float* KL    = ws + WS_KL;
    float* Z     = ws + WS_Z;
    float* ELT   = ws + WS_ELT;
    float* DRIFT = ws + WS_DRIFT;
    float* ROWP  = ws + WS_ROWP;
    float* S     = ws + WS_S;
    int*   ibase = (int*)(ws + WS_INT);

    // choose t-chunk so S fits in ws
    long avail = (long)(ws_size / 4) - WS_S;
    int NT = 2048;
    while (NT > 64 && (long)PRED_OUT * NT > avail) NT >>= 1;
    int nchunk = T_STEPS / NT;

    init_kernel<<<2048, 256, 0, stream>>>(emb_in, out);
    preds_kernel<<<T_STEPS/4, 256, 0, stream>>>(ev, ibase);
    levels_kernel<<<1, 1024, 0, stream>>>(ibase);
    precomp_k<<<T_STEPS, 128, 0, stream>>>(ev, du, dl, kg, wihu, bihu, bhhu,
                                           wihl, bihl, bhhl, KU, KL);
    {
        const int* a_ev = ev; const float* a_emb0 = emb_in;
        const float* a_wihu = wihu; const float* a_whhu = whhu;
        const float* a_whhl = whhl; const float* a_wihl = wihl;
        const float* a_KU = KU; const float* a_KL = KL;
        const float* a_du = du; const float* a_pw = projw;
        const float* a_projb = projb; const float* a_kg = kg;
        float* a_NEWU = NEWU; float* a_NEWL = NEWL; float* a_DRIFT = DRIFT;
        float* a_Z = Z; float* a_ELT = ELT; float* a_out = out;
        int* a_ibase = ibase;
        void* args[] = {(void*)&a_ev, (void*)&a_emb0, (void*)&a_wihu, (void*)&a_whhu,
                        (void*)&a_whhl, (void*)&a_wihl, (void*)&a_KU, (void*)&a_KL,
                        (void*)&a_du, (void*)&a_pw, (void*)&a_projb, (void*)&a_kg,
                        (void*)&a_NEWU, (void*)&a_NEWL, (void*)&a_DRIFT,
                        (void*)&a_Z, (void*)&a_ELT, (void*)&a_out, (void*)&a_ibase};
        hipLaunchCooperativeKernel((void*)chain_coop, dim3(256), dim3(512),
                                   args, 0, stream);
    }
    for (int c = 0; c < nchunk; ++c) {
        int t0 = c * NT;
        pred_dense<<<dim3(NT/64, 66), 256, 0, stream>>>(predw, Z, S, NT, t0);
        pred_scatter<<<PRED_OUT, 64, 0, stream>>>(ev, predw, predb, kg, S, ELT,
                                                  ROWP, NT, t0, c);
    }
    final_reduce<<<1, 256, 0, stream>>>(ROWP, DRIFT, out, nchunk);
}

// Round 7
// 311.713 us; speedup vs baseline: 14.8027x; 1.9292x over previous
//
#include <hip/hip_runtime.h>

#define T_STEPS 2048
#define NUSERS 4000
#define NLOCAS 4000
#define DD 128
#define KK 64
#define PRED_OUT 4192
#define PRED_IN 8256
#define OUT_EMB 1024000   // 8000*128
#define TAIL_LV 16

// ---- ws layout (float offsets) ----
#define WS_NEWU   0          // 262144
#define WS_NEWL   262144
#define WS_KU     524288
#define WS_KL     786432
#define WS_Z      1048576    // 2048*320
#define WS_ELT    1703936    // 128*2048
#define WS_DRIFT  1966080    // 2048
#define WS_ROWP   1968128    // up to 32*4192
#define WS_INT    2107392    // 14400 ints
#define WS_S      2121792    // 4192*NT floats
// ---- int offsets within WS_INT ----
#define IO_PU     0
#define IO_PL     2048
#define IO_PP     4096
#define IO_LASTU  6144
#define IO_LASTL  8192
#define IO_ORDER  10240
#define IO_OFF    12288      // 2049 entries
#define IO_NLEV   14337

__global__ __launch_bounds__(256) void init_kernel(const float* __restrict__ emb_in,
                                                   float* __restrict__ out) {
    int i = blockIdx.x * blockDim.x + threadIdx.x;
    int stride = gridDim.x * blockDim.x;
    for (; i < OUT_EMB; i += stride) out[i] = emb_in[i];
}

// Wave-parallel predecessor scan: one 64-lane wave per step t.
__global__ __launch_bounds__(256) void preds_kernel(const int* __restrict__ ev,
                                                    int* __restrict__ ibase) {
    __shared__ int su[T_STEPS];
    __shared__ int sl[T_STEPS];
    const int tid  = threadIdx.x;
    const int lane = tid & 63;
    const int wid  = tid >> 6;
    for (int i = tid; i < T_STEPS; i += 256) { su[i] = ev[i*5]; sl[i] = ev[i*5+1]; }
    __syncthreads();

    const int t = blockIdx.x * 4 + wid;
    const int u = su[t], l = sl[t], p = ev[t*5 + 2];

    int pu = -1, pl = -1, pp = -1;
    {
        int round = 0;
        while (true) {
            const int q = t - 1 - lane - (round << 6);
            const int squ = (q >= 0) ? su[q] : -1;
            const int sql = (q >= 0) ? sl[q] : -1;
            if (pu < 0) {
                unsigned long long b = __ballot(squ == u);
                if (b) pu = t - 1 - (__ffsll(b) - 1) - (round << 6);
            }
            if (pl < 0) {
                unsigned long long b = __ballot(sql == l);
                if (b) pl = t - 1 - (__ffsll(b) - 1) - (round << 6);
            }
            if (pp < 0) {
                unsigned long long b = __ballot(sql == p);
                if (b) pp = t - 1 - (__ffsll(b) - 1) - (round << 6);
            }
            ++round;
            if ((pu >= 0 && pl >= 0 && pp >= 0) || (t - 1 - (round << 6) < 0)) break;
        }
    }

    int lastu = 1, lastl = 1;
    {
        int round = 0;
        while (true) {
            const int q = t + 1 + lane + (round << 6);
            const int squ = (q < T_STEPS) ? su[q] : -1;
            const int sql = (q < T_STEPS) ? sl[q] : -1;
            if (lastu && __ballot(squ == u)) lastu = 0;
            if (lastl && __ballot(sql == l)) lastl = 0;
            ++round;
            if ((!lastu && !lastl) || (t + 1 + (round << 6) >= T_STEPS)) break;
        }
    }

    if (lane == 0) {
        ibase[IO_PU + t] = pu;
        ibase[IO_PL + t] = pl;
        ibase[IO_PP + t] = pp;
        ibase[IO_LASTU + t] = lastu;
        ibase[IO_LASTL + t] = lastl;
    }
}

// DAG levels via monotone fixpoint; counting sort into ORDER with OFF[], NLEV.
__global__ __launch_bounds__(1024) void levels_kernel(int* __restrict__ ibase) {
    __shared__ int lev[T_STEPS];
    __shared__ int spu[T_STEPS];
    __shared__ int spl[T_STEPS];
    __shared__ int cnt[T_STEPS + 1];
    __shared__ int changed;
    __shared__ int smax;
    const int tid = threadIdx.x;

    for (int i = tid; i < T_STEPS; i += 1024) {
        spu[i] = ibase[IO_PU + i];
        spl[i] = ibase[IO_PL + i];
        lev[i] = 0;
    }
    if (tid == 0) smax = 0;
    __syncthreads();

    while (true) {
        if (tid == 0) changed = 0;
        __syncthreads();
        for (int i = tid; i < T_STEPS; i += 1024) {
            int nl = 0, a = spu[i], b = spl[i];
            if (a >= 0) nl = lev[a] + 1;
            if (b >= 0) { int v = lev[b] + 1; if (v > nl) nl = v; }
            if (nl > lev[i]) { lev[i] = nl; changed = 1; }
        }
        __syncthreads();
        if (!changed) break;
        __syncthreads();
    }

    for (int i = tid; i <= T_STEPS; i += 1024) cnt[i] = 0;
    __syncthreads();
    for (int i = tid; i < T_STEPS; i += 1024) {
        atomicAdd(&cnt[lev[i]], 1);
        atomicMax(&smax, lev[i]);
    }
    __syncthreads();
    if (tid == 0) {
        int nlev = smax + 1;
        int acc = 0;
        for (int k = 0; k < nlev; ++k) {
            ibase[IO_OFF + k] = acc;
            int c = cnt[k]; cnt[k] = acc; acc += c;
        }
        ibase[IO_OFF + nlev] = acc;
        ibase[IO_NLEV] = nlev;
        // pad OFF up to TAIL_LV+1 so sweeps beyond nlev see empty ranges
        for (int k = nlev + 1; k <= TAIL_LV; ++k) ibase[IO_OFF + k] = acc;
    }
    __syncthreads();
    for (int i = tid; i < T_STEPS; i += 1024) {
        int pos = atomicAdd(&cnt[lev[i]], 1);
        ibase[IO_ORDER + pos] = i;
    }
}

// KU[t][r] = b_ih_u[r]+b_hh_u[r]+w_ih_u[r][192]*du[t]+sum_j w_ih_u[r][128+j]*kg[know_t][j]
__global__ __launch_bounds__(128) void precomp_k(const int* __restrict__ ev,
    const float* __restrict__ du, const float* __restrict__ dl,
    const float* __restrict__ kg,
    const float* __restrict__ wihu, const float* __restrict__ bihu, const float* __restrict__ bhhu,
    const float* __restrict__ wihl, const float* __restrict__ bihl, const float* __restrict__ bhhl,
    float* __restrict__ KU, float* __restrict__ KL) {
    int t = blockIdx.x;
    int r = threadIdx.x;
    __shared__ float skg[KK];
    int kn = ev[t*5 + 4];
    if (r < KK) skg[r] = kg[kn*KK + r];
    __syncthreads();
    float dut = du[t], dlt = dl[t];
    const float* wu = wihu + r*193;
    const float* wl = wihl + r*193;
    float ku = bihu[r] + bhhu[r] + wu[192]*dut;
    float kl = bihl[r] + bhhl[r] + wl[192]*dlt;
    #pragma unroll
    for (int j = 0; j < KK; ++j) {
        float s = skg[j];
        ku += wu[128+j]*s;
        kl += wl[128+j]*s;
    }
    KU[t*DD + r] = ku;
    KL[t*DD + r] = kl;
}

// One DAG level per launch (levels 0..TAIL_LV-1). 256 blocks x 512 threads.
// Cross-level ordering via kernel boundaries on the stream.
__global__ __launch_bounds__(512) void chain_sweep(int lv, const int* __restrict__ ev,
    const float* __restrict__ emb0,
    const float* __restrict__ wihu, const float* __restrict__ whhu,
    const float* __restrict__ whhl, const float* __restrict__ wihl,
    const float* __restrict__ KU, const float* __restrict__ KL,
    float* __restrict__ NEWU, float* __restrict__ NEWL, float* __restrict__ DRIFT,
    const int* __restrict__ ibase) {
    const int start = ibase[IO_OFF + lv];
    const int end   = ibase[IO_OFF + lv + 1];
    if ((int)blockIdx.x >= end - start) return;

    const int tid  = threadIdx.x;
    const int h    = tid >> 8;
    const int r    = tid & 255;
    const int lane = tid & 63;
    const int wid  = tid >> 6;

    float w[128];
    {
        const float* src;
        if (h == 0) src = (r < 128) ? (wihu + r*193) : (whhl + (r-128)*128);
        else        src = (r < 128) ? (whhu + r*128) : (wihl + (r-128)*193);
        #pragma unroll
        for (int j = 0; j < 128; ++j) w[j] = src[j];
    }

    __shared__ float xs[256];
    __shared__ float partial[512];
    __shared__ float wsum[8];

    for (int s = start + blockIdx.x; s < end; s += gridDim.x) {
        const int t  = ibase[IO_ORDER + s];
        const int u  = ev[t*5];
        const int l  = ev[t*5 + 1];
        const int pu = ibase[IO_PU + t];
        const int pl = ibase[IO_PL + t];

        float kv = 0.f;
        if (tid < 128) {
            xs[tid] = (pl >= 0) ? NEWL[pl*DD + tid] : emb0[(size_t)(l + NUSERS)*DD + tid];
            kv = KU[t*DD + tid];
        } else if (tid < 256) {
            int d = tid - 128;
            xs[tid] = (pu >= 0) ? NEWU[pu*DD + d] : emb0[(size_t)u*DD + d];
            kv = KL[t*DD + d];
        }
        __syncthreads();                               // B1

        float acc = 0.f;
        {
            const float* xp = xs + h*128;
            #pragma unroll
            for (int j = 0; j < 128; ++j) acc += w[j] * xp[j];
        }
        partial[tid] = acc;
        __syncthreads();                               // B2

        float th = 0.f;
        if (tid < 256) {
            float pre = partial[tid] + partial[256 + tid] + kv;
            th = tanhf(pre);
            float ss = th * th;
            #pragma unroll
            for (int o = 32; o > 0; o >>= 1) ss += __shfl_xor(ss, o, 64);
            if (lane == 0) wsum[wid] = ss;
        }
        __syncthreads();                               // B3

        if (tid < 256) {
            float S  = (tid < 128) ? (wsum[0] + wsum[1]) : (wsum[2] + wsum[3]);
            float sf = 1.f / fmaxf(sqrtf(S), 1e-12f);
            float v2 = th * sf;
            float old = (tid < 128) ? xs[128 + tid] : xs[tid - 128];
            if (tid < 128) NEWU[t*DD + tid]       = v2;
            else           NEWL[t*DD + (tid-128)] = v2;
            float dd = v2 - old;
            float s2 = dd * dd;
            #pragma unroll
            for (int o = 32; o > 0; o >>= 1) s2 += __shfl_xor(s2, o, 64);
            if (lane == 0) wsum[4 + wid] = s2;
        }
        __syncthreads();                               // B4
        if (tid == 0)
            DRIFT[t] = (wsum[4] + wsum[5] + wsum[6] + wsum[7]) * (1.f / 128.f);
    }
}

// Tail: ONE block processes ALL levels >= TAIL_LV sequentially in level order.
// Program order + __syncthreads => correct for any DAG depth (no guard needed).
__global__ __launch_bounds__(512) void chain_tail(const int* __restrict__ ev,
    const float* __restrict__ emb0,
    const float* __restrict__ wihu, const float* __restrict__ whhu,
    const float* __restrict__ whhl, const float* __restrict__ wihl,
    const float* __restrict__ KU, const float* __restrict__ KL,
    float* __restrict__ NEWU, float* __restrict__ NEWL, float* __restrict__ DRIFT,
    const int* __restrict__ ibase) {
    const int nlev = ibase[IO_NLEV];
    if (nlev <= TAIL_LV) return;
    const int start = ibase[IO_OFF + TAIL_LV];
    const int end   = ibase[IO_OFF + nlev];

    const int tid  = threadIdx.x;
    const int h    = tid >> 8;
    const int r    = tid & 255;
    const int lane = tid & 63;
    const int wid  = tid >> 6;

    float w[128];
    {
        const float* src;
        if (h == 0) src = (r < 128) ? (wihu + r*193) : (whhl + (r-128)*128);
        else        src = (r < 128) ? (whhu + r*128) : (wihl + (r-128)*193);
        #pragma unroll
        for (int j = 0; j < 128; ++j) w[j] = src[j];
    }

    __shared__ float xs[256];
    __shared__ float partial[512];
    __shared__ float wsum[8];

    for (int s = start; s < end; ++s) {
        const int t  = ibase[IO_ORDER + s];
        const int u  = ev[t*5];
        const int l  = ev[t*5 + 1];
        const int pu = ibase[IO_PU + t];
        const int pl = ibase[IO_PL + t];

        float kv = 0.f;
        if (tid < 128) {
            xs[tid] = (pl >= 0) ? NEWL[pl*DD + tid] : emb0[(size_t)(l + NUSERS)*DD + tid];
            kv = KU[t*DD + tid];
        } else if (tid < 256) {
            int d = tid - 128;
            xs[tid] = (pu >= 0) ? NEWU[pu*DD + d] : emb0[(size_t)u*DD + d];
            kv = KL[t*DD + d];
        }
        __syncthreads();                               // B1

        float acc = 0.f;
        {
            const float* xp = xs + h*128;
            #pragma unroll
            for (int j = 0; j < 128; ++j) acc += w[j] * xp[j];
        }
        partial[tid] = acc;
        __syncthreads();                               // B2

        float th = 0.f;
        if (tid < 256) {
            float pre = partial[tid] + partial[256 + tid] + kv;
            th = tanhf(pre);
            float ss = th * th;
            #pragma unroll
            for (int o = 32; o > 0; o >>= 1) ss += __shfl_xor(ss, o, 64);
            if (lane == 0) wsum[wid] = ss;
        }
        __syncthreads();                               // B3

        if (tid < 256) {
            float S  = (tid < 128) ? (wsum[0] + wsum[1]) : (wsum[2] + wsum[3]);
            float sf = 1.f / fmaxf(sqrtf(S), 1e-12f);
            float v2 = th * sf;
            float old = (tid < 128) ? xs[128 + tid] : xs[tid - 128];
            if (tid < 128) NEWU[t*DD + tid]       = v2;
            else           NEWL[t*DD + (tid-128)] = v2;
            float dd = v2 - old;
            float s2 = dd * dd;
            #pragma unroll
            for (int o = 32; o > 0; o >>= 1) s2 += __shfl_xor(s2, o, 64);
            if (lane == 0) wsum[4 + wid] = s2;
        }
        __syncthreads();                               // B4 (orders NEWU/NEWL for next step)
        if (tid == 0)
            DRIFT[t] = (wsum[4] + wsum[5] + wsum[6] + wsum[7]) * (1.f / 128.f);
    }
}

// Wide epilogue: Z, ELT, scatter-last.
__global__ __launch_bounds__(256) void build_z(const int* __restrict__ ev,
    const float* __restrict__ emb0, const float* __restrict__ du,
    const float* __restrict__ pw, const float* __restrict__ projb,
    const float* __restrict__ kg,
    const float* __restrict__ NEWU, const float* __restrict__ NEWL,
    float* __restrict__ Z, float* __restrict__ ELT,
    float* __restrict__ out, const int* __restrict__ ibase) {
    const int gsz = gridDim.x * blockDim.x;
    const int gid = blockIdx.x * blockDim.x + threadIdx.x;

    for (int i = gid; i < T_STEPS*320; i += gsz) {
        int t = i / 320, j = i - t*320;
        float zv;
        if (j < 128) {
            int pu = ibase[IO_PU + t];
            int uu = ev[t*5];
            float eu = (pu >= 0) ? NEWU[pu*DD + j] : emb0[(size_t)uu*DD + j];
            zv = eu * (1.f + pw[j]*du[t] + projb[j]);
        } else if (j < 256) {
            int jj = j - 128;
            int pp = ibase[IO_PP + t];
            int pv = ev[t*5 + 2];
            zv = (pp >= 0) ? NEWL[pp*DD + jj] : emb0[(size_t)(pv + NUSERS)*DD + jj];
        } else {
            int kp = ev[t*5 + 3];
            zv = kg[kp*KK + (j - 256)];
        }
        Z[i] = zv;
    }
    for (int i = gid; i < DD*T_STEPS; i += gsz) {     // ELT[d][t]
        int d = i >> 11, t = i & 2047;
        int pl = ibase[IO_PL + t];
        int l  = ev[t*5 + 1];
        ELT[i] = (pl >= 0) ? NEWL[pl*DD + d] : emb0[(size_t)(l + NUSERS)*DD + d];
    }
    for (int i = gid; i < T_STEPS*DD; i += gsz) {     // scatter last-occurrence
        int t = i >> 7, d = i & 127;
        if (ibase[IO_LASTU + t]) out[(size_t)ev[t*5]*DD + d]            = NEWU[i];
        if (ibase[IO_LASTL + t]) out[(size_t)(ev[t*5+1]+NUSERS)*DD + d] = NEWL[i];
    }
}

// Dense GEMM: S[r][t] = sum_{j<320} predw[r][j] * Z[t][j].
__global__ __launch_bounds__(256) void pred_dense(const float* __restrict__ predw,
    const float* __restrict__ Z, float* __restrict__ S, int NT, int t0) {
    __shared__ float wT[32][68];
    __shared__ float zT[32][68];
    const int tid = threadIdx.x;
    const int tx = tid & 15, ty = tid >> 4;
    const int r0  = blockIdx.y * 64;
    const int tt0 = blockIdx.x * 64;
    float acc[4][4];
    #pragma unroll
    for (int a = 0; a < 4; ++a)
        #pragma unroll
        for (int b = 0; b < 4; ++b) acc[a][b] = 0.f;

    for (int j0 = 0; j0 < 320; j0 += 32) {
        #pragma unroll
        for (int k = 0; k < 2; ++k) {
            int idx = tid + k*256;
            int rr = idx >> 3;
            int jc = (idx & 7) * 4;
            int rg = r0 + rr; if (rg > PRED_OUT-1) rg = PRED_OUT-1;
            const float4 v = *(const float4*)(predw + (size_t)rg*PRED_IN + j0 + jc);
            wT[jc+0][rr] = v.x; wT[jc+1][rr] = v.y; wT[jc+2][rr] = v.z; wT[jc+3][rr] = v.w;
        }
        #pragma unroll
        for (int k = 0; k < 2; ++k) {
            int idx = tid + k*256;
            int tt = idx >> 3;
            int jc = (idx & 7) * 4;
            const float4 v = *(const float4*)(Z + (size_t)(t0 + tt0 + tt)*320 + j0 + jc);
            zT[jc+0][tt] = v.x; zT[jc+1][tt] = v.y; zT[jc+2][tt] = v.z; zT[jc+3][tt] = v.w;
        }
        __syncthreads();
        #pragma unroll
        for (int j = 0; j < 32; ++j) {
            const float4 wv = *(const float4*)&wT[j][ty*4];
            const float4 zv = *(const float4*)&zT[j][tx*4];
            acc[0][0] += wv.x*zv.x; acc[0][1] += wv.x*zv.y; acc[0][2] += wv.x*zv.z; acc[0][3] += wv.x*zv.w;
            acc[1][0] += wv.y*zv.x; acc[1][1] += wv.y*zv.y; acc[1][2] += wv.y*zv.z; acc[1][3] += wv.y*zv.w;
            acc[2][0] += wv.z*zv.x; acc[2][1] += wv.z*zv.y; acc[2][2] += wv.z*zv.z; acc[2][3] += wv.z*zv.w;
            acc[3][0] += wv.w*zv.x; acc[3][1] += wv.w*zv.y; acc[3][2] += wv.w*zv.z; acc[3][3] += wv.w*zv.w;
        }
        __syncthreads();
    }
    #pragma unroll
    for (int a = 0; a < 4; ++a) {
        int r = r0 + ty*4 + a;
        if (r < PRED_OUT) {
            float4 o; o.x = acc[a][0]; o.y = acc[a][1]; o.z = acc[a][2]; o.w = acc[a][3];
            *(float4*)(S + (size_t)r*NT + tt0 + tx*4) = o;
        }
    }
}

// Row-centric scatter+finalize.
__global__ __launch_bounds__(64) void pred_scatter(const int* __restrict__ ev,
    const float* __restrict__ predw, const float* __restrict__ predb,
    const float* __restrict__ kg, const float* __restrict__ S,
    const float* __restrict__ ELT, float* __restrict__ rowp,
    int NT, int t0, int chunk) {
    __shared__ float swsl[NLOCAS];
    __shared__ float swsu[NUSERS];
    const int tid = threadIdx.x;
    const int r = blockIdx.x;
    const float* base = predw + (size_t)r*PRED_IN;
    for (int i = tid; i < NLOCAS; i += 64) swsl[i] = base[320 + i];
    for (int i = tid; i < NUSERS; i += 64) swsu[i] = base[320 + NLOCAS + i];
    __syncthreads();
    const float bias = predb[r];
    const int mode = (r < DD) ? 0 : (r < DD + NLOCAS ? 1 : 2);
    float lsum = 0.f;
    for (int tb = 0; tb < NT; tb += 64) {
        int tloc = tb + tid;
        int t = t0 + tloc;
        int pv = ev[t*5 + 2];
        int uu = ev[t*5 + 0];
        float v = S[(size_t)r*NT + tloc] + bias + swsl[pv] + swsu[uu];
        float tv;
        if (mode == 0)      tv = ELT[r*T_STEPS + t];
        else if (mode == 1) tv = (pv == r - DD) ? 1.f : 0.f;
        else                tv = kg[ev[t*5+4]*KK + (r - DD - NLOCAS)];
        float d = v - tv;
        lsum += d*d;
    }
    #pragma unroll
    for (int o = 32; o > 0; o >>= 1) lsum += __shfl_xor(lsum, o, 64);
    if (tid == 0) rowp[chunk*PRED_OUT + r] = lsum;
}

__global__ __launch_bounds__(256) void final_reduce(const float* __restrict__ rowp,
                                                    const float* __restrict__ drift,
                                                    float* __restrict__ out, int nchunk) {
    int tid = threadIdx.x;
    float s = 0.f;
    for (int i = tid; i < nchunk*PRED_OUT; i += 256) s += rowp[i];
    s *= (1.0f / PRED_OUT);
    for (int i = tid; i < T_STEPS; i += 256) s += drift[i];
    #pragma unroll
    for (int o = 32; o > 0; o >>= 1) s += __shfl_xor(s, o, 64);
    __shared__ float red[4];
    if ((tid & 63) == 0) red[tid >> 6] = s;
    __syncthreads();
    if (tid == 0) out[OUT_EMB] = red[0] + red[1] + red[2] + red[3];
}

extern "C" void kernel_launch(void* const* d_in, const int* in_sizes, int n_in,
                              void* d_out, int out_size, void* d_ws, size_t ws_size,
                              hipStream_t stream) {
    const float* emb_in = (const float*)d_in[0];
    const int*   ev     = (const int*)  d_in[1];
    const float* du     = (const float*)d_in[2];
    const float* dl     = (const float*)d_in[3];
    const float* kg     = (const float*)d_in[4];
    const float* wihu   = (const float*)d_in[5];
    const float* whhu   = (const float*)d_in[6];
    const float* bihu   = (const float*)d_in[7];
    const float* bhhu   = (const float*)d_in[8];
    const float* wihl   = (const float*)d_in[9];
    const float* whhl   = (const float*)d_in[10];
    const float* bihl   = (const float*)d_in[11];
    const float* bhhl   = (const float*)d_in[12];
    const float* projw  = (const float*)d_in[13];
    const float* projb  = (const float*)d_in[14];
    const float* predw  = (const float*)d_in[15];
    const float* predb  = (const float*)d_in[16];

    float* out = (float*)d_out;
    float* ws  = (float*)d_ws;
    float* NEWU  = ws + WS_NEWU;
    float* NEWL  = ws + WS_NEWL;
    float* KU    = ws + WS_KU;
    float* KL    = ws + WS_KL;
    float* Z     = ws + WS_Z;
    float* ELT   = ws + WS_ELT;
    float* DRIFT = ws + WS_DRIFT;
    float* ROWP  = ws + WS_ROWP;
    float* S     = ws + WS_S;
    int*   ibase = (int*)(ws + WS_INT);

    long avail = (long)(ws_size / 4) - WS_S;
    int NT = 2048;
    while (NT > 64 && (long)PRED_OUT * NT > avail) NT >>= 1;
    int nchunk = T_STEPS / NT;

    init_kernel<<<2048, 256, 0, stream>>>(emb_in, out);
    preds_kernel<<<T_STEPS/4, 256, 0, stream>>>(ev, ibase);
    levels_kernel<<<1, 1024, 0, stream>>>(ibase);
    precomp_k<<<T_STEPS, 128, 0, stream>>>(ev, du, dl, kg, wihu, bihu, bhhu,
                                           wihl, bihl, bhhl, KU, KL);
    for (int lv = 0; lv < TAIL_LV; ++lv)
        chain_sweep<<<256, 512, 0, stream>>>(lv, ev, emb_in, wihu, whhu, whhl, wihl,
                                             KU, KL, NEWU, NEWL, DRIFT, ibase);
    chain_tail<<<1, 512, 0, stream>>>(ev, emb_in, wihu, whhu, whhl, wihl,
                                      KU, KL, NEWU, NEWL, DRIFT, ibase);
    build_z<<<1024, 256, 0, stream>>>(ev, emb_in, du, projw, projb, kg,
                                      NEWU, NEWL, Z, ELT, out, ibase);
    for (int c = 0; c < nchunk; ++c) {
        int t0 = c * NT;
        pred_dense<<<dim3(NT/64, 66), 256, 0, stream>>>(predw, Z, S, NT, t0);
        pred_scatter<<<PRED_OUT, 64, 0, stream>>>(ev, predw, predb, kg, S, ELT,
                                                  ROWP, NT, t0, c);
    }
    final_reduce<<<1, 256, 0, stream>>>(ROWP, DRIFT, out, nchunk);
}

// Round 8
// 253.990 us; speedup vs baseline: 18.1668x; 1.2273x over previous
//
#include <hip/hip_runtime.h>

#define T_STEPS 2048
#define NUSERS 4000
#define NLOCAS 4000
#define DD 128
#define KK 64
#define PRED_OUT 4192
#define PRED_IN 8256
#define OUT_EMB 1024000   // 8000*128
#define TAIL_LV 8

// ---- ws layout (float offsets) ----
#define WS_NEWU   0          // 262144
#define WS_NEWL   262144
#define WS_KU     524288
#define WS_KL     786432
#define WS_Z      1048576    // 2048*320
#define WS_ELT    1703936    // 128*2048
#define WS_DRIFT  1966080    // 2048
#define WS_ROWP   1968128    // up to 32*4192
#define WS_INT    2107392    // 14400 ints
#define WS_S      2121792    // 4192*NT floats
// ---- int offsets within WS_INT ----
#define IO_PU     0
#define IO_PL     2048
#define IO_PP     4096
#define IO_LASTU  6144
#define IO_LASTL  8192
#define IO_ORDER  10240
#define IO_OFF    12288      // 2049 entries
#define IO_NLEV   14337

__global__ __launch_bounds__(256) void init_kernel(const float* __restrict__ emb_in,
                                                   float* __restrict__ out) {
    int i = blockIdx.x * blockDim.x + threadIdx.x;
    int stride = gridDim.x * blockDim.x;
    for (; i < OUT_EMB; i += stride) out[i] = emb_in[i];
}

// Wave-parallel predecessor scan: one 64-lane wave per step t.
__global__ __launch_bounds__(256) void preds_kernel(const int* __restrict__ ev,
                                                    int* __restrict__ ibase) {
    __shared__ int su[T_STEPS];
    __shared__ int sl[T_STEPS];
    const int tid  = threadIdx.x;
    const int lane = tid & 63;
    const int wid  = tid >> 6;
    for (int i = tid; i < T_STEPS; i += 256) { su[i] = ev[i*5]; sl[i] = ev[i*5+1]; }
    __syncthreads();

    const int t = blockIdx.x * 4 + wid;
    const int u = su[t], l = sl[t], p = ev[t*5 + 2];

    int pu = -1, pl = -1, pp = -1;
    {
        int round = 0;
        while (true) {
            const int q = t - 1 - lane - (round << 6);
            const int squ = (q >= 0) ? su[q] : -1;
            const int sql = (q >= 0) ? sl[q] : -1;
            if (pu < 0) {
                unsigned long long b = __ballot(squ == u);
                if (b) pu = t - 1 - (__ffsll(b) - 1) - (round << 6);
            }
            if (pl < 0) {
                unsigned long long b = __ballot(sql == l);
                if (b) pl = t - 1 - (__ffsll(b) - 1) - (round << 6);
            }
            if (pp < 0) {
                unsigned long long b = __ballot(sql == p);
                if (b) pp = t - 1 - (__ffsll(b) - 1) - (round << 6);
            }
            ++round;
            if ((pu >= 0 && pl >= 0 && pp >= 0) || (t - 1 - (round << 6) < 0)) break;
        }
    }

    int lastu = 1, lastl = 1;
    {
        int round = 0;
        while (true) {
            const int q = t + 1 + lane + (round << 6);
            const int squ = (q < T_STEPS) ? su[q] : -1;
            const int sql = (q < T_STEPS) ? sl[q] : -1;
            if (lastu && __ballot(squ == u)) lastu = 0;
            if (lastl && __ballot(sql == l)) lastl = 0;
            ++round;
            if ((!lastu && !lastl) || (t + 1 + (round << 6) >= T_STEPS)) break;
        }
    }

    if (lane == 0) {
        ibase[IO_PU + t] = pu;
        ibase[IO_PL + t] = pl;
        ibase[IO_PP + t] = pp;
        ibase[IO_LASTU + t] = lastu;
        ibase[IO_LASTL + t] = lastl;
    }
}

// DAG levels via monotone fixpoint; counting sort into ORDER with OFF[], NLEV.
__global__ __launch_bounds__(1024) void levels_kernel(int* __restrict__ ibase) {
    __shared__ int lev[T_STEPS];
    __shared__ int spu[T_STEPS];
    __shared__ int spl[T_STEPS];
    __shared__ int cnt[T_STEPS + 1];
    __shared__ int changed;
    __shared__ int smax;
    const int tid = threadIdx.x;

    for (int i = tid; i < T_STEPS; i += 1024) {
        spu[i] = ibase[IO_PU + i];
        spl[i] = ibase[IO_PL + i];
        lev[i] = 0;
    }
    if (tid == 0) smax = 0;
    __syncthreads();

    while (true) {
        if (tid == 0) changed = 0;
        __syncthreads();
        for (int i = tid; i < T_STEPS; i += 1024) {
            int nl = 0, a = spu[i], b = spl[i];
            if (a >= 0) nl = lev[a] + 1;
            if (b >= 0) { int v = lev[b] + 1; if (v > nl) nl = v; }
            if (nl > lev[i]) { lev[i] = nl; changed = 1; }
        }
        __syncthreads();
        if (!changed) break;
        __syncthreads();
    }

    for (int i = tid; i <= T_STEPS; i += 1024) cnt[i] = 0;
    __syncthreads();
    for (int i = tid; i < T_STEPS; i += 1024) {
        atomicAdd(&cnt[lev[i]], 1);
        atomicMax(&smax, lev[i]);
    }
    __syncthreads();
    if (tid == 0) {
        int nlev = smax + 1;
        int acc = 0;
        for (int k = 0; k < nlev; ++k) {
            ibase[IO_OFF + k] = acc;
            int c = cnt[k]; cnt[k] = acc; acc += c;
        }
        ibase[IO_OFF + nlev] = acc;
        ibase[IO_NLEV] = nlev;
        for (int k = nlev + 1; k <= TAIL_LV; ++k) ibase[IO_OFF + k] = acc;
    }
    __syncthreads();
    for (int i = tid; i < T_STEPS; i += 1024) {
        int pos = atomicAdd(&cnt[lev[i]], 1);
        ibase[IO_ORDER + pos] = i;
    }
}

// KU[t][r] = b_ih_u[r]+b_hh_u[r]+w_ih_u[r][192]*du[t]+sum_j w_ih_u[r][128+j]*kg[know_t][j]
__global__ __launch_bounds__(128) void precomp_k(const int* __restrict__ ev,
    const float* __restrict__ du, const float* __restrict__ dl,
    const float* __restrict__ kg,
    const float* __restrict__ wihu, const float* __restrict__ bihu, const float* __restrict__ bhhu,
    const float* __restrict__ wihl, const float* __restrict__ bihl, const float* __restrict__ bhhl,
    float* __restrict__ KU, float* __restrict__ KL) {
    int t = blockIdx.x;
    int r = threadIdx.x;
    __shared__ float skg[KK];
    int kn = ev[t*5 + 4];
    if (r < KK) skg[r] = kg[kn*KK + r];
    __syncthreads();
    float dut = du[t], dlt = dl[t];
    const float* wu = wihu + r*193;
    const float* wl = wihl + r*193;
    float ku = bihu[r] + bhhu[r] + wu[192]*dut;
    float kl = bihl[r] + bhhl[r] + wl[192]*dlt;
    #pragma unroll
    for (int j = 0; j < KK; ++j) {
        float s = skg[j];
        ku += wu[128+j]*s;
        kl += wl[128+j]*s;
    }
    KU[t*DD + r] = ku;
    KL[t*DD + r] = kl;
}

// One DAG level per launch (levels 0..TAIL_LV-1). 256 blocks x 512 threads.
__global__ __launch_bounds__(512) void chain_sweep(int lv, const int* __restrict__ ev,
    const float* __restrict__ emb0,
    const float* __restrict__ wihu, const float* __restrict__ whhu,
    const float* __restrict__ whhl, const float* __restrict__ wihl,
    const float* __restrict__ KU, const float* __restrict__ KL,
    float* __restrict__ NEWU, float* __restrict__ NEWL, float* __restrict__ DRIFT,
    const int* __restrict__ ibase) {
    const int start = ibase[IO_OFF + lv];
    const int end   = ibase[IO_OFF + lv + 1];
    if ((int)blockIdx.x >= end - start) return;

    const int tid  = threadIdx.x;
    const int h    = tid >> 8;
    const int r    = tid & 255;
    const int lane = tid & 63;
    const int wid  = tid >> 6;

    float w[128];
    {
        const float* src;
        if (h == 0) src = (r < 128) ? (wihu + r*193) : (whhl + (r-128)*128);
        else        src = (r < 128) ? (whhu + r*128) : (wihl + (r-128)*193);
        #pragma unroll
        for (int j = 0; j < 128; ++j) w[j] = src[j];
    }

    __shared__ float xs[256];
    __shared__ float partial[512];
    __shared__ float wsum[8];

    for (int s = start + blockIdx.x; s < end; s += gridDim.x) {
        const int t  = ibase[IO_ORDER + s];
        const int u  = ev[t*5];
        const int l  = ev[t*5 + 1];
        const int pu = ibase[IO_PU + t];
        const int pl = ibase[IO_PL + t];

        float kv = 0.f;
        if (tid < 128) {
            xs[tid] = (pl >= 0) ? NEWL[pl*DD + tid] : emb0[(size_t)(l + NUSERS)*DD + tid];
            kv = KU[t*DD + tid];
        } else if (tid < 256) {
            int d = tid - 128;
            xs[tid] = (pu >= 0) ? NEWU[pu*DD + d] : emb0[(size_t)u*DD + d];
            kv = KL[t*DD + d];
        }
        __syncthreads();                               // B1

        float acc = 0.f;
        {
            const float* xp = xs + h*128;
            #pragma unroll
            for (int j = 0; j < 128; ++j) acc += w[j] * xp[j];
        }
        partial[tid] = acc;
        __syncthreads();                               // B2

        float th = 0.f;
        if (tid < 256) {
            float pre = partial[tid] + partial[256 + tid] + kv;
            th = tanhf(pre);
            float ss = th * th;
            #pragma unroll
            for (int o = 32; o > 0; o >>= 1) ss += __shfl_xor(ss, o, 64);
            if (lane == 0) wsum[wid] = ss;
        }
        __syncthreads();                               // B3

        if (tid < 256) {
            float S  = (tid < 128) ? (wsum[0] + wsum[1]) : (wsum[2] + wsum[3]);
            float sf = 1.f / fmaxf(sqrtf(S), 1e-12f);
            float v2 = th * sf;
            float old = (tid < 128) ? xs[128 + tid] : xs[tid - 128];
            if (tid < 128) NEWU[t*DD + tid]       = v2;
            else           NEWL[t*DD + (tid-128)] = v2;
            float dd = v2 - old;
            float s2 = dd * dd;
            #pragma unroll
            for (int o = 32; o > 0; o >>= 1) s2 += __shfl_xor(s2, o, 64);
            if (lane == 0) wsum[4 + wid] = s2;
        }
        __syncthreads();                               // B4
        if (tid == 0)
            DRIFT[t] = (wsum[4] + wsum[5] + wsum[6] + wsum[7]) * (1.f / 128.f);
    }
}

// Tail: ONE block processes ALL levels >= TAIL_LV sequentially in level order.
__global__ __launch_bounds__(512) void chain_tail(const int* __restrict__ ev,
    const float* __restrict__ emb0,
    const float* __restrict__ wihu, const float* __restrict__ whhu,
    const float* __restrict__ whhl, const float* __restrict__ wihl,
    const float* __restrict__ KU, const float* __restrict__ KL,
    float* __restrict__ NEWU, float* __restrict__ NEWL, float* __restrict__ DRIFT,
    const int* __restrict__ ibase) {
    const int nlev = ibase[IO_NLEV];
    if (nlev <= TAIL_LV) return;
    const int start = ibase[IO_OFF + TAIL_LV];
    const int end   = ibase[IO_OFF + nlev];

    const int tid  = threadIdx.x;
    const int h    = tid >> 8;
    const int r    = tid & 255;
    const int lane = tid & 63;
    const int wid  = tid >> 6;

    float w[128];
    {
        const float* src;
        if (h == 0) src = (r < 128) ? (wihu + r*193) : (whhl + (r-128)*128);
        else        src = (r < 128) ? (whhu + r*128) : (wihl + (r-128)*193);
        #pragma unroll
        for (int j = 0; j < 128; ++j) w[j] = src[j];
    }

    __shared__ float xs[256];
    __shared__ float partial[512];
    __shared__ float wsum[8];

    for (int s = start; s < end; ++s) {
        const int t  = ibase[IO_ORDER + s];
        const int u  = ev[t*5];
        const int l  = ev[t*5 + 1];
        const int pu = ibase[IO_PU + t];
        const int pl = ibase[IO_PL + t];

        float kv = 0.f;
        if (tid < 128) {
            xs[tid] = (pl >= 0) ? NEWL[pl*DD + tid] : emb0[(size_t)(l + NUSERS)*DD + tid];
            kv = KU[t*DD + tid];
        } else if (tid < 256) {
            int d = tid - 128;
            xs[tid] = (pu >= 0) ? NEWU[pu*DD + d] : emb0[(size_t)u*DD + d];
            kv = KL[t*DD + d];
        }
        __syncthreads();                               // B1

        float acc = 0.f;
        {
            const float* xp = xs + h*128;
            #pragma unroll
            for (int j = 0; j < 128; ++j) acc += w[j] * xp[j];
        }
        partial[tid] = acc;
        __syncthreads();                               // B2

        float th = 0.f;
        if (tid < 256) {
            float pre = partial[tid] + partial[256 + tid] + kv;
            th = tanhf(pre);
            float ss = th * th;
            #pragma unroll
            for (int o = 32; o > 0; o >>= 1) ss += __shfl_xor(ss, o, 64);
            if (lane == 0) wsum[wid] = ss;
        }
        __syncthreads();                               // B3

        if (tid < 256) {
            float S  = (tid < 128) ? (wsum[0] + wsum[1]) : (wsum[2] + wsum[3]);
            float sf = 1.f / fmaxf(sqrtf(S), 1e-12f);
            float v2 = th * sf;
            float old = (tid < 128) ? xs[128 + tid] : xs[tid - 128];
            if (tid < 128) NEWU[t*DD + tid]       = v2;
            else           NEWL[t*DD + (tid-128)] = v2;
            float dd = v2 - old;
            float s2 = dd * dd;
            #pragma unroll
            for (int o = 32; o > 0; o >>= 1) s2 += __shfl_xor(s2, o, 64);
            if (lane == 0) wsum[4 + wid] = s2;
        }
        __syncthreads();                               // B4
        if (tid == 0)
            DRIFT[t] = (wsum[4] + wsum[5] + wsum[6] + wsum[7]) * (1.f / 128.f);
    }
}

// Wide epilogue: Z, ELT, scatter-last.
__global__ __launch_bounds__(256) void build_z(const int* __restrict__ ev,
    const float* __restrict__ emb0, const float* __restrict__ du,
    const float* __restrict__ pw, const float* __restrict__ projb,
    const float* __restrict__ kg,
    const float* __restrict__ NEWU, const float* __restrict__ NEWL,
    float* __restrict__ Z, float* __restrict__ ELT,
    float* __restrict__ out, const int* __restrict__ ibase) {
    const int gsz = gridDim.x * blockDim.x;
    const int gid = blockIdx.x * blockDim.x + threadIdx.x;

    for (int i = gid; i < T_STEPS*320; i += gsz) {
        int t = i / 320, j = i - t*320;
        float zv;
        if (j < 128) {
            int pu = ibase[IO_PU + t];
            int uu = ev[t*5];
            float eu = (pu >= 0) ? NEWU[pu*DD + j] : emb0[(size_t)uu*DD + j];
            zv = eu * (1.f + pw[j]*du[t] + projb[j]);
        } else if (j < 256) {
            int jj = j - 128;
            int pp = ibase[IO_PP + t];
            int pv = ev[t*5 + 2];
            zv = (pp >= 0) ? NEWL[pp*DD + jj] : emb0[(size_t)(pv + NUSERS)*DD + jj];
        } else {
            int kp = ev[t*5 + 3];
            zv = kg[kp*KK + (j - 256)];
        }
        Z[i] = zv;
    }
    for (int i = gid; i < DD*T_STEPS; i += gsz) {     // ELT[d][t]
        int d = i >> 11, t = i & 2047;
        int pl = ibase[IO_PL + t];
        int l  = ev[t*5 + 1];
        ELT[i] = (pl >= 0) ? NEWL[pl*DD + d] : emb0[(size_t)(l + NUSERS)*DD + d];
    }
    for (int i = gid; i < T_STEPS*DD; i += gsz) {     // scatter last-occurrence
        int t = i >> 7, d = i & 127;
        if (ibase[IO_LASTU + t]) out[(size_t)ev[t*5]*DD + d]            = NEWU[i];
        if (ibase[IO_LASTL + t]) out[(size_t)(ev[t*5+1]+NUSERS)*DD + d] = NEWL[i];
    }
}

// Dense GEMM: S[r][t] = sum_{j<320} predw[r][j] * Z[t][j].
__global__ __launch_bounds__(256) void pred_dense(const float* __restrict__ predw,
    const float* __restrict__ Z, float* __restrict__ S, int NT, int t0) {
    __shared__ float wT[32][68];
    __shared__ float zT[32][68];
    const int tid = threadIdx.x;
    const int tx = tid & 15, ty = tid >> 4;
    const int r0  = blockIdx.y * 64;
    const int tt0 = blockIdx.x * 64;
    float acc[4][4];
    #pragma unroll
    for (int a = 0; a < 4; ++a)
        #pragma unroll
        for (int b = 0; b < 4; ++b) acc[a][b] = 0.f;

    for (int j0 = 0; j0 < 320; j0 += 32) {
        #pragma unroll
        for (int k = 0; k < 2; ++k) {
            int idx = tid + k*256;
            int rr = idx >> 3;
            int jc = (idx & 7) * 4;
            int rg = r0 + rr; if (rg > PRED_OUT-1) rg = PRED_OUT-1;
            const float4 v = *(const float4*)(predw + (size_t)rg*PRED_IN + j0 + jc);
            wT[jc+0][rr] = v.x; wT[jc+1][rr] = v.y; wT[jc+2][rr] = v.z; wT[jc+3][rr] = v.w;
        }
        #pragma unroll
        for (int k = 0; k < 2; ++k) {
            int idx = tid + k*256;
            int tt = idx >> 3;
            int jc = (idx & 7) * 4;
            const float4 v = *(const float4*)(Z + (size_t)(t0 + tt0 + tt)*320 + j0 + jc);
            zT[jc+0][tt] = v.x; zT[jc+1][tt] = v.y; zT[jc+2][tt] = v.z; zT[jc+3][tt] = v.w;
        }
        __syncthreads();
        #pragma unroll
        for (int j = 0; j < 32; ++j) {
            const float4 wv = *(const float4*)&wT[j][ty*4];
            const float4 zv = *(const float4*)&zT[j][tx*4];
            acc[0][0] += wv.x*zv.x; acc[0][1] += wv.x*zv.y; acc[0][2] += wv.x*zv.z; acc[0][3] += wv.x*zv.w;
            acc[1][0] += wv.y*zv.x; acc[1][1] += wv.y*zv.y; acc[1][2] += wv.y*zv.z; acc[1][3] += wv.y*zv.w;
            acc[2][0] += wv.z*zv.x; acc[2][1] += wv.z*zv.y; acc[2][2] += wv.z*zv.z; acc[2][3] += wv.z*zv.w;
            acc[3][0] += wv.w*zv.x; acc[3][1] += wv.w*zv.y; acc[3][2] += wv.w*zv.z; acc[3][3] += wv.w*zv.w;
        }
        __syncthreads();
    }
    #pragma unroll
    for (int a = 0; a < 4; ++a) {
        int r = r0 + ty*4 + a;
        if (r < PRED_OUT) {
            float4 o; o.x = acc[a][0]; o.y = acc[a][1]; o.z = acc[a][2]; o.w = acc[a][3];
            *(float4*)(S + (size_t)r*NT + tt0 + tx*4) = o;
        }
    }
}

// Row-centric scatter+finalize: 256 threads/block (4 waves), one row per block.
// 32KB row staged via float4 with 4 waves in flight; gathers from LDS.
__global__ __launch_bounds__(256) void pred_scatter(const int* __restrict__ ev,
    const float* __restrict__ predw, const float* __restrict__ predb,
    const float* __restrict__ kg, const float* __restrict__ S,
    const float* __restrict__ ELT, float* __restrict__ rowp,
    int NT, int t0, int chunk) {
    __shared__ float srow[NLOCAS + NUSERS];   // 32 KB
    __shared__ float red[4];
    const int tid = threadIdx.x;
    const int lane = tid & 63, wid = tid >> 6;
    const int r = blockIdx.x;
    const float* base = predw + (size_t)r*PRED_IN + 320;
    #pragma unroll
    for (int i = 0; i < 8; ++i) {
        int idx = (tid + i*256) * 4;          // 2000 float4 = 8000 floats
        if (idx < NLOCAS + NUSERS) {
            float4 v = *(const float4*)(base + idx);
            *(float4*)(srow + idx) = v;
        }
    }
    __syncthreads();
    const float bias = predb[r];
    const int mode = (r < DD) ? 0 : (r < DD + NLOCAS ? 1 : 2);
    float lsum = 0.f;
    for (int tloc = tid; tloc < NT; tloc += 256) {
        int t = t0 + tloc;
        int pv = ev[t*5 + 2];
        int uu = ev[t*5 + 0];
        float v = S[(size_t)r*NT + tloc] + bias + srow[pv] + srow[NLOCAS + uu];
        float tv;
        if (mode == 0)      tv = ELT[r*T_STEPS + t];
        else if (mode == 1) tv = (pv == r - DD) ? 1.f : 0.f;
        else                tv = kg[ev[t*5+4]*KK + (r - DD - NLOCAS)];
        float d = v - tv;
        lsum += d*d;
    }
    #pragma unroll
    for (int o = 32; o > 0; o >>= 1) lsum += __shfl_xor(lsum, o, 64);
    if (lane == 0) red[wid] = lsum;
    __syncthreads();
    if (tid == 0) rowp[chunk*PRED_OUT + r] = red[0] + red[1] + red[2] + red[3];
}

__global__ __launch_bounds__(256) void final_reduce(const float* __restrict__ rowp,
                                                    const float* __restrict__ drift,
                                                    float* __restrict__ out, int nchunk) {
    int tid = threadIdx.x;
    float s = 0.f;
    for (int i = tid; i < nchunk*PRED_OUT; i += 256) s += rowp[i];
    s *= (1.0f / PRED_OUT);
    for (int i = tid; i < T_STEPS; i += 256) s += drift[i];
    #pragma unroll
    for (int o = 32; o > 0; o >>= 1) s += __shfl_xor(s, o, 64);
    __shared__ float red[4];
    if ((tid & 63) == 0) red[tid >> 6] = s;
    __syncthreads();
    if (tid == 0) out[OUT_EMB] = red[0] + red[1] + red[2] + red[3];
}

extern "C" void kernel_launch(void* const* d_in, const int* in_sizes, int n_in,
                              void* d_out, int out_size, void* d_ws, size_t ws_size,
                              hipStream_t stream) {
    const float* emb_in = (const float*)d_in[0];
    const int*   ev     = (const int*)  d_in[1];
    const float* du     = (const float*)d_in[2];
    const float* dl     = (const float*)d_in[3];
    const float* kg     = (const float*)d_in[4];
    const float* wihu   = (const float*)d_in[5];
    const float* whhu   = (const float*)d_in[6];
    const float* bihu   = (const float*)d_in[7];
    const float* bhhu   = (const float*)d_in[8];
    const float* wihl   = (const float*)d_in[9];
    const float* whhl   = (const float*)d_in[10];
    const float* bihl   = (const float*)d_in[11];
    const float* bhhl   = (const float*)d_in[12];
    const float* projw  = (const float*)d_in[13];
    const float* projb  = (const float*)d_in[14];
    const float* predw  = (const float*)d_in[15];
    const float* predb  = (const float*)d_in[16];

    float* out = (float*)d_out;
    float* ws  = (float*)d_ws;
    float* NEWU  = ws + WS_NEWU;
    float* NEWL  = ws + WS_NEWL;
    float* KU    = ws + WS_KU;
    float* KL    = ws + WS_KL;
    float* Z     = ws + WS_Z;
    float* ELT   = ws + WS_ELT;
    float* DRIFT = ws + WS_DRIFT;
    float* ROWP  = ws + WS_ROWP;
    float* S     = ws + WS_S;
    int*   ibase = (int*)(ws + WS_INT);

    long avail = (long)(ws_size / 4) - WS_S;
    int NT = 2048;
    while (NT > 64 && (long)PRED_OUT * NT > avail) NT >>= 1;
    int nchunk = T_STEPS / NT;

    init_kernel<<<2048, 256, 0, stream>>>(emb_in, out);
    preds_kernel<<<T_STEPS/4, 256, 0, stream>>>(ev, ibase);
    levels_kernel<<<1, 1024, 0, stream>>>(ibase);
    precomp_k<<<T_STEPS, 128, 0, stream>>>(ev, du, dl, kg, wihu, bihu, bhhu,
                                           wihl, bihl, bhhl, KU, KL);
    for (int lv = 0; lv < TAIL_LV; ++lv)
        chain_sweep<<<256, 512, 0, stream>>>(lv, ev, emb_in, wihu, whhu, whhl, wihl,
                                             KU, KL, NEWU, NEWL, DRIFT, ibase);
    chain_tail<<<1, 512, 0, stream>>>(ev, emb_in, wihu, whhu, whhl, wihl,
                                      KU, KL, NEWU, NEWL, DRIFT, ibase);
    build_z<<<1024, 256, 0, stream>>>(ev, emb_in, du, projw, projb, kg,
                                      NEWU, NEWL, Z, ELT, out, ibase);
    for (int c = 0; c < nchunk; ++c) {
        int t0 = c * NT;
        pred_dense<<<dim3(NT/64, 66), 256, 0, stream>>>(predw, Z, S, NT, t0);
        pred_scatter<<<PRED_OUT, 256, 0, stream>>>(ev, predw, predb, kg, S, ELT,
                                                   ROWP, NT, t0, c);
    }
    final_reduce<<<1, 256, 0, stream>>>(ROWP, DRIFT, out, nchunk);
}

// Round 9
// 211.731 us; speedup vs baseline: 21.7927x; 1.1996x over previous
//
#include <hip/hip_runtime.h>

#define T_STEPS 2048
#define NUSERS 4000
#define NLOCAS 4000
#define DD 128
#define KK 64
#define PRED_OUT 4192
#define PRED_IN 8256
#define OUT_EMB 1024000   // 8000*128
#define TAIL_LV 8
#define WB_ROWS 4224      // 4192 padded to 33*128

typedef __attribute__((ext_vector_type(8))) short short8v;
typedef __attribute__((ext_vector_type(4))) float f32x4;

// ---- ws layout (float offsets) ----
#define WS_NEWU   0          // 262144
#define WS_NEWL   262144
#define WS_KU     524288
#define WS_KL     786432
#define WS_ZB     1048576    // 2048*320 ushort = 327680 float slots
#define WS_WB     1376256    // 4224*320 ushort = 675840 float slots
#define WS_ELT    2052096    // 128*2048
#define WS_DRIFT  2314240    // 2048
#define WS_ROWP   2316288    // 4192*16 max
#define WS_INT    2450432    // 14400 ints
#define WS_S      2464832    // 4192*NT floats
// ---- int offsets within WS_INT ----
#define IO_PU     0
#define IO_PL     2048
#define IO_PP     4096
#define IO_LASTU  6144
#define IO_LASTL  8192
#define IO_ORDER  10240
#define IO_OFF    12288      // 2049 entries
#define IO_NLEV   14337

__device__ inline unsigned short f2bf(float f) {
    unsigned int x = __float_as_uint(f);
    unsigned int r = (x + 0x7FFFu + ((x >> 16) & 1u)) >> 16;
    return (unsigned short)r;
}

__global__ __launch_bounds__(256) void init_kernel(const float* __restrict__ emb_in,
                                                   float* __restrict__ out) {
    int i = blockIdx.x * blockDim.x + threadIdx.x;
    int stride = gridDim.x * blockDim.x;
    for (; i < OUT_EMB; i += stride) out[i] = emb_in[i];
}

// Wave-parallel predecessor scan: one 64-lane wave per step t.
__global__ __launch_bounds__(256) void preds_kernel(const int* __restrict__ ev,
                                                    int* __restrict__ ibase) {
    __shared__ int su[T_STEPS];
    __shared__ int sl[T_STEPS];
    const int tid  = threadIdx.x;
    const int lane = tid & 63;
    const int wid  = tid >> 6;
    for (int i = tid; i < T_STEPS; i += 256) { su[i] = ev[i*5]; sl[i] = ev[i*5+1]; }
    __syncthreads();

    const int t = blockIdx.x * 4 + wid;
    const int u = su[t], l = sl[t], p = ev[t*5 + 2];

    int pu = -1, pl = -1, pp = -1;
    {
        int round = 0;
        while (true) {
            const int q = t - 1 - lane - (round << 6);
            const int squ = (q >= 0) ? su[q] : -1;
            const int sql = (q >= 0) ? sl[q] : -1;
            if (pu < 0) {
                unsigned long long b = __ballot(squ == u);
                if (b) pu = t - 1 - (__ffsll(b) - 1) - (round << 6);
            }
            if (pl < 0) {
                unsigned long long b = __ballot(sql == l);
                if (b) pl = t - 1 - (__ffsll(b) - 1) - (round << 6);
            }
            if (pp < 0) {
                unsigned long long b = __ballot(sql == p);
                if (b) pp = t - 1 - (__ffsll(b) - 1) - (round << 6);
            }
            ++round;
            if ((pu >= 0 && pl >= 0 && pp >= 0) || (t - 1 - (round << 6) < 0)) break;
        }
    }

    int lastu = 1, lastl = 1;
    {
        int round = 0;
        while (true) {
            const int q = t + 1 + lane + (round << 6);
            const int squ = (q < T_STEPS) ? su[q] : -1;
            const int sql = (q < T_STEPS) ? sl[q] : -1;
            if (lastu && __ballot(squ == u)) lastu = 0;
            if (lastl && __ballot(sql == l)) lastl = 0;
            ++round;
            if ((!lastu && !lastl) || (t + 1 + (round << 6) >= T_STEPS)) break;
        }
    }

    if (lane == 0) {
        ibase[IO_PU + t] = pu;
        ibase[IO_PL + t] = pl;
        ibase[IO_PP + t] = pp;
        ibase[IO_LASTU + t] = lastu;
        ibase[IO_LASTL + t] = lastl;
    }
}

// DAG levels via monotone fixpoint; counting sort into ORDER with OFF[], NLEV.
__global__ __launch_bounds__(1024) void levels_kernel(int* __restrict__ ibase) {
    __shared__ int lev[T_STEPS];
    __shared__ int spu[T_STEPS];
    __shared__ int spl[T_STEPS];
    __shared__ int cnt[T_STEPS + 1];
    __shared__ int changed;
    __shared__ int smax;
    const int tid = threadIdx.x;

    for (int i = tid; i < T_STEPS; i += 1024) {
        spu[i] = ibase[IO_PU + i];
        spl[i] = ibase[IO_PL + i];
        lev[i] = 0;
    }
    if (tid == 0) smax = 0;
    __syncthreads();

    while (true) {
        if (tid == 0) changed = 0;
        __syncthreads();
        for (int i = tid; i < T_STEPS; i += 1024) {
            int nl = 0, a = spu[i], b = spl[i];
            if (a >= 0) nl = lev[a] + 1;
            if (b >= 0) { int v = lev[b] + 1; if (v > nl) nl = v; }
            if (nl > lev[i]) { lev[i] = nl; changed = 1; }
        }
        __syncthreads();
        if (!changed) break;
        __syncthreads();
    }

    for (int i = tid; i <= T_STEPS; i += 1024) cnt[i] = 0;
    __syncthreads();
    for (int i = tid; i < T_STEPS; i += 1024) {
        atomicAdd(&cnt[lev[i]], 1);
        atomicMax(&smax, lev[i]);
    }
    __syncthreads();
    if (tid == 0) {
        int nlev = smax + 1;
        int acc = 0;
        for (int k = 0; k < nlev; ++k) {
            ibase[IO_OFF + k] = acc;
            int c = cnt[k]; cnt[k] = acc; acc += c;
        }
        ibase[IO_OFF + nlev] = acc;
        ibase[IO_NLEV] = nlev;
        for (int k = nlev + 1; k <= TAIL_LV; ++k) ibase[IO_OFF + k] = acc;
    }
    __syncthreads();
    for (int i = tid; i < T_STEPS; i += 1024) {
        int pos = atomicAdd(&cnt[lev[i]], 1);
        ibase[IO_ORDER + pos] = i;
    }
}

// KU[t][r] = b_ih_u[r]+b_hh_u[r]+w_ih_u[r][192]*du[t]+sum_j w_ih_u[r][128+j]*kg[know_t][j]
__global__ __launch_bounds__(128) void precomp_k(const int* __restrict__ ev,
    const float* __restrict__ du, const float* __restrict__ dl,
    const float* __restrict__ kg,
    const float* __restrict__ wihu, const float* __restrict__ bihu, const float* __restrict__ bhhu,
    const float* __restrict__ wihl, const float* __restrict__ bihl, const float* __restrict__ bhhl,
    float* __restrict__ KU, float* __restrict__ KL) {
    int t = blockIdx.x;
    int r = threadIdx.x;
    __shared__ float skg[KK];
    int kn = ev[t*5 + 4];
    if (r < KK) skg[r] = kg[kn*KK + r];
    __syncthreads();
    float dut = du[t], dlt = dl[t];
    const float* wu = wihu + r*193;
    const float* wl = wihl + r*193;
    float ku = bihu[r] + bhhu[r] + wu[192]*dut;
    float kl = bihl[r] + bhhl[r] + wl[192]*dlt;
    #pragma unroll
    for (int j = 0; j < KK; ++j) {
        float s = skg[j];
        ku += wu[128+j]*s;
        kl += wl[128+j]*s;
    }
    KU[t*DD + r] = ku;
    KL[t*DD + r] = kl;
}

// One DAG level per launch (levels 0..TAIL_LV-1). 256 blocks x 512 threads.
__global__ __launch_bounds__(512) void chain_sweep(int lv, const int* __restrict__ ev,
    const float* __restrict__ emb0,
    const float* __restrict__ wihu, const float* __restrict__ whhu,
    const float* __restrict__ whhl, const float* __restrict__ wihl,
    const float* __restrict__ KU, const float* __restrict__ KL,
    float* __restrict__ NEWU, float* __restrict__ NEWL, float* __restrict__ DRIFT,
    const int* __restrict__ ibase) {
    const int start = ibase[IO_OFF + lv];
    const int end   = ibase[IO_OFF + lv + 1];
    if ((int)blockIdx.x >= end - start) return;

    const int tid  = threadIdx.x;
    const int h    = tid >> 8;
    const int r    = tid & 255;
    const int lane = tid & 63;
    const int wid  = tid >> 6;

    float w[128];
    {
        const float* src;
        if (h == 0) src = (r < 128) ? (wihu + r*193) : (whhl + (r-128)*128);
        else        src = (r < 128) ? (whhu + r*128) : (wihl + (r-128)*193);
        #pragma unroll
        for (int j = 0; j < 128; ++j) w[j] = src[j];
    }

    __shared__ float xs[256];
    __shared__ float partial[512];
    __shared__ float wsum[8];

    for (int s = start + blockIdx.x; s < end; s += gridDim.x) {
        const int t  = ibase[IO_ORDER + s];
        const int u  = ev[t*5];
        const int l  = ev[t*5 + 1];
        const int pu = ibase[IO_PU + t];
        const int pl = ibase[IO_PL + t];

        float kv = 0.f;
        if (tid < 128) {
            xs[tid] = (pl >= 0) ? NEWL[pl*DD + tid] : emb0[(size_t)(l + NUSERS)*DD + tid];
            kv = KU[t*DD + tid];
        } else if (tid < 256) {
            int d = tid - 128;
            xs[tid] = (pu >= 0) ? NEWU[pu*DD + d] : emb0[(size_t)u*DD + d];
            kv = KL[t*DD + d];
        }
        __syncthreads();                               // B1

        float acc = 0.f;
        {
            const float* xp = xs + h*128;
            #pragma unroll
            for (int j = 0; j < 128; ++j) acc += w[j] * xp[j];
        }
        partial[tid] = acc;
        __syncthreads();                               // B2

        float th = 0.f;
        if (tid < 256) {
            float pre = partial[tid] + partial[256 + tid] + kv;
            th = tanhf(pre);
            float ss = th * th;
            #pragma unroll
            for (int o = 32; o > 0; o >>= 1) ss += __shfl_xor(ss, o, 64);
            if (lane == 0) wsum[wid] = ss;
        }
        __syncthreads();                               // B3

        if (tid < 256) {
            float S  = (tid < 128) ? (wsum[0] + wsum[1]) : (wsum[2] + wsum[3]);
            float sf = 1.f / fmaxf(sqrtf(S), 1e-12f);
            float v2 = th * sf;
            float old = (tid < 128) ? xs[128 + tid] : xs[tid - 128];
            if (tid < 128) NEWU[t*DD + tid]       = v2;
            else           NEWL[t*DD + (tid-128)] = v2;
            float dd = v2 - old;
            float s2 = dd * dd;
            #pragma unroll
            for (int o = 32; o > 0; o >>= 1) s2 += __shfl_xor(s2, o, 64);
            if (lane == 0) wsum[4 + wid] = s2;
        }
        __syncthreads();                               // B4
        if (tid == 0)
            DRIFT[t] = (wsum[4] + wsum[5] + wsum[6] + wsum[7]) * (1.f / 128.f);
    }
}

// Tail: ONE block processes ALL levels >= TAIL_LV sequentially in level order.
__global__ __launch_bounds__(512) void chain_tail(const int* __restrict__ ev,
    const float* __restrict__ emb0,
    const float* __restrict__ wihu, const float* __restrict__ whhu,
    const float* __restrict__ whhl, const float* __restrict__ wihl,
    const float* __restrict__ KU, const float* __restrict__ KL,
    float* __restrict__ NEWU, float* __restrict__ NEWL, float* __restrict__ DRIFT,
    const int* __restrict__ ibase) {
    const int nlev = ibase[IO_NLEV];
    if (nlev <= TAIL_LV) return;
    const int start = ibase[IO_OFF + TAIL_LV];
    const int end   = ibase[IO_OFF + nlev];

    const int tid  = threadIdx.x;
    const int h    = tid >> 8;
    const int r    = tid & 255;
    const int lane = tid & 63;
    const int wid  = tid >> 6;

    float w[128];
    {
        const float* src;
        if (h == 0) src = (r < 128) ? (wihu + r*193) : (whhl + (r-128)*128);
        else        src = (r < 128) ? (whhu + r*128) : (wihl + (r-128)*193);
        #pragma unroll
        for (int j = 0; j < 128; ++j) w[j] = src[j];
    }

    __shared__ float xs[256];
    __shared__ float partial[512];
    __shared__ float wsum[8];

    for (int s = start; s < end; ++s) {
        const int t  = ibase[IO_ORDER + s];
        const int u  = ev[t*5];
        const int l  = ev[t*5 + 1];
        const int pu = ibase[IO_PU + t];
        const int pl = ibase[IO_PL + t];

        float kv = 0.f;
        if (tid < 128) {
            xs[tid] = (pl >= 0) ? NEWL[pl*DD + tid] : emb0[(size_t)(l + NUSERS)*DD + tid];
            kv = KU[t*DD + tid];
        } else if (tid < 256) {
            int d = tid - 128;
            xs[tid] = (pu >= 0) ? NEWU[pu*DD + d] : emb0[(size_t)u*DD + d];
            kv = KL[t*DD + d];
        }
        __syncthreads();                               // B1

        float acc = 0.f;
        {
            const float* xp = xs + h*128;
            #pragma unroll
            for (int j = 0; j < 128; ++j) acc += w[j] * xp[j];
        }
        partial[tid] = acc;
        __syncthreads();                               // B2

        float th = 0.f;
        if (tid < 256) {
            float pre = partial[tid] + partial[256 + tid] + kv;
            th = tanhf(pre);
            float ss = th * th;
            #pragma unroll
            for (int o = 32; o > 0; o >>= 1) ss += __shfl_xor(ss, o, 64);
            if (lane == 0) wsum[wid] = ss;
        }
        __syncthreads();                               // B3

        if (tid < 256) {
            float S  = (tid < 128) ? (wsum[0] + wsum[1]) : (wsum[2] + wsum[3]);
            float sf = 1.f / fmaxf(sqrtf(S), 1e-12f);
            float v2 = th * sf;
            float old = (tid < 128) ? xs[128 + tid] : xs[tid - 128];
            if (tid < 128) NEWU[t*DD + tid]       = v2;
            else           NEWL[t*DD + (tid-128)] = v2;
            float dd = v2 - old;
            float s2 = dd * dd;
            #pragma unroll
            for (int o = 32; o > 0; o >>= 1) s2 += __shfl_xor(s2, o, 64);
            if (lane == 0) wsum[4 + wid] = s2;
        }
        __syncthreads();                               // B4
        if (tid == 0)
            DRIFT[t] = (wsum[4] + wsum[5] + wsum[6] + wsum[7]) * (1.f / 128.f);
    }
}

// Wide epilogue: Zb (bf16), ELT, scatter-last.
__global__ __launch_bounds__(256) void build_z(const int* __restrict__ ev,
    const float* __restrict__ emb0, const float* __restrict__ du,
    const float* __restrict__ pw, const float* __restrict__ projb,
    const float* __restrict__ kg,
    const float* __restrict__ NEWU, const float* __restrict__ NEWL,
    unsigned short* __restrict__ Zb, float* __restrict__ ELT,
    float* __restrict__ out, const int* __restrict__ ibase) {
    const int gsz = gridDim.x * blockDim.x;
    const int gid = blockIdx.x * blockDim.x + threadIdx.x;

    for (int i = gid; i < T_STEPS*320; i += gsz) {
        int t = i / 320, j = i - t*320;
        float zv;
        if (j < 128) {
            int pu = ibase[IO_PU + t];
            int uu = ev[t*5];
            float eu = (pu >= 0) ? NEWU[pu*DD + j] : emb0[(size_t)uu*DD + j];
            zv = eu * (1.f + pw[j]*du[t] + projb[j]);
        } else if (j < 256) {
            int jj = j - 128;
            int pp = ibase[IO_PP + t];
            int pv = ev[t*5 + 2];
            zv = (pp >= 0) ? NEWL[pp*DD + jj] : emb0[(size_t)(pv + NUSERS)*DD + jj];
        } else {
            int kp = ev[t*5 + 3];
            zv = kg[kp*KK + (j - 256)];
        }
        Zb[i] = f2bf(zv);
    }
    for (int i = gid; i < DD*T_STEPS; i += gsz) {     // ELT[d][t]
        int d = i >> 11, t = i & 2047;
        int pl = ibase[IO_PL + t];
        int l  = ev[t*5 + 1];
        ELT[i] = (pl >= 0) ? NEWL[pl*DD + d] : emb0[(size_t)(l + NUSERS)*DD + d];
    }
    for (int i = gid; i < T_STEPS*DD; i += gsz) {     // scatter last-occurrence
        int t = i >> 7, d = i & 127;
        if (ibase[IO_LASTU + t]) out[(size_t)ev[t*5]*DD + d]            = NEWU[i];
        if (ibase[IO_LASTL + t]) out[(size_t)(ev[t*5+1]+NUSERS)*DD + d] = NEWL[i];
    }
}

// Convert predw's dense 320-col slice to bf16 (rows padded to WB_ROWS with 0).
__global__ __launch_bounds__(256) void convw(const float* __restrict__ predw,
                                             unsigned short* __restrict__ Wb) {
    const int gsz = gridDim.x * blockDim.x;
    for (int i = blockIdx.x * blockDim.x + threadIdx.x; i < WB_ROWS*80; i += gsz) {
        int r = i / 80, kc = (i - r*80) * 4;
        unsigned short o0 = 0, o1 = 0, o2 = 0, o3 = 0;
        if (r < PRED_OUT) {
            const float4 v = *(const float4*)(predw + (size_t)r*PRED_IN + kc);
            o0 = f2bf(v.x); o1 = f2bf(v.y); o2 = f2bf(v.z); o3 = f2bf(v.w);
        }
        unsigned short* dst = Wb + (size_t)r*320 + kc;
        dst[0] = o0; dst[1] = o1; dst[2] = o2; dst[3] = o3;
    }
}

// MFMA GEMM: S[r][t] = sum_k W[r][k]*Z[t][k]. 128x128 block tile, 4 waves (2x2),
// 64x64 per wave = 4x4 fragments of mfma_f32_16x16x32_bf16. No LDS: per-lane
// 16B loads are 64B-line coalesced per row; W/Z bf16 tiles are L2-resident.
// Layout (m89-verified): A row=l&15 k=(l>>4)*8+j; B col=l&15 same k;
// D col=l&15 row=(l>>4)*4+reg.
__global__ __launch_bounds__(256) void pred_dense_mfma(
    const unsigned short* __restrict__ Wb, const unsigned short* __restrict__ Zb,
    float* __restrict__ S, int NT, int t0) {
    const int tid = threadIdx.x;
    const int l   = tid & 63;
    const int w   = tid >> 6;
    const int wr  = w >> 1, wc = w & 1;
    const int lr  = l & 15;
    const int kg8 = (l >> 4) * 8;
    const int r0  = blockIdx.y * 128 + wr * 64;
    const int tt0 = blockIdx.x * 128 + wc * 64;

    f32x4 acc[4][4];
    #pragma unroll
    for (int m = 0; m < 4; ++m)
        #pragma unroll
        for (int n = 0; n < 4; ++n) acc[m][n] = (f32x4){0.f, 0.f, 0.f, 0.f};

    for (int k0 = 0; k0 < 320; k0 += 32) {
        short8v a[4], b[4];
        #pragma unroll
        for (int m = 0; m < 4; ++m)
            a[m] = *(const short8v*)(Wb + (size_t)(r0 + m*16 + lr)*320 + k0 + kg8);
        #pragma unroll
        for (int n = 0; n < 4; ++n)
            b[n] = *(const short8v*)(Zb + (size_t)(t0 + tt0 + n*16 + lr)*320 + k0 + kg8);
        #pragma unroll
        for (int m = 0; m < 4; ++m)
            #pragma unroll
            for (int n = 0; n < 4; ++n)
                acc[m][n] = __builtin_amdgcn_mfma_f32_16x16x32_bf16(a[m], b[n], acc[m][n], 0, 0, 0);
    }

    const int orow = (l >> 4) * 4;
    #pragma unroll
    for (int m = 0; m < 4; ++m) {
        #pragma unroll
        for (int i = 0; i < 4; ++i) {
            int r = r0 + m*16 + orow + i;
            if (r < PRED_OUT) {
                float* dst = S + (size_t)r*NT + tt0 + lr;
                #pragma unroll
                for (int n = 0; n < 4; ++n) dst[n*16] = acc[m][n][i];
            }
        }
    }
}

// Row-centric scatter+finalize: 256 threads/block (4 waves), one row per block.
__global__ __launch_bounds__(256) void pred_scatter(const int* __restrict__ ev,
    const float* __restrict__ predw, const float* __restrict__ predb,
    const float* __restrict__ kg, const float* __restrict__ S,
    const float* __restrict__ ELT, float* __restrict__ rowp,
    int NT, int t0, int chunk) {
    __shared__ float srow[NLOCAS + NUSERS];   // 32 KB
    __shared__ float red[4];
    const int tid = threadIdx.x;
    const int lane = tid & 63, wid = tid >> 6;
    const int r = blockIdx.x;
    const float* base = predw + (size_t)r*PRED_IN + 320;
    #pragma unroll
    for (int i = 0; i < 8; ++i) {
        int idx = (tid + i*256) * 4;
        if (idx < NLOCAS + NUSERS) {
            float4 v = *(const float4*)(base + idx);
            *(float4*)(srow + idx) = v;
        }
    }
    __syncthreads();
    const float bias = predb[r];
    const int mode = (r < DD) ? 0 : (r < DD + NLOCAS ? 1 : 2);
    float lsum = 0.f;
    for (int tloc = tid; tloc < NT; tloc += 256) {
        int t = t0 + tloc;
        int pv = ev[t*5 + 2];
        int uu = ev[t*5 + 0];
        float v = S[(size_t)r*NT + tloc] + bias + srow[pv] + srow[NLOCAS + uu];
        float tv;
        if (mode == 0)      tv = ELT[r*T_STEPS + t];
        else if (mode == 1) tv = (pv == r - DD) ? 1.f : 0.f;
        else                tv = kg[ev[t*5+4]*KK + (r - DD - NLOCAS)];
        float d = v - tv;
        lsum += d*d;
    }
    #pragma unroll
    for (int o = 32; o > 0; o >>= 1) lsum += __shfl_xor(lsum, o, 64);
    if (lane == 0) red[wid] = lsum;
    __syncthreads();
    if (tid == 0) rowp[chunk*PRED_OUT + r] = red[0] + red[1] + red[2] + red[3];
}

__global__ __launch_bounds__(256) void final_reduce(const float* __restrict__ rowp,
                                                    const float* __restrict__ drift,
                                                    float* __restrict__ out, int nchunk) {
    int tid = threadIdx.x;
    float s = 0.f;
    for (int i = tid; i < nchunk*PRED_OUT; i += 256) s += rowp[i];
    s *= (1.0f / PRED_OUT);
    for (int i = tid; i < T_STEPS; i += 256) s += drift[i];
    #pragma unroll
    for (int o = 32; o > 0; o >>= 1) s += __shfl_xor(s, o, 64);
    __shared__ float red[4];
    if ((tid & 63) == 0) red[tid >> 6] = s;
    __syncthreads();
    if (tid == 0) out[OUT_EMB] = red[0] + red[1] + red[2] + red[3];
}

extern "C" void kernel_launch(void* const* d_in, const int* in_sizes, int n_in,
                              void* d_out, int out_size, void* d_ws, size_t ws_size,
                              hipStream_t stream) {
    const float* emb_in = (const float*)d_in[0];
    const int*   ev     = (const int*)  d_in[1];
    const float* du     = (const float*)d_in[2];
    const float* dl     = (const float*)d_in[3];
    const float* kg     = (const float*)d_in[4];
    const float* wihu   = (const float*)d_in[5];
    const float* whhu   = (const float*)d_in[6];
    const float* bihu   = (const float*)d_in[7];
    const float* bhhu   = (const float*)d_in[8];
    const float* wihl   = (const float*)d_in[9];
    const float* whhl   = (const float*)d_in[10];
    const float* bihl   = (const float*)d_in[11];
    const float* bhhl   = (const float*)d_in[12];
    const float* projw  = (const float*)d_in[13];
    const float* projb  = (const float*)d_in[14];
    const float* predw  = (const float*)d_in[15];
    const float* predb  = (const float*)d_in[16];

    float* out = (float*)d_out;
    float* ws  = (float*)d_ws;
    float* NEWU  = ws + WS_NEWU;
    float* NEWL  = ws + WS_NEWL;
    float* KU    = ws + WS_KU;
    float* KL    = ws + WS_KL;
    unsigned short* Zb = (unsigned short*)(ws + WS_ZB);
    unsigned short* Wb = (unsigned short*)(ws + WS_WB);
    float* ELT   = ws + WS_ELT;
    float* DRIFT = ws + WS_DRIFT;
    float* ROWP  = ws + WS_ROWP;
    float* S     = ws + WS_S;
    int*   ibase = (int*)(ws + WS_INT);

    long avail = (long)(ws_size / 4) - WS_S;
    int NT = 2048;
    while (NT > 128 && (long)PRED_OUT * NT > avail) NT >>= 1;
    int nchunk = T_STEPS / NT;

    init_kernel<<<2048, 256, 0, stream>>>(emb_in, out);
    preds_kernel<<<T_STEPS/4, 256, 0, stream>>>(ev, ibase);
    levels_kernel<<<1, 1024, 0, stream>>>(ibase);
    precomp_k<<<T_STEPS, 128, 0, stream>>>(ev, du, dl, kg, wihu, bihu, bhhu,
                                           wihl, bihl, bhhl, KU, KL);
    convw<<<1320, 256, 0, stream>>>(predw, Wb);
    for (int lv = 0; lv < TAIL_LV; ++lv)
        chain_sweep<<<256, 512, 0, stream>>>(lv, ev, emb_in, wihu, whhu, whhl, wihl,
                                             KU, KL, NEWU, NEWL, DRIFT, ibase);
    chain_tail<<<1, 512, 0, stream>>>(ev, emb_in, wihu, whhu, whhl, wihl,
                                      KU, KL, NEWU, NEWL, DRIFT, ibase);
    build_z<<<1024, 256, 0, stream>>>(ev, emb_in, du, projw, projb, kg,
                                      NEWU, NEWL, Zb, ELT, out, ibase);
    for (int c = 0; c < nchunk; ++c) {
        int t0 = c * NT;
        pred_dense_mfma<<<dim3(NT/128, 33), 256, 0, stream>>>(Wb, Zb, S, NT, t0);
        pred_scatter<<<PRED_OUT, 256, 0, stream>>>(ev, predw, predb, kg, S, ELT,
                                                   ROWP, NT, t0, c);
    }
    final_reduce<<<1, 256, 0, stream>>>(ROWP, DRIFT, out, nchunk);
}

// Round 10
// 204.321 us; speedup vs baseline: 22.5830x; 1.0363x over previous
//
#include <hip/hip_runtime.h>

#define T_STEPS 2048
#define NUSERS 4000
#define NLOCAS 4000
#define DD 128
#define KK 64
#define PRED_OUT 4192
#define PRED_IN 8256
#define OUT_EMB 1024000   // 8000*128
#define TAIL_LV 8
#define WB_ROWS 4224      // 4192 padded to 33*128

typedef __attribute__((ext_vector_type(8))) short short8v;
typedef __attribute__((ext_vector_type(4))) float f32x4;

// ---- ws layout (float offsets) ----
#define WS_NEWU   0          // 262144
#define WS_NEWL   262144
#define WS_KU     524288
#define WS_KL     786432
#define WS_ZB     1048576    // 2048*320 ushort = 327680 float slots
#define WS_WB     1376256    // 4224*320 ushort = 675840 float slots
#define WS_ELT    2052096    // 128*2048
#define WS_DRIFT  2314240    // 2048
#define WS_ROWP   2316288    // 4192*16 max
#define WS_INT    2450432    // 14400 ints
#define WS_S      2464832    // 4192*NT floats
// ---- int offsets within WS_INT ----
#define IO_PU     0
#define IO_PL     2048
#define IO_PP     4096
#define IO_LASTU  6144
#define IO_LASTL  8192
#define IO_ORDER  10240
#define IO_OFF    12288      // 2049 entries
#define IO_NLEV   14337

__device__ inline unsigned short f2bf(float f) {
    unsigned int x = __float_as_uint(f);
    unsigned int r = (x + 0x7FFFu + ((x >> 16) & 1u)) >> 16;
    return (unsigned short)r;
}

// Fused prep: blocks 0..511 = wave-parallel preds scan (4 t/block);
// blocks 512..1023 = precomp_k (4 t/block) + grid-stride {init copy, convw}.
__global__ __launch_bounds__(256) void prep_kernel(const int* __restrict__ ev,
    const float* __restrict__ emb_in, const float* __restrict__ du,
    const float* __restrict__ dl, const float* __restrict__ kg,
    const float* __restrict__ wihu, const float* __restrict__ bihu,
    const float* __restrict__ bhhu, const float* __restrict__ wihl,
    const float* __restrict__ bihl, const float* __restrict__ bhhl,
    const float* __restrict__ predw,
    float* __restrict__ out, float* __restrict__ KU, float* __restrict__ KL,
    unsigned short* __restrict__ Wb, int* __restrict__ ibase) {
    __shared__ int su[T_STEPS];
    __shared__ int sl[T_STEPS];
    __shared__ float skg[4][KK];
    __shared__ int kn4[4];
    const int tid = threadIdx.x;

    if (blockIdx.x < 512) {
        // ---- preds scan ----
        const int lane = tid & 63;
        const int wid  = tid >> 6;
        for (int i = tid; i < T_STEPS; i += 256) { su[i] = ev[i*5]; sl[i] = ev[i*5+1]; }
        __syncthreads();

        const int t = blockIdx.x * 4 + wid;
        const int u = su[t], l = sl[t], p = ev[t*5 + 2];

        int pu = -1, pl = -1, pp = -1;
        {
            int round = 0;
            while (true) {
                const int q = t - 1 - lane - (round << 6);
                const int squ = (q >= 0) ? su[q] : -1;
                const int sql = (q >= 0) ? sl[q] : -1;
                if (pu < 0) {
                    unsigned long long b = __ballot(squ == u);
                    if (b) pu = t - 1 - (__ffsll(b) - 1) - (round << 6);
                }
                if (pl < 0) {
                    unsigned long long b = __ballot(sql == l);
                    if (b) pl = t - 1 - (__ffsll(b) - 1) - (round << 6);
                }
                if (pp < 0) {
                    unsigned long long b = __ballot(sql == p);
                    if (b) pp = t - 1 - (__ffsll(b) - 1) - (round << 6);
                }
                ++round;
                if ((pu >= 0 && pl >= 0 && pp >= 0) || (t - 1 - (round << 6) < 0)) break;
            }
        }
        int lastu = 1, lastl = 1;
        {
            int round = 0;
            while (true) {
                const int q = t + 1 + lane + (round << 6);
                const int squ = (q < T_STEPS) ? su[q] : -1;
                const int sql = (q < T_STEPS) ? sl[q] : -1;
                if (lastu && __ballot(squ == u)) lastu = 0;
                if (lastl && __ballot(sql == l)) lastl = 0;
                ++round;
                if ((!lastu && !lastl) || (t + 1 + (round << 6) >= T_STEPS)) break;
            }
        }
        if (lane == 0) {
            ibase[IO_PU + t] = pu;
            ibase[IO_PL + t] = pl;
            ibase[IO_PP + t] = pp;
            ibase[IO_LASTU + t] = lastu;
            ibase[IO_LASTL + t] = lastl;
        }
        return;
    }

    // ---- precomp_k for 4 t ----
    const int pb = blockIdx.x - 512;
    if (tid < 4) kn4[tid] = ev[(pb*4 + tid)*5 + 4];
    __syncthreads();
    skg[tid >> 6][tid & 63] = kg[kn4[tid >> 6]*KK + (tid & 63)];
    __syncthreads();
    #pragma unroll
    for (int p = 0; p < 2; ++p) {
        const int sub = p*2 + (tid >> 7);
        const int t = pb*4 + sub;
        const int r = tid & 127;
        const float* wu = wihu + r*193;
        const float* wl = wihl + r*193;
        const float dut = du[t], dlt = dl[t];
        float ku = bihu[r] + bhhu[r] + wu[192]*dut;
        float kl = bihl[r] + bhhl[r] + wl[192]*dlt;
        const float* sk = skg[sub];
        #pragma unroll
        for (int j = 0; j < KK; ++j) {
            float s = sk[j];
            ku += wu[128+j]*s;
            kl += wl[128+j]*s;
        }
        KU[t*DD + r] = ku;
        KL[t*DD + r] = kl;
    }

    // ---- init copy (float4) + convw, grid-stride over B-blocks ----
    const int gsz = 512 * 256;
    const int gid = pb * 256 + tid;
    for (int i = gid; i < OUT_EMB/4; i += gsz)
        ((float4*)out)[i] = ((const float4*)emb_in)[i];
    for (int i = gid; i < WB_ROWS*80; i += gsz) {
        int r = i / 80, kc = (i - r*80) * 4;
        unsigned short o0 = 0, o1 = 0, o2 = 0, o3 = 0;
        if (r < PRED_OUT) {
            const float4 v = *(const float4*)(predw + (size_t)r*PRED_IN + kc);
            o0 = f2bf(v.x); o1 = f2bf(v.y); o2 = f2bf(v.z); o3 = f2bf(v.w);
        }
        unsigned short* dst = Wb + (size_t)r*320 + kc;
        dst[0] = o0; dst[1] = o1; dst[2] = o2; dst[3] = o3;
    }
}

// DAG levels via monotone fixpoint; counting sort into ORDER with OFF[], NLEV.
__global__ __launch_bounds__(1024) void levels_kernel(int* __restrict__ ibase) {
    __shared__ int lev[T_STEPS];
    __shared__ int spu[T_STEPS];
    __shared__ int spl[T_STEPS];
    __shared__ int cnt[T_STEPS + 1];
    __shared__ int changed;
    __shared__ int smax;
    const int tid = threadIdx.x;

    for (int i = tid; i < T_STEPS; i += 1024) {
        spu[i] = ibase[IO_PU + i];
        spl[i] = ibase[IO_PL + i];
        lev[i] = 0;
    }
    if (tid == 0) smax = 0;
    __syncthreads();

    while (true) {
        if (tid == 0) changed = 0;
        __syncthreads();
        for (int i = tid; i < T_STEPS; i += 1024) {
            int nl = 0, a = spu[i], b = spl[i];
            if (a >= 0) nl = lev[a] + 1;
            if (b >= 0) { int v = lev[b] + 1; if (v > nl) nl = v; }
            if (nl > lev[i]) { lev[i] = nl; changed = 1; }
        }
        __syncthreads();
        if (!changed) break;
        __syncthreads();
    }

    for (int i = tid; i <= T_STEPS; i += 1024) cnt[i] = 0;
    __syncthreads();
    for (int i = tid; i < T_STEPS; i += 1024) {
        atomicAdd(&cnt[lev[i]], 1);
        atomicMax(&smax, lev[i]);
    }
    __syncthreads();
    if (tid == 0) {
        int nlev = smax + 1;
        int acc = 0;
        for (int k = 0; k < nlev; ++k) {
            ibase[IO_OFF + k] = acc;
            int c = cnt[k]; cnt[k] = acc; acc += c;
        }
        ibase[IO_OFF + nlev] = acc;
        ibase[IO_NLEV] = nlev;
        for (int k = nlev + 1; k <= TAIL_LV; ++k) ibase[IO_OFF + k] = acc;
    }
    __syncthreads();
    for (int i = tid; i < T_STEPS; i += 1024) {
        int pos = atomicAdd(&cnt[lev[i]], 1);
        ibase[IO_ORDER + pos] = i;
    }
}

// One DAG level per launch (levels 0..TAIL_LV-1). 256 blocks x 512 threads.
__global__ __launch_bounds__(512) void chain_sweep(int lv, const int* __restrict__ ev,
    const float* __restrict__ emb0,
    const float* __restrict__ wihu, const float* __restrict__ whhu,
    const float* __restrict__ whhl, const float* __restrict__ wihl,
    const float* __restrict__ KU, const float* __restrict__ KL,
    float* __restrict__ NEWU, float* __restrict__ NEWL, float* __restrict__ DRIFT,
    const int* __restrict__ ibase) {
    const int start = ibase[IO_OFF + lv];
    const int end   = ibase[IO_OFF + lv + 1];
    if ((int)blockIdx.x >= end - start) return;

    const int tid  = threadIdx.x;
    const int h    = tid >> 8;
    const int r    = tid & 255;
    const int lane = tid & 63;
    const int wid  = tid >> 6;

    float w[128];
    {
        const float* src;
        if (h == 0) src = (r < 128) ? (wihu + r*193) : (whhl + (r-128)*128);
        else        src = (r < 128) ? (whhu + r*128) : (wihl + (r-128)*193);
        #pragma unroll
        for (int j = 0; j < 32; ++j) {
            const float4 v = *(const float4*)(src + j*4);
            w[j*4+0] = v.x; w[j*4+1] = v.y; w[j*4+2] = v.z; w[j*4+3] = v.w;
        }
    }

    __shared__ float xs[256];
    __shared__ float partial[512];
    __shared__ float wsum[8];

    for (int s = start + blockIdx.x; s < end; s += gridDim.x) {
        const int t  = ibase[IO_ORDER + s];
        const int u  = ev[t*5];
        const int l  = ev[t*5 + 1];
        const int pu = ibase[IO_PU + t];
        const int pl = ibase[IO_PL + t];

        float kv = 0.f;
        if (tid < 128) {
            xs[tid] = (pl >= 0) ? NEWL[pl*DD + tid] : emb0[(size_t)(l + NUSERS)*DD + tid];
            kv = KU[t*DD + tid];
        } else if (tid < 256) {
            int d = tid - 128;
            xs[tid] = (pu >= 0) ? NEWU[pu*DD + d] : emb0[(size_t)u*DD + d];
            kv = KL[t*DD + d];
        }
        __syncthreads();                               // B1

        float acc = 0.f;
        {
            const float* xp = xs + h*128;
            #pragma unroll
            for (int j = 0; j < 128; ++j) acc += w[j] * xp[j];
        }
        partial[tid] = acc;
        __syncthreads();                               // B2

        float th = 0.f;
        if (tid < 256) {
            float pre = partial[tid] + partial[256 + tid] + kv;
            th = tanhf(pre);
            float ss = th * th;
            #pragma unroll
            for (int o = 32; o > 0; o >>= 1) ss += __shfl_xor(ss, o, 64);
            if (lane == 0) wsum[wid] = ss;
        }
        __syncthreads();                               // B3

        if (tid < 256) {
            float S  = (tid < 128) ? (wsum[0] + wsum[1]) : (wsum[2] + wsum[3]);
            float sf = 1.f / fmaxf(sqrtf(S), 1e-12f);
            float v2 = th * sf;
            float old = (tid < 128) ? xs[128 + tid] : xs[tid - 128];
            if (tid < 128) NEWU[t*DD + tid]       = v2;
            else           NEWL[t*DD + (tid-128)] = v2;
            float dd = v2 - old;
            float s2 = dd * dd;
            #pragma unroll
            for (int o = 32; o > 0; o >>= 1) s2 += __shfl_xor(s2, o, 64);
            if (lane == 0) wsum[4 + wid] = s2;
        }
        __syncthreads();                               // B4
        if (tid == 0)
            DRIFT[t] = (wsum[4] + wsum[5] + wsum[6] + wsum[7]) * (1.f / 128.f);
    }
}

// Tail: ONE block processes ALL levels >= TAIL_LV sequentially in level order.
__global__ __launch_bounds__(512) void chain_tail(const int* __restrict__ ev,
    const float* __restrict__ emb0,
    const float* __restrict__ wihu, const float* __restrict__ whhu,
    const float* __restrict__ whhl, const float* __restrict__ wihl,
    const float* __restrict__ KU, const float* __restrict__ KL,
    float* __restrict__ NEWU, float* __restrict__ NEWL, float* __restrict__ DRIFT,
    const int* __restrict__ ibase) {
    const int nlev = ibase[IO_NLEV];
    if (nlev <= TAIL_LV) return;
    const int start = ibase[IO_OFF + TAIL_LV];
    const int end   = ibase[IO_OFF + nlev];

    const int tid  = threadIdx.x;
    const int h    = tid >> 8;
    const int r    = tid & 255;
    const int lane = tid & 63;
    const int wid  = tid >> 6;

    float w[128];
    {
        const float* src;
        if (h == 0) src = (r < 128) ? (wihu + r*193) : (whhl + (r-128)*128);
        else        src = (r < 128) ? (whhu + r*128) : (wihl + (r-128)*193);
        #pragma unroll
        for (int j = 0; j < 32; ++j) {
            const float4 v = *(const float4*)(src + j*4);
            w[j*4+0] = v.x; w[j*4+1] = v.y; w[j*4+2] = v.z; w[j*4+3] = v.w;
        }
    }

    __shared__ float xs[256];
    __shared__ float partial[512];
    __shared__ float wsum[8];

    for (int s = start; s < end; ++s) {
        const int t  = ibase[IO_ORDER + s];
        const int u  = ev[t*5];
        const int l  = ev[t*5 + 1];
        const int pu = ibase[IO_PU + t];
        const int pl = ibase[IO_PL + t];

        float kv = 0.f;
        if (tid < 128) {
            xs[tid] = (pl >= 0) ? NEWL[pl*DD + tid] : emb0[(size_t)(l + NUSERS)*DD + tid];
            kv = KU[t*DD + tid];
        } else if (tid < 256) {
            int d = tid - 128;
            xs[tid] = (pu >= 0) ? NEWU[pu*DD + d] : emb0[(size_t)u*DD + d];
            kv = KL[t*DD + d];
        }
        __syncthreads();                               // B1

        float acc = 0.f;
        {
            const float* xp = xs + h*128;
            #pragma unroll
            for (int j = 0; j < 128; ++j) acc += w[j] * xp[j];
        }
        partial[tid] = acc;
        __syncthreads();                               // B2

        float th = 0.f;
        if (tid < 256) {
            float pre = partial[tid] + partial[256 + tid] + kv;
            th = tanhf(pre);
            float ss = th * th;
            #pragma unroll
            for (int o = 32; o > 0; o >>= 1) ss += __shfl_xor(ss, o, 64);
            if (lane == 0) wsum[wid] = ss;
        }
        __syncthreads();                               // B3

        if (tid < 256) {
            float S  = (tid < 128) ? (wsum[0] + wsum[1]) : (wsum[2] + wsum[3]);
            float sf = 1.f / fmaxf(sqrtf(S), 1e-12f);
            float v2 = th * sf;
            float old = (tid < 128) ? xs[128 + tid] : xs[tid - 128];
            if (tid < 128) NEWU[t*DD + tid]       = v2;
            else           NEWL[t*DD + (tid-128)] = v2;
            float dd = v2 - old;
            float s2 = dd * dd;
            #pragma unroll
            for (int o = 32; o > 0; o >>= 1) s2 += __shfl_xor(s2, o, 64);
            if (lane == 0) wsum[4 + wid] = s2;
        }
        __syncthreads();                               // B4
        if (tid == 0)
            DRIFT[t] = (wsum[4] + wsum[5] + wsum[6] + wsum[7]) * (1.f / 128.f);
    }
}

// Wide epilogue: Zb (bf16), ELT, scatter-last.
__global__ __launch_bounds__(256) void build_z(const int* __restrict__ ev,
    const float* __restrict__ emb0, const float* __restrict__ du,
    const float* __restrict__ pw, const float* __restrict__ projb,
    const float* __restrict__ kg,
    const float* __restrict__ NEWU, const float* __restrict__ NEWL,
    unsigned short* __restrict__ Zb, float* __restrict__ ELT,
    float* __restrict__ out, const int* __restrict__ ibase) {
    const int gsz = gridDim.x * blockDim.x;
    const int gid = blockIdx.x * blockDim.x + threadIdx.x;

    for (int i = gid; i < T_STEPS*320; i += gsz) {
        int t = i / 320, j = i - t*320;
        float zv;
        if (j < 128) {
            int pu = ibase[IO_PU + t];
            int uu = ev[t*5];
            float eu = (pu >= 0) ? NEWU[pu*DD + j] : emb0[(size_t)uu*DD + j];
            zv = eu * (1.f + pw[j]*du[t] + projb[j]);
        } else if (j < 256) {
            int jj = j - 128;
            int pp = ibase[IO_PP + t];
            int pv = ev[t*5 + 2];
            zv = (pp >= 0) ? NEWL[pp*DD + jj] : emb0[(size_t)(pv + NUSERS)*DD + jj];
        } else {
            int kp = ev[t*5 + 3];
            zv = kg[kp*KK + (j - 256)];
        }
        Zb[i] = f2bf(zv);
    }
    for (int i = gid; i < DD*T_STEPS; i += gsz) {     // ELT[d][t]
        int d = i >> 11, t = i & 2047;
        int pl = ibase[IO_PL + t];
        int l  = ev[t*5 + 1];
        ELT[i] = (pl >= 0) ? NEWL[pl*DD + d] : emb0[(size_t)(l + NUSERS)*DD + d];
    }
    for (int i = gid; i < T_STEPS*DD; i += gsz) {     // scatter last-occurrence
        int t = i >> 7, d = i & 127;
        if (ibase[IO_LASTU + t]) out[(size_t)ev[t*5]*DD + d]            = NEWU[i];
        if (ibase[IO_LASTL + t]) out[(size_t)(ev[t*5+1]+NUSERS)*DD + d] = NEWL[i];
    }
}

// MFMA GEMM: S[r][t] = sum_k W[r][k]*Z[t][k]. 128x128 block tile, 4 waves (2x2).
__global__ __launch_bounds__(256) void pred_dense_mfma(
    const unsigned short* __restrict__ Wb, const unsigned short* __restrict__ Zb,
    float* __restrict__ S, int NT, int t0) {
    const int tid = threadIdx.x;
    const int l   = tid & 63;
    const int w   = tid >> 6;
    const int wr  = w >> 1, wc = w & 1;
    const int lr  = l & 15;
    const int kg8 = (l >> 4) * 8;
    const int r0  = blockIdx.y * 128 + wr * 64;
    const int tt0 = blockIdx.x * 128 + wc * 64;

    f32x4 acc[4][4];
    #pragma unroll
    for (int m = 0; m < 4; ++m)
        #pragma unroll
        for (int n = 0; n < 4; ++n) acc[m][n] = (f32x4){0.f, 0.f, 0.f, 0.f};

    for (int k0 = 0; k0 < 320; k0 += 32) {
        short8v a[4], b[4];
        #pragma unroll
        for (int m = 0; m < 4; ++m)
            a[m] = *(const short8v*)(Wb + (size_t)(r0 + m*16 + lr)*320 + k0 + kg8);
        #pragma unroll
        for (int n = 0; n < 4; ++n)
            b[n] = *(const short8v*)(Zb + (size_t)(t0 + tt0 + n*16 + lr)*320 + k0 + kg8);
        #pragma unroll
        for (int m = 0; m < 4; ++m)
            #pragma unroll
            for (int n = 0; n < 4; ++n)
                acc[m][n] = __builtin_amdgcn_mfma_f32_16x16x32_bf16(a[m], b[n], acc[m][n], 0, 0, 0);
    }

    const int orow = (l >> 4) * 4;
    #pragma unroll
    for (int m = 0; m < 4; ++m) {
        #pragma unroll
        for (int i = 0; i < 4; ++i) {
            int r = r0 + m*16 + orow + i;
            if (r < PRED_OUT) {
                float* dst = S + (size_t)r*NT + tt0 + lr;
                #pragma unroll
                for (int n = 0; n < 4; ++n) dst[n*16] = acc[m][n][i];
            }
        }
    }
}

// Row-centric scatter+finalize: 256 threads/block, one row per block; t-loop x4.
__global__ __launch_bounds__(256) void pred_scatter(const int* __restrict__ ev,
    const float* __restrict__ predw, const float* __restrict__ predb,
    const float* __restrict__ kg, const float* __restrict__ S,
    const float* __restrict__ ELT, float* __restrict__ rowp,
    int NT, int t0, int chunk) {
    __shared__ float srow[NLOCAS + NUSERS];   // 32 KB
    __shared__ float red[4];
    const int tid = threadIdx.x;
    const int lane = tid & 63, wid = tid >> 6;
    const int r = blockIdx.x;
    const float* base = predw + (size_t)r*PRED_IN + 320;
    #pragma unroll
    for (int i = 0; i < 8; ++i) {
        int idx = (tid + i*256) * 4;
        if (idx < NLOCAS + NUSERS) {
            float4 v = *(const float4*)(base + idx);
            *(float4*)(srow + idx) = v;
        }
    }
    __syncthreads();
    const float bias = predb[r];
    const int mode = (r < DD) ? 0 : (r < DD + NLOCAS ? 1 : 2);
    float lsum = 0.f;
    for (int tb = tid*4; tb < NT; tb += 1024) {
        const float4 sv = *(const float4*)(S + (size_t)r*NT + tb);
        const float sa[4] = {sv.x, sv.y, sv.z, sv.w};
        #pragma unroll
        for (int q = 0; q < 4; ++q) {
            int t = t0 + tb + q;
            int pv = ev[t*5 + 2];
            int uu = ev[t*5 + 0];
            float v = sa[q] + bias + srow[pv] + srow[NLOCAS + uu];
            float tv;
            if (mode == 0)      tv = ELT[r*T_STEPS + t];
            else if (mode == 1) tv = (pv == r - DD) ? 1.f : 0.f;
            else                tv = kg[ev[t*5+4]*KK + (r - DD - NLOCAS)];
            float d = v - tv;
            lsum += d*d;
        }
    }
    #pragma unroll
    for (int o = 32; o > 0; o >>= 1) lsum += __shfl_xor(lsum, o, 64);
    if (lane == 0) red[wid] = lsum;
    __syncthreads();
    if (tid == 0) rowp[chunk*PRED_OUT + r] = red[0] + red[1] + red[2] + red[3];
}

__global__ __launch_bounds__(256) void final_reduce(const float* __restrict__ rowp,
                                                    const float* __restrict__ drift,
                                                    float* __restrict__ out, int nchunk) {
    int tid = threadIdx.x;
    float s = 0.f;
    for (int i = tid; i < nchunk*PRED_OUT; i += 256) s += rowp[i];
    s *= (1.0f / PRED_OUT);
    for (int i = tid; i < T_STEPS; i += 256) s += drift[i];
    #pragma unroll
    for (int o = 32; o > 0; o >>= 1) s += __shfl_xor(s, o, 64);
    __shared__ float red[4];
    if ((tid & 63) == 0) red[tid >> 6] = s;
    __syncthreads();
    if (tid == 0) out[OUT_EMB] = red[0] + red[1] + red[2] + red[3];
}

extern "C" void kernel_launch(void* const* d_in, const int* in_sizes, int n_in,
                              void* d_out, int out_size, void* d_ws, size_t ws_size,
                              hipStream_t stream) {
    const float* emb_in = (const float*)d_in[0];
    const int*   ev     = (const int*)  d_in[1];
    const float* du     = (const float*)d_in[2];
    const float* dl     = (const float*)d_in[3];
    const float* kg     = (const float*)d_in[4];
    const float* wihu   = (const float*)d_in[5];
    const float* whhu   = (const float*)d_in[6];
    const float* bihu   = (const float*)d_in[7];
    const float* bhhu   = (const float*)d_in[8];
    const float* wihl   = (const float*)d_in[9];
    const float* whhl   = (const float*)d_in[10];
    const float* bihl   = (const float*)d_in[11];
    const float* bhhl   = (const float*)d_in[12];
    const float* projw  = (const float*)d_in[13];
    const float* projb  = (const float*)d_in[14];
    const float* predw  = (const float*)d_in[15];
    const float* predb  = (const float*)d_in[16];

    float* out = (float*)d_out;
    float* ws  = (float*)d_ws;
    float* NEWU  = ws + WS_NEWU;
    float* NEWL  = ws + WS_NEWL;
    float* KU    = ws + WS_KU;
    float* KL    = ws + WS_KL;
    unsigned short* Zb = (unsigned short*)(ws + WS_ZB);
    unsigned short* Wb = (unsigned short*)(ws + WS_WB);
    float* ELT   = ws + WS_ELT;
    float* DRIFT = ws + WS_DRIFT;
    float* ROWP  = ws + WS_ROWP;
    float* S     = ws + WS_S;
    int*   ibase = (int*)(ws + WS_INT);

    long avail = (long)(ws_size / 4) - WS_S;
    int NT = 2048;
    while (NT > 128 && (long)PRED_OUT * NT > avail) NT >>= 1;
    int nchunk = T_STEPS / NT;

    prep_kernel<<<1024, 256, 0, stream>>>(ev, emb_in, du, dl, kg,
                                          wihu, bihu, bhhu, wihl, bihl, bhhl,
                                          predw, out, KU, KL, Wb, ibase);
    levels_kernel<<<1, 1024, 0, stream>>>(ibase);
    for (int lv = 0; lv < TAIL_LV; ++lv)
        chain_sweep<<<256, 512, 0, stream>>>(lv, ev, emb_in, wihu, whhu, whhl, wihl,
                                             KU, KL, NEWU, NEWL, DRIFT, ibase);
    chain_tail<<<1, 512, 0, stream>>>(ev, emb_in, wihu, whhu, whhl, wihl,
                                      KU, KL, NEWU, NEWL, DRIFT, ibase);
    build_z<<<1024, 256, 0, stream>>>(ev, emb_in, du, projw, projb, kg,
                                      NEWU, NEWL, Zb, ELT, out, ibase);
    for (int c = 0; c < nchunk; ++c) {
        int t0 = c * NT;
        pred_dense_mfma<<<dim3(NT/128, 33), 256, 0, stream>>>(Wb, Zb, S, NT, t0);
        pred_scatter<<<PRED_OUT, 256, 0, stream>>>(ev, predw, predb, kg, S, ELT,
                                                   ROWP, NT, t0, c);
    }
    final_reduce<<<1, 256, 0, stream>>>(ROWP, DRIFT, out, nchunk);
}

// Round 11
// 190.324 us; speedup vs baseline: 24.2439x; 1.0735x over previous
//
#include <hip/hip_runtime.h>

#define T_STEPS 2048
#define NUSERS 4000
#define NLOCAS 4000
#define DD 128
#define KK 64
#define PRED_OUT 4192
#define PRED_IN 8256
#define OUT_EMB 1024000   // 8000*128
#define TAIL_LV 6
#define WB_ROWS 4224      // 4192 padded to 33*128

typedef __attribute__((ext_vector_type(8))) short short8v;
typedef __attribute__((ext_vector_type(8))) unsigned short ushort8v;
typedef __attribute__((ext_vector_type(4))) float f32x4;

// ---- ws layout (float offsets) ----
#define WS_NEWU   0          // 262144
#define WS_NEWL   262144
#define WS_KU     524288
#define WS_KL     786432
#define WS_ZB     1048576    // 2048*320 ushort = 327680 float slots
#define WS_WB     1376256    // 4224*320 ushort = 675840 float slots
#define WS_ELT    2052096    // 128*2048
#define WS_DRIFT  2314240    // 2048
#define WS_ROWP   2316288    // 4192*16 max
#define WS_INT    2450432    // 14400 ints
#define WS_PVU    2464832    // 2048 int4 = 8192 ints
#define WS_S      2473024    // ushort S[4192*NT]
// ---- int offsets within WS_INT ----
#define IO_PU     0
#define IO_PL     2048
#define IO_PP     4096
#define IO_LASTU  6144
#define IO_LASTL  8192
#define IO_ORDER  10240
#define IO_OFF    12288      // 2049 entries
#define IO_NLEV   14337

__device__ inline unsigned short f2bf(float f) {
    unsigned int x = __float_as_uint(f);
    unsigned int r = (x + 0x7FFFu + ((x >> 16) & 1u)) >> 16;
    return (unsigned short)r;
}
__device__ inline float bf2f(unsigned short u) {
    return __uint_as_float(((unsigned int)u) << 16);
}

// Fused prep: blocks 0..511 = wave-parallel preds scan (4 t/block);
// blocks 512..1023 = precomp_k (4 t/block) + grid-stride {init copy, convw}.
__global__ __launch_bounds__(256) void prep_kernel(const int* __restrict__ ev,
    const float* __restrict__ emb_in, const float* __restrict__ du,
    const float* __restrict__ dl, const float* __restrict__ kg,
    const float* __restrict__ wihu, const float* __restrict__ bihu,
    const float* __restrict__ bhhu, const float* __restrict__ wihl,
    const float* __restrict__ bihl, const float* __restrict__ bhhl,
    const float* __restrict__ predw,
    float* __restrict__ out, float* __restrict__ KU, float* __restrict__ KL,
    unsigned short* __restrict__ Wb, int* __restrict__ ibase) {
    __shared__ int su[T_STEPS];
    __shared__ int sl[T_STEPS];
    __shared__ float skg[4][KK];
    __shared__ int kn4[4];
    const int tid = threadIdx.x;

    if (blockIdx.x < 512) {
        const int lane = tid & 63;
        const int wid  = tid >> 6;
        for (int i = tid; i < T_STEPS; i += 256) { su[i] = ev[i*5]; sl[i] = ev[i*5+1]; }
        __syncthreads();

        const int t = blockIdx.x * 4 + wid;
        const int u = su[t], l = sl[t], p = ev[t*5 + 2];

        int pu = -1, pl = -1, pp = -1;
        {
            int round = 0;
            while (true) {
                const int q = t - 1 - lane - (round << 6);
                const int squ = (q >= 0) ? su[q] : -1;
                const int sql = (q >= 0) ? sl[q] : -1;
                if (pu < 0) {
                    unsigned long long b = __ballot(squ == u);
                    if (b) pu = t - 1 - (__ffsll(b) - 1) - (round << 6);
                }
                if (pl < 0) {
                    unsigned long long b = __ballot(sql == l);
                    if (b) pl = t - 1 - (__ffsll(b) - 1) - (round << 6);
                }
                if (pp < 0) {
                    unsigned long long b = __ballot(sql == p);
                    if (b) pp = t - 1 - (__ffsll(b) - 1) - (round << 6);
                }
                ++round;
                if ((pu >= 0 && pl >= 0 && pp >= 0) || (t - 1 - (round << 6) < 0)) break;
            }
        }
        int lastu = 1, lastl = 1;
        {
            int round = 0;
            while (true) {
                const int q = t + 1 + lane + (round << 6);
                const int squ = (q < T_STEPS) ? su[q] : -1;
                const int sql = (q < T_STEPS) ? sl[q] : -1;
                if (lastu && __ballot(squ == u)) lastu = 0;
                if (lastl && __ballot(sql == l)) lastl = 0;
                ++round;
                if ((!lastu && !lastl) || (t + 1 + (round << 6) >= T_STEPS)) break;
            }
        }
        if (lane == 0) {
            ibase[IO_PU + t] = pu;
            ibase[IO_PL + t] = pl;
            ibase[IO_PP + t] = pp;
            ibase[IO_LASTU + t] = lastu;
            ibase[IO_LASTL + t] = lastl;
        }
        return;
    }

    // ---- precomp_k for 4 t ----
    const int pb = blockIdx.x - 512;
    if (tid < 4) kn4[tid] = ev[(pb*4 + tid)*5 + 4];
    __syncthreads();
    skg[tid >> 6][tid & 63] = kg[kn4[tid >> 6]*KK + (tid & 63)];
    __syncthreads();
    #pragma unroll
    for (int p = 0; p < 2; ++p) {
        const int sub = p*2 + (tid >> 7);
        const int t = pb*4 + sub;
        const int r = tid & 127;
        const float* wu = wihu + r*193;
        const float* wl = wihl + r*193;
        const float dut = du[t], dlt = dl[t];
        float ku = bihu[r] + bhhu[r] + wu[192]*dut;
        float kl = bihl[r] + bhhl[r] + wl[192]*dlt;
        const float* sk = skg[sub];
        #pragma unroll
        for (int j = 0; j < KK; ++j) {
            float s = sk[j];
            ku += wu[128+j]*s;
            kl += wl[128+j]*s;
        }
        KU[t*DD + r] = ku;
        KL[t*DD + r] = kl;
    }

    // ---- init copy (float4) + convw, grid-stride ----
    const int gsz = 512 * 256;
    const int gid = pb * 256 + tid;
    for (int i = gid; i < OUT_EMB/4; i += gsz)
        ((float4*)out)[i] = ((const float4*)emb_in)[i];
    for (int i = gid; i < WB_ROWS*80; i += gsz) {
        int r = i / 80, kc = (i - r*80) * 4;
        unsigned short o0 = 0, o1 = 0, o2 = 0, o3 = 0;
        if (r < PRED_OUT) {
            const float4 v = *(const float4*)(predw + (size_t)r*PRED_IN + kc);
            o0 = f2bf(v.x); o1 = f2bf(v.y); o2 = f2bf(v.z); o3 = f2bf(v.w);
        }
        unsigned short* dst = Wb + (size_t)r*320 + kc;
        dst[0] = o0; dst[1] = o1; dst[2] = o2; dst[3] = o3;
    }
}

// DAG levels via monotone fixpoint; counting sort into ORDER with OFF[], NLEV.
__global__ __launch_bounds__(1024) void levels_kernel(int* __restrict__ ibase) {
    __shared__ int lev[T_STEPS];
    __shared__ int spu[T_STEPS];
    __shared__ int spl[T_STEPS];
    __shared__ int cnt[T_STEPS + 1];
    __shared__ int changed;
    __shared__ int smax;
    const int tid = threadIdx.x;

    for (int i = tid; i < T_STEPS; i += 1024) {
        spu[i] = ibase[IO_PU + i];
        spl[i] = ibase[IO_PL + i];
        lev[i] = 0;
    }
    if (tid == 0) smax = 0;
    __syncthreads();

    while (true) {
        if (tid == 0) changed = 0;
        __syncthreads();
        for (int i = tid; i < T_STEPS; i += 1024) {
            int nl = 0, a = spu[i], b = spl[i];
            if (a >= 0) nl = lev[a] + 1;
            if (b >= 0) { int v = lev[b] + 1; if (v > nl) nl = v; }
            if (nl > lev[i]) { lev[i] = nl; changed = 1; }
        }
        __syncthreads();
        if (!changed) break;
        __syncthreads();
    }

    for (int i = tid; i <= T_STEPS; i += 1024) cnt[i] = 0;
    __syncthreads();
    for (int i = tid; i < T_STEPS; i += 1024) {
        atomicAdd(&cnt[lev[i]], 1);
        atomicMax(&smax, lev[i]);
    }
    __syncthreads();
    if (tid == 0) {
        int nlev = smax + 1;
        int acc = 0;
        for (int k = 0; k < nlev; ++k) {
            ibase[IO_OFF + k] = acc;
            int c = cnt[k]; cnt[k] = acc; acc += c;
        }
        ibase[IO_OFF + nlev] = acc;
        ibase[IO_NLEV] = nlev;
        for (int k = nlev + 1; k <= TAIL_LV; ++k) ibase[IO_OFF + k] = acc;
    }
    __syncthreads();
    for (int i = tid; i < T_STEPS; i += 1024) {
        int pos = atomicAdd(&cnt[lev[i]], 1);
        ibase[IO_ORDER + pos] = i;
    }
}

// One DAG level per launch (levels 0..TAIL_LV-1). 256 blocks x 512 threads.
__global__ __launch_bounds__(512) void chain_sweep(int lv, const int* __restrict__ ev,
    const float* __restrict__ emb0,
    const float* __restrict__ wihu, const float* __restrict__ whhu,
    const float* __restrict__ whhl, const float* __restrict__ wihl,
    const float* __restrict__ KU, const float* __restrict__ KL,
    float* __restrict__ NEWU, float* __restrict__ NEWL, float* __restrict__ DRIFT,
    const int* __restrict__ ibase) {
    const int start = ibase[IO_OFF + lv];
    const int end   = ibase[IO_OFF + lv + 1];
    if ((int)blockIdx.x >= end - start) return;

    const int tid  = threadIdx.x;
    const int h    = tid >> 8;
    const int r    = tid & 255;
    const int lane = tid & 63;
    const int wid  = tid >> 6;

    float w[128];
    {
        const float* src;
        if (h == 0) src = (r < 128) ? (wihu + r*193) : (whhl + (r-128)*128);
        else        src = (r < 128) ? (whhu + r*128) : (wihl + (r-128)*193);
        #pragma unroll
        for (int j = 0; j < 32; ++j) {
            const float4 v = *(const float4*)(src + j*4);
            w[j*4+0] = v.x; w[j*4+1] = v.y; w[j*4+2] = v.z; w[j*4+3] = v.w;
        }
    }

    __shared__ float xs[256];
    __shared__ float partial[512];
    __shared__ float wsum[8];

    for (int s = start + blockIdx.x; s < end; s += gridDim.x) {
        const int t  = ibase[IO_ORDER + s];
        const int u  = ev[t*5];
        const int l  = ev[t*5 + 1];
        const int pu = ibase[IO_PU + t];
        const int pl = ibase[IO_PL + t];

        float kv = 0.f;
        if (tid < 128) {
            xs[tid] = (pl >= 0) ? NEWL[pl*DD + tid] : emb0[(size_t)(l + NUSERS)*DD + tid];
            kv = KU[t*DD + tid];
        } else if (tid < 256) {
            int d = tid - 128;
            xs[tid] = (pu >= 0) ? NEWU[pu*DD + d] : emb0[(size_t)u*DD + d];
            kv = KL[t*DD + d];
        }
        __syncthreads();                               // B1

        float acc = 0.f;
        {
            const float* xp = xs + h*128;
            #pragma unroll
            for (int j = 0; j < 128; ++j) acc += w[j] * xp[j];
        }
        partial[tid] = acc;
        __syncthreads();                               // B2

        float th = 0.f;
        if (tid < 256) {
            float pre = partial[tid] + partial[256 + tid] + kv;
            th = tanhf(pre);
            float ss = th * th;
            #pragma unroll
            for (int o = 32; o > 0; o >>= 1) ss += __shfl_xor(ss, o, 64);
            if (lane == 0) wsum[wid] = ss;
        }
        __syncthreads();                               // B3

        if (tid < 256) {
            float S  = (tid < 128) ? (wsum[0] + wsum[1]) : (wsum[2] + wsum[3]);
            float sf = 1.f / fmaxf(sqrtf(S), 1e-12f);
            float v2 = th * sf;
            float old = (tid < 128) ? xs[128 + tid] : xs[tid - 128];
            if (tid < 128) NEWU[t*DD + tid]       = v2;
            else           NEWL[t*DD + (tid-128)] = v2;
            float dd = v2 - old;
            float s2 = dd * dd;
            #pragma unroll
            for (int o = 32; o > 0; o >>= 1) s2 += __shfl_xor(s2, o, 64);
            if (lane == 0) wsum[4 + wid] = s2;
        }
        __syncthreads();                               // B4
        if (tid == 0)
            DRIFT[t] = (wsum[4] + wsum[5] + wsum[6] + wsum[7]) * (1.f / 128.f);
    }
}

// Tail: ONE block processes ALL levels >= TAIL_LV sequentially in level order.
__global__ __launch_bounds__(512) void chain_tail(const int* __restrict__ ev,
    const float* __restrict__ emb0,
    const float* __restrict__ wihu, const float* __restrict__ whhu,
    const float* __restrict__ whhl, const float* __restrict__ wihl,
    const float* __restrict__ KU, const float* __restrict__ KL,
    float* __restrict__ NEWU, float* __restrict__ NEWL, float* __restrict__ DRIFT,
    const int* __restrict__ ibase) {
    const int nlev = ibase[IO_NLEV];
    if (nlev <= TAIL_LV) return;
    const int start = ibase[IO_OFF + TAIL_LV];
    const int end   = ibase[IO_OFF + nlev];

    const int tid  = threadIdx.x;
    const int h    = tid >> 8;
    const int r    = tid & 255;
    const int lane = tid & 63;
    const int wid  = tid >> 6;

    float w[128];
    {
        const float* src;
        if (h == 0) src = (r < 128) ? (wihu + r*193) : (whhl + (r-128)*128);
        else        src = (r < 128) ? (whhu + r*128) : (wihl + (r-128)*193);
        #pragma unroll
        for (int j = 0; j < 32; ++j) {
            const float4 v = *(const float4*)(src + j*4);
            w[j*4+0] = v.x; w[j*4+1] = v.y; w[j*4+2] = v.z; w[j*4+3] = v.w;
        }
    }

    __shared__ float xs[256];
    __shared__ float partial[512];
    __shared__ float wsum[8];

    for (int s = start; s < end; ++s) {
        const int t  = ibase[IO_ORDER + s];
        const int u  = ev[t*5];
        const int l  = ev[t*5 + 1];
        const int pu = ibase[IO_PU + t];
        const int pl = ibase[IO_PL + t];

        float kv = 0.f;
        if (tid < 128) {
            xs[tid] = (pl >= 0) ? NEWL[pl*DD + tid] : emb0[(size_t)(l + NUSERS)*DD + tid];
            kv = KU[t*DD + tid];
        } else if (tid < 256) {
            int d = tid - 128;
            xs[tid] = (pu >= 0) ? NEWU[pu*DD + d] : emb0[(size_t)u*DD + d];
            kv = KL[t*DD + d];
        }
        __syncthreads();                               // B1

        float acc = 0.f;
        {
            const float* xp = xs + h*128;
            #pragma unroll
            for (int j = 0; j < 128; ++j) acc += w[j] * xp[j];
        }
        partial[tid] = acc;
        __syncthreads();                               // B2

        float th = 0.f;
        if (tid < 256) {
            float pre = partial[tid] + partial[256 + tid] + kv;
            th = tanhf(pre);
            float ss = th * th;
            #pragma unroll
            for (int o = 32; o > 0; o >>= 1) ss += __shfl_xor(ss, o, 64);
            if (lane == 0) wsum[wid] = ss;
        }
        __syncthreads();                               // B3

        if (tid < 256) {
            float S  = (tid < 128) ? (wsum[0] + wsum[1]) : (wsum[2] + wsum[3]);
            float sf = 1.f / fmaxf(sqrtf(S), 1e-12f);
            float v2 = th * sf;
            float old = (tid < 128) ? xs[128 + tid] : xs[tid - 128];
            if (tid < 128) NEWU[t*DD + tid]       = v2;
            else           NEWL[t*DD + (tid-128)] = v2;
            float dd = v2 - old;
            float s2 = dd * dd;
            #pragma unroll
            for (int o = 32; o > 0; o >>= 1) s2 += __shfl_xor(s2, o, 64);
            if (lane == 0) wsum[4 + wid] = s2;
        }
        __syncthreads();                               // B4
        if (tid == 0)
            DRIFT[t] = (wsum[4] + wsum[5] + wsum[6] + wsum[7]) * (1.f / 128.f);
    }
}

// Wide epilogue: Zb (bf16), ELT, PVU pack, scatter-last.
__global__ __launch_bounds__(256) void build_z(const int* __restrict__ ev,
    const float* __restrict__ emb0, const float* __restrict__ du,
    const float* __restrict__ pw, const float* __restrict__ projb,
    const float* __restrict__ kg,
    const float* __restrict__ NEWU, const float* __restrict__ NEWL,
    unsigned short* __restrict__ Zb, float* __restrict__ ELT,
    int4* __restrict__ PVU,
    float* __restrict__ out, const int* __restrict__ ibase) {
    const int gsz = gridDim.x * blockDim.x;
    const int gid = blockIdx.x * blockDim.x + threadIdx.x;

    for (int i = gid; i < T_STEPS; i += gsz)
        PVU[i] = make_int4(ev[i*5 + 2], ev[i*5 + 0], ev[i*5 + 4], 0);

    for (int i = gid; i < T_STEPS*320; i += gsz) {
        int t = i / 320, j = i - t*320;
        float zv;
        if (j < 128) {
            int pu = ibase[IO_PU + t];
            int uu = ev[t*5];
            float eu = (pu >= 0) ? NEWU[pu*DD + j] : emb0[(size_t)uu*DD + j];
            zv = eu * (1.f + pw[j]*du[t] + projb[j]);
        } else if (j < 256) {
            int jj = j - 128;
            int pp = ibase[IO_PP + t];
            int pv = ev[t*5 + 2];
            zv = (pp >= 0) ? NEWL[pp*DD + jj] : emb0[(size_t)(pv + NUSERS)*DD + jj];
        } else {
            int kp = ev[t*5 + 3];
            zv = kg[kp*KK + (j - 256)];
        }
        Zb[i] = f2bf(zv);
    }
    for (int i = gid; i < DD*T_STEPS; i += gsz) {     // ELT[d][t]
        int d = i >> 11, t = i & 2047;
        int pl = ibase[IO_PL + t];
        int l  = ev[t*5 + 1];
        ELT[i] = (pl >= 0) ? NEWL[pl*DD + d] : emb0[(size_t)(l + NUSERS)*DD + d];
    }
    for (int i = gid; i < T_STEPS*DD; i += gsz) {     // scatter last-occurrence
        int t = i >> 7, d = i & 127;
        if (ibase[IO_LASTU + t]) out[(size_t)ev[t*5]*DD + d]            = NEWU[i];
        if (ibase[IO_LASTL + t]) out[(size_t)(ev[t*5+1]+NUSERS)*DD + d] = NEWL[i];
    }
}

// MFMA GEMM: S[r][t] = sum_k W[r][k]*Z[t][k], bf16 output. 128x128 tile, 4 waves.
__global__ __launch_bounds__(256) void pred_dense_mfma(
    const unsigned short* __restrict__ Wb, const unsigned short* __restrict__ Zb,
    unsigned short* __restrict__ S, int NT, int t0) {
    const int tid = threadIdx.x;
    const int l   = tid & 63;
    const int w   = tid >> 6;
    const int wr  = w >> 1, wc = w & 1;
    const int lr  = l & 15;
    const int kg8 = (l >> 4) * 8;
    const int r0  = blockIdx.y * 128 + wr * 64;
    const int tt0 = blockIdx.x * 128 + wc * 64;

    f32x4 acc[4][4];
    #pragma unroll
    for (int m = 0; m < 4; ++m)
        #pragma unroll
        for (int n = 0; n < 4; ++n) acc[m][n] = (f32x4){0.f, 0.f, 0.f, 0.f};

    for (int k0 = 0; k0 < 320; k0 += 32) {
        short8v a[4], b[4];
        #pragma unroll
        for (int m = 0; m < 4; ++m)
            a[m] = *(const short8v*)(Wb + (size_t)(r0 + m*16 + lr)*320 + k0 + kg8);
        #pragma unroll
        for (int n = 0; n < 4; ++n)
            b[n] = *(const short8v*)(Zb + (size_t)(t0 + tt0 + n*16 + lr)*320 + k0 + kg8);
        #pragma unroll
        for (int m = 0; m < 4; ++m)
            #pragma unroll
            for (int n = 0; n < 4; ++n)
                acc[m][n] = __builtin_amdgcn_mfma_f32_16x16x32_bf16(a[m], b[n], acc[m][n], 0, 0, 0);
    }

    const int orow = (l >> 4) * 4;
    #pragma unroll
    for (int m = 0; m < 4; ++m) {
        #pragma unroll
        for (int i = 0; i < 4; ++i) {
            int r = r0 + m*16 + orow + i;
            if (r < PRED_OUT) {
                unsigned short* dst = S + (size_t)r*NT + tt0 + lr;
                #pragma unroll
                for (int n = 0; n < 4; ++n) dst[n*16] = f2bf(acc[m][n][i]);
            }
        }
    }
}

// Row-centric scatter+finalize. S/PVU/ELT register loads issued BEFORE the
// staging barrier so their latency hides under the 32KB row stage.
__global__ __launch_bounds__(256) void pred_scatter(const int4* __restrict__ PVU,
    const float* __restrict__ predw, const float* __restrict__ predb,
    const float* __restrict__ kg, const unsigned short* __restrict__ S,
    const float* __restrict__ ELT, float* __restrict__ rowp,
    int NT, int t0, int chunk) {
    __shared__ float srow[NLOCAS + NUSERS];   // 32 KB
    __shared__ float red[4];
    const int tid = threadIdx.x;
    const int lane = tid & 63, wid = tid >> 6;
    const int r = blockIdx.x;
    const int mode = (r < DD) ? 0 : (r < DD + NLOCAS ? 1 : 2);
    const bool active = tid < (NT >> 3);      // 8 t per thread

    // ---- pre-barrier independent loads (overlap with stage) ----
    ushort8v sv = (ushort8v)0;
    int4 pq[8];
    float4 e0 = make_float4(0,0,0,0), e1 = make_float4(0,0,0,0);
    if (active) {
        sv = *(const ushort8v*)(S + (size_t)r*NT + tid*8);
        #pragma unroll
        for (int q = 0; q < 8; ++q) pq[q] = PVU[t0 + tid*8 + q];
        if (mode == 0) {
            e0 = *(const float4*)(ELT + r*T_STEPS + t0 + tid*8);
            e1 = *(const float4*)(ELT + r*T_STEPS + t0 + tid*8 + 4);
        }
    }

    // ---- stage 32KB row ----
    const float* base = predw + (size_t)r*PRED_IN + 320;
    #pragma unroll
    for (int i = 0; i < 8; ++i) {
        int idx = (tid + i*256) * 4;
        if (idx < NLOCAS + NUSERS) {
            float4 v = *(const float4*)(base + idx);
            *(float4*)(srow + idx) = v;
        }
    }
    __syncthreads();

    const float bias = predb[r];
    const int kcol = r - DD - NLOCAS;
    float lsum = 0.f;
    if (active) {
        const float ee[8] = {e0.x, e0.y, e0.z, e0.w, e1.x, e1.y, e1.z, e1.w};
        #pragma unroll
        for (int q = 0; q < 8; ++q) {
            const int pv = pq[q].x, uu = pq[q].y, kn = pq[q].z;
            float v = bf2f(sv[q]) + bias + srow[pv] + srow[NLOCAS + uu];
            float tv;
            if (mode == 0)      tv = ee[q];
            else if (mode == 1) tv = (pv == r - DD) ? 1.f : 0.f;
            else                tv = kg[kn*KK + kcol];
            float d = v - tv;
            lsum += d*d;
        }
    }
    #pragma unroll
    for (int o = 32; o > 0; o >>= 1) lsum += __shfl_xor(lsum, o, 64);
    if (lane == 0) red[wid] = lsum;
    __syncthreads();
    if (tid == 0) rowp[chunk*PRED_OUT + r] = red[0] + red[1] + red[2] + red[3];
}

__global__ __launch_bounds__(256) void final_reduce(const float* __restrict__ rowp,
                                                    const float* __restrict__ drift,
                                                    float* __restrict__ out, int nchunk) {
    int tid = threadIdx.x;
    float s = 0.f;
    for (int i = tid; i < nchunk*PRED_OUT; i += 256) s += rowp[i];
    s *= (1.0f / PRED_OUT);
    for (int i = tid; i < T_STEPS; i += 256) s += drift[i];
    #pragma unroll
    for (int o = 32; o > 0; o >>= 1) s += __shfl_xor(s, o, 64);
    __shared__ float red[4];
    if ((tid & 63) == 0) red[tid >> 6] = s;
    __syncthreads();
    if (tid == 0) out[OUT_EMB] = red[0] + red[1] + red[2] + red[3];
}

extern "C" void kernel_launch(void* const* d_in, const int* in_sizes, int n_in,
                              void* d_out, int out_size, void* d_ws, size_t ws_size,
                              hipStream_t stream) {
    const float* emb_in = (const float*)d_in[0];
    const int*   ev     = (const int*)  d_in[1];
    const float* du     = (const float*)d_in[2];
    const float* dl     = (const float*)d_in[3];
    const float* kg     = (const float*)d_in[4];
    const float* wihu   = (const float*)d_in[5];
    const float* whhu   = (const float*)d_in[6];
    const float* bihu   = (const float*)d_in[7];
    const float* bhhu   = (const float*)d_in[8];
    const float* wihl   = (const float*)d_in[9];
    const float* whhl   = (const float*)d_in[10];
    const float* bihl   = (const float*)d_in[11];
    const float* bhhl   = (const float*)d_in[12];
    const float* projw  = (const float*)d_in[13];
    const float* projb  = (const float*)d_in[14];
    const float* predw  = (const float*)d_in[15];
    const float* predb  = (const float*)d_in[16];

    float* out = (float*)d_out;
    float* ws  = (float*)d_ws;
    float* NEWU  = ws + WS_NEWU;
    float* NEWL  = ws + WS_NEWL;
    float* KU    = ws + WS_KU;
    float* KL    = ws + WS_KL;
    unsigned short* Zb = (unsigned short*)(ws + WS_ZB);
    unsigned short* Wb = (unsigned short*)(ws + WS_WB);
    float* ELT   = ws + WS_ELT;
    float* DRIFT = ws + WS_DRIFT;
    float* ROWP  = ws + WS_ROWP;
    int4*  PVU   = (int4*)(ws + WS_PVU);
    unsigned short* S = (unsigned short*)(ws + WS_S);
    int*   ibase = (int*)(ws + WS_INT);

    long cap = ((long)ws_size - (long)WS_S*4) / 2;   // ushort slots for S
    int NT = 2048;
    while (NT > 128 && (long)PRED_OUT * NT > cap) NT >>= 1;
    int nchunk = T_STEPS / NT;

    prep_kernel<<<1024, 256, 0, stream>>>(ev, emb_in, du, dl, kg,
                                          wihu, bihu, bhhu, wihl, bihl, bhhl,
                                          predw, out, KU, KL, Wb, ibase);
    levels_kernel<<<1, 1024, 0, stream>>>(ibase);
    for (int lv = 0; lv < TAIL_LV; ++lv)
        chain_sweep<<<256, 512, 0, stream>>>(lv, ev, emb_in, wihu, whhu, whhl, wihl,
                                             KU, KL, NEWU, NEWL, DRIFT, ibase);
    chain_tail<<<1, 512, 0, stream>>>(ev, emb_in, wihu, whhu, whhl, wihl,
                                      KU, KL, NEWU, NEWL, DRIFT, ibase);
    build_z<<<1024, 256, 0, stream>>>(ev, emb_in, du, projw, projb, kg,
                                      NEWU, NEWL, Zb, ELT, PVU, out, ibase);
    for (int c = 0; c < nchunk; ++c) {
        int t0 = c * NT;
        pred_dense_mfma<<<dim3(NT/128, 33), 256, 0, stream>>>(Wb, Zb, S, NT, t0);
        pred_scatter<<<PRED_OUT, 256, 0, stream>>>(PVU, predw, predb, kg, S, ELT,
                                                   ROWP, NT, t0, c);
    }
    final_reduce<<<1, 256, 0, stream>>>(ROWP, DRIFT, out, nchunk);
}

// Round 12
// 183.886 us; speedup vs baseline: 25.0927x; 1.0350x over previous
//
#include <hip/hip_runtime.h>

#define T_STEPS 2048
#define NUSERS 4000
#define NLOCAS 4000
#define DD 128
#define KK 64
#define PRED_OUT 4192
#define PRED_IN 8256
#define OUT_EMB 1024000   // 8000*128
#define TAIL_LV 6
#define WB_ROWS 4224      // 4192 padded to 33*128

typedef __attribute__((ext_vector_type(8))) short short8v;
typedef __attribute__((ext_vector_type(8))) unsigned short ushort8v;
typedef __attribute__((ext_vector_type(4))) unsigned short ushort4v;
typedef __attribute__((ext_vector_type(4))) float f32x4;

// ---- ws layout (float offsets) ----
#define WS_NEWU   0          // 262144
#define WS_NEWL   262144
#define WS_KU     524288
#define WS_KL     786432
#define WS_ZB     1048576    // 2048*320 ushort
#define WS_WB     1376256    // 4224*320 ushort
#define WS_ELT    2052096    // 128*2048
#define WS_DRIFT  2314240    // 2048
#define WS_ROWP   2316288    // 4192*16 max
#define WS_INT    2450432    // 14400 ints
#define WS_PVU    2464832    // 2048 int2 = 4096 ints, then KN 2048 ints
#define WS_S      2473024    // ushort S[4192*NT]
// ---- int offsets within WS_INT ----
#define IO_PU     0
#define IO_PL     2048
#define IO_PP     4096
#define IO_LASTU  6144
#define IO_LASTL  8192
#define IO_ORDER  10240
#define IO_OFF    12288      // 2049 entries
#define IO_NLEV   14337

__device__ inline unsigned short f2bf(float f) {
    unsigned int x = __float_as_uint(f);
    unsigned int r = (x + 0x7FFFu + ((x >> 16) & 1u)) >> 16;
    return (unsigned short)r;
}
__device__ inline float bf2f(unsigned short u) {
    return __uint_as_float(((unsigned int)u) << 16);
}

// Fused prep: blocks 0..511 = wave-parallel preds scan (4 t/block);
// blocks 512..1023 = precomp_k (4 t/block) + grid-stride {init copy, convw}.
__global__ __launch_bounds__(256) void prep_kernel(const int* __restrict__ ev,
    const float* __restrict__ emb_in, const float* __restrict__ du,
    const float* __restrict__ dl, const float* __restrict__ kg,
    const float* __restrict__ wihu, const float* __restrict__ bihu,
    const float* __restrict__ bhhu, const float* __restrict__ wihl,
    const float* __restrict__ bihl, const float* __restrict__ bhhl,
    const float* __restrict__ predw,
    float* __restrict__ out, float* __restrict__ KU, float* __restrict__ KL,
    unsigned short* __restrict__ Wb, int* __restrict__ ibase) {
    __shared__ int su[T_STEPS];
    __shared__ int sl[T_STEPS];
    __shared__ float skg[4][KK];
    __shared__ int kn4[4];
    const int tid = threadIdx.x;

    if (blockIdx.x < 512) {
        const int lane = tid & 63;
        const int wid  = tid >> 6;
        for (int i = tid; i < T_STEPS; i += 256) { su[i] = ev[i*5]; sl[i] = ev[i*5+1]; }
        __syncthreads();

        const int t = blockIdx.x * 4 + wid;
        const int u = su[t], l = sl[t], p = ev[t*5 + 2];

        int pu = -1, pl = -1, pp = -1;
        {
            int round = 0;
            while (true) {
                const int q = t - 1 - lane - (round << 6);
                const int squ = (q >= 0) ? su[q] : -1;
                const int sql = (q >= 0) ? sl[q] : -1;
                if (pu < 0) {
                    unsigned long long b = __ballot(squ == u);
                    if (b) pu = t - 1 - (__ffsll(b) - 1) - (round << 6);
                }
                if (pl < 0) {
                    unsigned long long b = __ballot(sql == l);
                    if (b) pl = t - 1 - (__ffsll(b) - 1) - (round << 6);
                }
                if (pp < 0) {
                    unsigned long long b = __ballot(sql == p);
                    if (b) pp = t - 1 - (__ffsll(b) - 1) - (round << 6);
                }
                ++round;
                if ((pu >= 0 && pl >= 0 && pp >= 0) || (t - 1 - (round << 6) < 0)) break;
            }
        }
        int lastu = 1, lastl = 1;
        {
            int round = 0;
            while (true) {
                const int q = t + 1 + lane + (round << 6);
                const int squ = (q < T_STEPS) ? su[q] : -1;
                const int sql = (q < T_STEPS) ? sl[q] : -1;
                if (lastu && __ballot(squ == u)) lastu = 0;
                if (lastl && __ballot(sql == l)) lastl = 0;
                ++round;
                if ((!lastu && !lastl) || (t + 1 + (round << 6) >= T_STEPS)) break;
            }
        }
        if (lane == 0) {
            ibase[IO_PU + t] = pu;
            ibase[IO_PL + t] = pl;
            ibase[IO_PP + t] = pp;
            ibase[IO_LASTU + t] = lastu;
            ibase[IO_LASTL + t] = lastl;
        }
        return;
    }

    // ---- precomp_k for 4 t ----
    const int pb = blockIdx.x - 512;
    if (tid < 4) kn4[tid] = ev[(pb*4 + tid)*5 + 4];
    __syncthreads();
    skg[tid >> 6][tid & 63] = kg[kn4[tid >> 6]*KK + (tid & 63)];
    __syncthreads();
    #pragma unroll
    for (int p = 0; p < 2; ++p) {
        const int sub = p*2 + (tid >> 7);
        const int t = pb*4 + sub;
        const int r = tid & 127;
        const float* wu = wihu + r*193;
        const float* wl = wihl + r*193;
        const float dut = du[t], dlt = dl[t];
        float ku = bihu[r] + bhhu[r] + wu[192]*dut;
        float kl = bihl[r] + bhhl[r] + wl[192]*dlt;
        const float* sk = skg[sub];
        #pragma unroll
        for (int j = 0; j < KK; ++j) {
            float s = sk[j];
            ku += wu[128+j]*s;
            kl += wl[128+j]*s;
        }
        KU[t*DD + r] = ku;
        KL[t*DD + r] = kl;
    }

    // ---- init copy (float4) + convw, grid-stride ----
    const int gsz = 512 * 256;
    const int gid = pb * 256 + tid;
    for (int i = gid; i < OUT_EMB/4; i += gsz)
        ((float4*)out)[i] = ((const float4*)emb_in)[i];
    for (int i = gid; i < WB_ROWS*80; i += gsz) {
        int r = i / 80, kc = (i - r*80) * 4;
        unsigned short o0 = 0, o1 = 0, o2 = 0, o3 = 0;
        if (r < PRED_OUT) {
            const float4 v = *(const float4*)(predw + (size_t)r*PRED_IN + kc);
            o0 = f2bf(v.x); o1 = f2bf(v.y); o2 = f2bf(v.z); o3 = f2bf(v.w);
        }
        unsigned short* dst = Wb + (size_t)r*320 + kc;
        dst[0] = o0; dst[1] = o1; dst[2] = o2; dst[3] = o3;
    }
}

// DAG levels via monotone fixpoint; counting sort into ORDER with OFF[], NLEV.
__global__ __launch_bounds__(1024) void levels_kernel(int* __restrict__ ibase) {
    __shared__ int lev[T_STEPS];
    __shared__ int spu[T_STEPS];
    __shared__ int spl[T_STEPS];
    __shared__ int cnt[T_STEPS + 1];
    __shared__ int changed;
    __shared__ int smax;
    const int tid = threadIdx.x;

    for (int i = tid; i < T_STEPS; i += 1024) {
        spu[i] = ibase[IO_PU + i];
        spl[i] = ibase[IO_PL + i];
        lev[i] = 0;
    }
    if (tid == 0) smax = 0;
    __syncthreads();

    while (true) {
        if (tid == 0) changed = 0;
        __syncthreads();
        for (int i = tid; i < T_STEPS; i += 1024) {
            int nl = 0, a = spu[i], b = spl[i];
            if (a >= 0) nl = lev[a] + 1;
            if (b >= 0) { int v = lev[b] + 1; if (v > nl) nl = v; }
            if (nl > lev[i]) { lev[i] = nl; changed = 1; }
        }
        __syncthreads();
        if (!changed) break;
        __syncthreads();
    }

    for (int i = tid; i <= T_STEPS; i += 1024) cnt[i] = 0;
    __syncthreads();
    for (int i = tid; i < T_STEPS; i += 1024) {
        atomicAdd(&cnt[lev[i]], 1);
        atomicMax(&smax, lev[i]);
    }
    __syncthreads();
    if (tid == 0) {
        int nlev = smax + 1;
        int acc = 0;
        for (int k = 0; k < nlev; ++k) {
            ibase[IO_OFF + k] = acc;
            int c = cnt[k]; cnt[k] = acc; acc += c;
        }
        ibase[IO_OFF + nlev] = acc;
        ibase[IO_NLEV] = nlev;
        for (int k = nlev + 1; k <= TAIL_LV; ++k) ibase[IO_OFF + k] = acc;
    }
    __syncthreads();
    for (int i = tid; i < T_STEPS; i += 1024) {
        int pos = atomicAdd(&cnt[lev[i]], 1);
        ibase[IO_ORDER + pos] = i;
    }
}

// One DAG level per launch (levels 0..TAIL_LV-1). 256 blocks x 512 threads.
__global__ __launch_bounds__(512) void chain_sweep(int lv, const int* __restrict__ ev,
    const float* __restrict__ emb0,
    const float* __restrict__ wihu, const float* __restrict__ whhu,
    const float* __restrict__ whhl, const float* __restrict__ wihl,
    const float* __restrict__ KU, const float* __restrict__ KL,
    float* __restrict__ NEWU, float* __restrict__ NEWL, float* __restrict__ DRIFT,
    const int* __restrict__ ibase) {
    const int start = ibase[IO_OFF + lv];
    const int end   = ibase[IO_OFF + lv + 1];
    if ((int)blockIdx.x >= end - start) return;

    const int tid  = threadIdx.x;
    const int h    = tid >> 8;
    const int r    = tid & 255;
    const int lane = tid & 63;
    const int wid  = tid >> 6;

    float w[128];
    {
        const float* src;
        if (h == 0) src = (r < 128) ? (wihu + r*193) : (whhl + (r-128)*128);
        else        src = (r < 128) ? (whhu + r*128) : (wihl + (r-128)*193);
        #pragma unroll
        for (int j = 0; j < 32; ++j) {
            const float4 v = *(const float4*)(src + j*4);
            w[j*4+0] = v.x; w[j*4+1] = v.y; w[j*4+2] = v.z; w[j*4+3] = v.w;
        }
    }

    __shared__ float xs[256];
    __shared__ float partial[512];
    __shared__ float wsum[8];

    for (int s = start + blockIdx.x; s < end; s += gridDim.x) {
        const int t  = ibase[IO_ORDER + s];
        const int u  = ev[t*5];
        const int l  = ev[t*5 + 1];
        const int pu = ibase[IO_PU + t];
        const int pl = ibase[IO_PL + t];

        float kv = 0.f;
        if (tid < 128) {
            xs[tid] = (pl >= 0) ? NEWL[pl*DD + tid] : emb0[(size_t)(l + NUSERS)*DD + tid];
            kv = KU[t*DD + tid];
        } else if (tid < 256) {
            int d = tid - 128;
            xs[tid] = (pu >= 0) ? NEWU[pu*DD + d] : emb0[(size_t)u*DD + d];
            kv = KL[t*DD + d];
        }
        __syncthreads();                               // B1

        float acc = 0.f;
        {
            const float* xp = xs + h*128;
            #pragma unroll
            for (int j = 0; j < 128; ++j) acc += w[j] * xp[j];
        }
        partial[tid] = acc;
        __syncthreads();                               // B2

        float th = 0.f;
        if (tid < 256) {
            float pre = partial[tid] + partial[256 + tid] + kv;
            th = tanhf(pre);
            float ss = th * th;
            #pragma unroll
            for (int o = 32; o > 0; o >>= 1) ss += __shfl_xor(ss, o, 64);
            if (lane == 0) wsum[wid] = ss;
        }
        __syncthreads();                               // B3

        if (tid < 256) {
            float S  = (tid < 128) ? (wsum[0] + wsum[1]) : (wsum[2] + wsum[3]);
            float sf = 1.f / fmaxf(sqrtf(S), 1e-12f);
            float v2 = th * sf;
            float old = (tid < 128) ? xs[128 + tid] : xs[tid - 128];
            if (tid < 128) NEWU[t*DD + tid]       = v2;
            else           NEWL[t*DD + (tid-128)] = v2;
            float dd = v2 - old;
            float s2 = dd * dd;
            #pragma unroll
            for (int o = 32; o > 0; o >>= 1) s2 += __shfl_xor(s2, o, 64);
            if (lane == 0) wsum[4 + wid] = s2;
        }
        __syncthreads();                               // B4
        if (tid == 0)
            DRIFT[t] = (wsum[4] + wsum[5] + wsum[6] + wsum[7]) * (1.f / 128.f);
    }
}

// Tail: ONE block processes ALL levels >= TAIL_LV sequentially in level order.
__global__ __launch_bounds__(512) void chain_tail(const int* __restrict__ ev,
    const float* __restrict__ emb0,
    const float* __restrict__ wihu, const float* __restrict__ whhu,
    const float* __restrict__ whhl, const float* __restrict__ wihl,
    const float* __restrict__ KU, const float* __restrict__ KL,
    float* __restrict__ NEWU, float* __restrict__ NEWL, float* __restrict__ DRIFT,
    const int* __restrict__ ibase) {
    const int nlev = ibase[IO_NLEV];
    if (nlev <= TAIL_LV) return;
    const int start = ibase[IO_OFF + TAIL_LV];
    const int end   = ibase[IO_OFF + nlev];

    const int tid  = threadIdx.x;
    const int h    = tid >> 8;
    const int r    = tid & 255;
    const int lane = tid & 63;
    const int wid  = tid >> 6;

    float w[128];
    {
        const float* src;
        if (h == 0) src = (r < 128) ? (wihu + r*193) : (whhl + (r-128)*128);
        else        src = (r < 128) ? (whhu + r*128) : (wihl + (r-128)*193);
        #pragma unroll
        for (int j = 0; j < 32; ++j) {
            const float4 v = *(const float4*)(src + j*4);
            w[j*4+0] = v.x; w[j*4+1] = v.y; w[j*4+2] = v.z; w[j*4+3] = v.w;
        }
    }

    __shared__ float xs[256];
    __shared__ float partial[512];
    __shared__ float wsum[8];

    for (int s = start; s < end; ++s) {
        const int t  = ibase[IO_ORDER + s];
        const int u  = ev[t*5];
        const int l  = ev[t*5 + 1];
        const int pu = ibase[IO_PU + t];
        const int pl = ibase[IO_PL + t];

        float kv = 0.f;
        if (tid < 128) {
            xs[tid] = (pl >= 0) ? NEWL[pl*DD + tid] : emb0[(size_t)(l + NUSERS)*DD + tid];
            kv = KU[t*DD + tid];
        } else if (tid < 256) {
            int d = tid - 128;
            xs[tid] = (pu >= 0) ? NEWU[pu*DD + d] : emb0[(size_t)u*DD + d];
            kv = KL[t*DD + d];
        }
        __syncthreads();                               // B1

        float acc = 0.f;
        {
            const float* xp = xs + h*128;
            #pragma unroll
            for (int j = 0; j < 128; ++j) acc += w[j] * xp[j];
        }
        partial[tid] = acc;
        __syncthreads();                               // B2

        float th = 0.f;
        if (tid < 256) {
            float pre = partial[tid] + partial[256 + tid] + kv;
            th = tanhf(pre);
            float ss = th * th;
            #pragma unroll
            for (int o = 32; o > 0; o >>= 1) ss += __shfl_xor(ss, o, 64);
            if (lane == 0) wsum[wid] = ss;
        }
        __syncthreads();                               // B3

        if (tid < 256) {
            float S  = (tid < 128) ? (wsum[0] + wsum[1]) : (wsum[2] + wsum[3]);
            float sf = 1.f / fmaxf(sqrtf(S), 1e-12f);
            float v2 = th * sf;
            float old = (tid < 128) ? xs[128 + tid] : xs[tid - 128];
            if (tid < 128) NEWU[t*DD + tid]       = v2;
            else           NEWL[t*DD + (tid-128)] = v2;
            float dd = v2 - old;
            float s2 = dd * dd;
            #pragma unroll
            for (int o = 32; o > 0; o >>= 1) s2 += __shfl_xor(s2, o, 64);
            if (lane == 0) wsum[4 + wid] = s2;
        }
        __syncthreads();                               // B4
        if (tid == 0)
            DRIFT[t] = (wsum[4] + wsum[5] + wsum[6] + wsum[7]) * (1.f / 128.f);
    }
}

// Wide epilogue: Zb (bf16), ELT, PVU(int2)+KN pack, scatter-last.
__global__ __launch_bounds__(256) void build_z(const int* __restrict__ ev,
    const float* __restrict__ emb0, const float* __restrict__ du,
    const float* __restrict__ pw, const float* __restrict__ projb,
    const float* __restrict__ kg,
    const float* __restrict__ NEWU, const float* __restrict__ NEWL,
    unsigned short* __restrict__ Zb, float* __restrict__ ELT,
    int2* __restrict__ PVU, int* __restrict__ KN,
    float* __restrict__ out, const int* __restrict__ ibase) {
    const int gsz = gridDim.x * blockDim.x;
    const int gid = blockIdx.x * blockDim.x + threadIdx.x;

    for (int i = gid; i < T_STEPS; i += gsz) {
        PVU[i] = make_int2(ev[i*5 + 2], ev[i*5 + 0]);
        KN[i]  = ev[i*5 + 4];
    }

    for (int i = gid; i < T_STEPS*320; i += gsz) {
        int t = i / 320, j = i - t*320;
        float zv;
        if (j < 128) {
            int pu = ibase[IO_PU + t];
            int uu = ev[t*5];
            float eu = (pu >= 0) ? NEWU[pu*DD + j] : emb0[(size_t)uu*DD + j];
            zv = eu * (1.f + pw[j]*du[t] + projb[j]);
        } else if (j < 256) {
            int jj = j - 128;
            int pp = ibase[IO_PP + t];
            int pv = ev[t*5 + 2];
            zv = (pp >= 0) ? NEWL[pp*DD + jj] : emb0[(size_t)(pv + NUSERS)*DD + jj];
        } else {
            int kp = ev[t*5 + 3];
            zv = kg[kp*KK + (j - 256)];
        }
        Zb[i] = f2bf(zv);
    }
    for (int i = gid; i < DD*T_STEPS; i += gsz) {     // ELT[d][t]
        int d = i >> 11, t = i & 2047;
        int pl = ibase[IO_PL + t];
        int l  = ev[t*5 + 1];
        ELT[i] = (pl >= 0) ? NEWL[pl*DD + d] : emb0[(size_t)(l + NUSERS)*DD + d];
    }
    for (int i = gid; i < T_STEPS*DD; i += gsz) {     // scatter last-occurrence
        int t = i >> 7, d = i & 127;
        if (ibase[IO_LASTU + t]) out[(size_t)ev[t*5]*DD + d]            = NEWU[i];
        if (ibase[IO_LASTL + t]) out[(size_t)(ev[t*5+1]+NUSERS)*DD + d] = NEWL[i];
    }
}

// MFMA GEMM: S[r][t] = sum_k W[r][k]*Z[t][k], bf16 output. 128x128 tile, 4 waves.
__global__ __launch_bounds__(256) void pred_dense_mfma(
    const unsigned short* __restrict__ Wb, const unsigned short* __restrict__ Zb,
    unsigned short* __restrict__ S, int NT, int t0) {
    const int tid = threadIdx.x;
    const int l   = tid & 63;
    const int w   = tid >> 6;
    const int wr  = w >> 1, wc = w & 1;
    const int lr  = l & 15;
    const int kg8 = (l >> 4) * 8;
    const int r0  = blockIdx.y * 128 + wr * 64;
    const int tt0 = blockIdx.x * 128 + wc * 64;

    f32x4 acc[4][4];
    #pragma unroll
    for (int m = 0; m < 4; ++m)
        #pragma unroll
        for (int n = 0; n < 4; ++n) acc[m][n] = (f32x4){0.f, 0.f, 0.f, 0.f};

    for (int k0 = 0; k0 < 320; k0 += 32) {
        short8v a[4], b[4];
        #pragma unroll
        for (int m = 0; m < 4; ++m)
            a[m] = *(const short8v*)(Wb + (size_t)(r0 + m*16 + lr)*320 + k0 + kg8);
        #pragma unroll
        for (int n = 0; n < 4; ++n)
            b[n] = *(const short8v*)(Zb + (size_t)(t0 + tt0 + n*16 + lr)*320 + k0 + kg8);
        #pragma unroll
        for (int m = 0; m < 4; ++m)
            #pragma unroll
            for (int n = 0; n < 4; ++n)
                acc[m][n] = __builtin_amdgcn_mfma_f32_16x16x32_bf16(a[m], b[n], acc[m][n], 0, 0, 0);
    }

    const int orow = (l >> 4) * 4;
    #pragma unroll
    for (int m = 0; m < 4; ++m) {
        #pragma unroll
        for (int i = 0; i < 4; ++i) {
            int r = r0 + m*16 + orow + i;
            if (r < PRED_OUT) {
                unsigned short* dst = S + (size_t)r*NT + tt0 + lr;
                #pragma unroll
                for (int n = 0; n < 4; ++n) dst[n*16] = f2bf(acc[m][n][i]);
            }
        }
    }
}

// Row-centric scatter+finalize. srow staged as bf16 (16KB LDS -> 8 blocks/CU).
// S/PVU/ELT register loads issued BEFORE the staging barrier.
__global__ __launch_bounds__(256) void pred_scatter(const int2* __restrict__ PVU,
    const int* __restrict__ KN,
    const float* __restrict__ predw, const float* __restrict__ predb,
    const float* __restrict__ kg, const unsigned short* __restrict__ S,
    const float* __restrict__ ELT, float* __restrict__ rowp,
    int NT, int t0, int chunk) {
    __shared__ unsigned short srow[NLOCAS + NUSERS];   // 16 KB (bf16)
    __shared__ float red[4];
    const int tid = threadIdx.x;
    const int lane = tid & 63, wid = tid >> 6;
    const int r = blockIdx.x;
    const int mode = (r < DD) ? 0 : (r < DD + NLOCAS ? 1 : 2);
    const bool active = tid < (NT >> 3);      // 8 t per thread

    // ---- pre-barrier independent loads (overlap with stage) ----
    ushort8v sv = (ushort8v)0;
    int4 pv4[4];                              // {pv0,u0,pv1,u1} pairs
    int4 kn0 = make_int4(0,0,0,0), kn1 = make_int4(0,0,0,0);
    float4 e0 = make_float4(0,0,0,0), e1 = make_float4(0,0,0,0);
    if (active) {
        sv = *(const ushort8v*)(S + (size_t)r*NT + tid*8);
        #pragma unroll
        for (int q = 0; q < 4; ++q)
            pv4[q] = *(const int4*)(PVU + t0 + tid*8 + q*2);
        if (mode == 0) {
            e0 = *(const float4*)(ELT + r*T_STEPS + t0 + tid*8);
            e1 = *(const float4*)(ELT + r*T_STEPS + t0 + tid*8 + 4);
        } else if (mode == 2) {
            kn0 = *(const int4*)(KN + t0 + tid*8);
            kn1 = *(const int4*)(KN + t0 + tid*8 + 4);
        }
    }

    // ---- stage 32KB row as bf16 (16KB LDS) ----
    const float* base = predw + (size_t)r*PRED_IN + 320;
    #pragma unroll
    for (int i = 0; i < 8; ++i) {
        int idx = (tid + i*256) * 4;
        if (idx < NLOCAS + NUSERS) {
            float4 v = *(const float4*)(base + idx);
            ushort4v o;
            o.x = f2bf(v.x); o.y = f2bf(v.y); o.z = f2bf(v.z); o.w = f2bf(v.w);
            *(ushort4v*)(srow + idx) = o;
        }
    }
    __syncthreads();

    const float bias = predb[r];
    const int kcol = r - DD - NLOCAS;
    float lsum = 0.f;
    if (active) {
        const float ee[8] = {e0.x, e0.y, e0.z, e0.w, e1.x, e1.y, e1.z, e1.w};
        const int kk[8] = {kn0.x, kn0.y, kn0.z, kn0.w, kn1.x, kn1.y, kn1.z, kn1.w};
        const int pvs[8] = {pv4[0].x, pv4[0].z, pv4[1].x, pv4[1].z,
                            pv4[2].x, pv4[2].z, pv4[3].x, pv4[3].z};
        const int uus[8] = {pv4[0].y, pv4[0].w, pv4[1].y, pv4[1].w,
                            pv4[2].y, pv4[2].w, pv4[3].y, pv4[3].w};
        #pragma unroll
        for (int q = 0; q < 8; ++q) {
            const int pv = pvs[q], uu = uus[q];
            float v = bf2f(sv[q]) + bias + bf2f(srow[pv]) + bf2f(srow[NLOCAS + uu]);
            float tv;
            if (mode == 0)      tv = ee[q];
            else if (mode == 1) tv = (pv == r - DD) ? 1.f : 0.f;
            else                tv = kg[kk[q]*KK + kcol];
            float d = v - tv;
            lsum += d*d;
        }
    }
    #pragma unroll
    for (int o = 32; o > 0; o >>= 1) lsum += __shfl_xor(lsum, o, 64);
    if (lane == 0) red[wid] = lsum;
    __syncthreads();
    if (tid == 0) rowp[chunk*PRED_OUT + r] = red[0] + red[1] + red[2] + red[3];
}

__global__ __launch_bounds__(256) void final_reduce(const float* __restrict__ rowp,
                                                    const float* __restrict__ drift,
                                                    float* __restrict__ out, int nchunk) {
    int tid = threadIdx.x;
    float s = 0.f;
    for (int i = tid; i < nchunk*PRED_OUT; i += 256) s += rowp[i];
    s *= (1.0f / PRED_OUT);
    for (int i = tid; i < T_STEPS; i += 256) s += drift[i];
    #pragma unroll
    for (int o = 32; o > 0; o >>= 1) s += __shfl_xor(s, o, 64);
    __shared__ float red[4];
    if ((tid & 63) == 0) red[tid >> 6] = s;
    __syncthreads();
    if (tid == 0) out[OUT_EMB] = red[0] + red[1] + red[2] + red[3];
}

extern "C" void kernel_launch(void* const* d_in, const int* in_sizes, int n_in,
                              void* d_out, int out_size, void* d_ws, size_t ws_size,
                              hipStream_t stream) {
    const float* emb_in = (const float*)d_in[0];
    const int*   ev     = (const int*)  d_in[1];
    const float* du     = (const float*)d_in[2];
    const float* dl     = (const float*)d_in[3];
    const float* kg     = (const float*)d_in[4];
    const float* wihu   = (const float*)d_in[5];
    const float* whhu   = (const float*)d_in[6];
    const float* bihu   = (const float*)d_in[7];
    const float* bhhu   = (const float*)d_in[8];
    const float* wihl   = (const float*)d_in[9];
    const float* whhl   = (const float*)d_in[10];
    const float* bihl   = (const float*)d_in[11];
    const float* bhhl   = (const float*)d_in[12];
    const float* projw  = (const float*)d_in[13];
    const float* projb  = (const float*)d_in[14];
    const float* predw  = (const float*)d_in[15];
    const float* predb  = (const float*)d_in[16];

    float* out = (float*)d_out;
    float* ws  = (float*)d_ws;
    float* NEWU  = ws + WS_NEWU;
    float* NEWL  = ws + WS_NEWL;
    float* KU    = ws + WS_KU;
    float* KL    = ws + WS_KL;
    unsigned short* Zb = (unsigned short*)(ws + WS_ZB);
    unsigned short* Wb = (unsigned short*)(ws + WS_WB);
    float* ELT   = ws + WS_ELT;
    float* DRIFT = ws + WS_DRIFT;
    float* ROWP  = ws + WS_ROWP;
    int2*  PVU   = (int2*)(ws + WS_PVU);
    int*   KN    = (int*)(ws + WS_PVU) + 4096;
    unsigned short* S = (unsigned short*)(ws + WS_S);
    int*   ibase = (int*)(ws + WS_INT);

    long cap = ((long)ws_size - (long)WS_S*4) / 2;   // ushort slots for S
    int NT = 2048;
    while (NT > 128 && (long)PRED_OUT * NT > cap) NT >>= 1;
    int nchunk = T_STEPS / NT;

    prep_kernel<<<1024, 256, 0, stream>>>(ev, emb_in, du, dl, kg,
                                          wihu, bihu, bhhu, wihl, bihl, bhhl,
                                          predw, out, KU, KL, Wb, ibase);
    levels_kernel<<<1, 1024, 0, stream>>>(ibase);
    for (int lv = 0; lv < TAIL_LV; ++lv)
        chain_sweep<<<256, 512, 0, stream>>>(lv, ev, emb_in, wihu, whhu, whhl, wihl,
                                             KU, KL, NEWU, NEWL, DRIFT, ibase);
    chain_tail<<<1, 512, 0, stream>>>(ev, emb_in, wihu, whhu, whhl, wihl,
                                      KU, KL, NEWU, NEWL, DRIFT, ibase);
    build_z<<<1024, 256, 0, stream>>>(ev, emb_in, du, projw, projb, kg,
                                      NEWU, NEWL, Zb, ELT, PVU, KN, out, ibase);
    for (int c = 0; c < nchunk; ++c) {
        int t0 = c * NT;
        pred_dense_mfma<<<dim3(NT/128, 33), 256, 0, stream>>>(Wb, Zb, S, NT, t0);
        pred_scatter<<<PRED_OUT, 256, 0, stream>>>(PVU, KN, predw, predb, kg, S, ELT,
                                                   ROWP, NT, t0, c);
    }
    final_reduce<<<1, 256, 0, stream>>>(ROWP, DRIFT, out, nchunk);
}